// Round 3
// baseline (433.950 us; speedup 1.0000x reference)
//
#include <hip/hip_runtime.h>

typedef unsigned short u16;
typedef __attribute__((ext_vector_type(8))) short bf16x8;
typedef __attribute__((ext_vector_type(4))) float f32x4;

__device__ inline u16 f2bf(float f) {
  unsigned int u = __float_as_uint(f);
  u += 0x7fffu + ((u >> 16) & 1u);
  return (u16)(u >> 16);
}
__device__ inline float bf2f(u16 h) { return __uint_as_float(((unsigned int)h) << 16); }

__device__ inline void gload_lds16(const void* gp, void* lp) {
  __builtin_amdgcn_global_load_lds(
      (const __attribute__((address_space(1))) unsigned int*)gp,
      (__attribute__((address_space(3))) unsigned int*)lp, 16, 0, 0);
}

// ---------------- LayerNorm: f32 [rows][1024] -> bf16 ----------------
__global__ __launch_bounds__(256) void ln_kernel(const float* __restrict__ x,
                                                 const float* __restrict__ g,
                                                 const float* __restrict__ beta,
                                                 u16* __restrict__ y) {
  __shared__ float red[8];
  const int row = blockIdx.x;
  const int t = threadIdx.x;
  const float4 xv = *(const float4*)(x + (long)row * 1024 + t * 4);
  float s = xv.x + xv.y + xv.z + xv.w;
  float sq = xv.x * xv.x + xv.y * xv.y + xv.z * xv.z + xv.w * xv.w;
#pragma unroll
  for (int d = 1; d < 64; d <<= 1) {
    s += __shfl_xor(s, d);
    sq += __shfl_xor(sq, d);
  }
  if ((t & 63) == 0) { red[t >> 6] = s; red[4 + (t >> 6)] = sq; }
  __syncthreads();
  s = red[0] + red[1] + red[2] + red[3];
  sq = red[4] + red[5] + red[6] + red[7];
  const float mean = s * (1.f / 1024.f);
  const float var = sq * (1.f / 1024.f) - mean * mean;
  const float inv = rsqrtf(var + 1e-5f);
  float xe[4] = {xv.x, xv.y, xv.z, xv.w};
  u16 ov[4];
#pragma unroll
  for (int e = 0; e < 4; ++e)
    ov[e] = f2bf((xe[e] - mean) * inv * g[t * 4 + e] + beta[t * 4 + e]);
  *(unsigned long long*)(y + (long)row * 1024 + t * 4) = *(unsigned long long*)ov;
}

// ------------- transpose + convert: f32 in[R][C] -> bf16 out[C][R] -------------
__global__ __launch_bounds__(256) void transpose_bf16(const float* __restrict__ in,
                                                      u16* __restrict__ out,
                                                      int R, int C) {
  __shared__ float tile[32][33];
  const int tx = threadIdx.x & 31, ty = threadIdx.x >> 5;
  const int c0 = blockIdx.x * 32, r0 = blockIdx.y * 32;
#pragma unroll
  for (int i = 0; i < 4; ++i)
    tile[ty + i * 8][tx] = in[(long)(r0 + ty + i * 8) * C + c0 + tx];
  __syncthreads();
#pragma unroll
  for (int i = 0; i < 4; ++i)
    out[(long)(c0 + ty + i * 8) * R + r0 + tx] = f2bf(tile[tx][ty + i * 8]);
}

// ------------- RoPE + split: qkv f32 [rows][3072] -> q,k (rotated, q scaled), v bf16 -------------
__global__ __launch_bounds__(256) void rope_kernel(const float* __restrict__ qkv,
                                                   u16* __restrict__ qr,
                                                   u16* __restrict__ kr,
                                                   u16* __restrict__ vv) {
  const int row = blockIdx.x;            // b*2048 + s
  const int s = row & 2047;
  const int t = threadIdx.x;
  const float* base = qkv + (long)row * 3072;
  const long orow = (long)row * 1024;
#pragma unroll
  for (int rep = 0; rep < 2; ++rep) {
    const int p = rep * 256 + t;         // 0..511 : h*32 + d0
    const int h = p >> 5, d0 = p & 31;
    const float inv = exp2f((float)d0 * (-13.287712379549449f / 32.f));
    const float ang = (float)s * inv;
    float sn, cs;
    sincosf(ang, &sn, &cs);
    const int c1 = h * 64 + d0, c2 = c1 + 32;
    float x1 = base[c1], x2 = base[c2];
    qr[orow + c1] = f2bf((x1 * cs - x2 * sn) * 0.125f);   // fold hd^-0.5
    qr[orow + c2] = f2bf((x2 * cs + x1 * sn) * 0.125f);
    float y1 = base[1024 + c1], y2 = base[1024 + c2];
    kr[orow + c1] = f2bf(y1 * cs - y2 * sn);
    kr[orow + c2] = f2bf(y2 * cs + y1 * sn);
  }
#pragma unroll
  for (int rep = 0; rep < 4; ++rep) {
    const int d = rep * 256 + t;
    vv[orow + d] = f2bf(base[2048 + d]);
  }
}

// ------------- local-causal flash attention, window 256, hd=64, H=16 -------------
__global__ __launch_bounds__(256) void attn_kernel(const u16* __restrict__ qr,
                                                   const u16* __restrict__ kr,
                                                   const u16* __restrict__ vv,
                                                   u16* __restrict__ o) {
  __shared__ __attribute__((aligned(16))) u16 Ks[320][72];
  __shared__ __attribute__((aligned(16))) u16 Vt[64][336];
  __shared__ __attribute__((aligned(16))) u16 Pl[4][16][40];

  const int blk = blockIdx.x;
  const int qt = blk & 31;
  const int h = (blk >> 5) & 15;
  const int b = blk >> 9;
  const int qs = qt * 64;
  const int jbase = qs - 256;
  const int t = threadIdx.x;
  const int w = t >> 6, l = t & 63;
  const int lr = l & 15, lg = l >> 4;
  const long bh = (long)b * 2048 * 1024 + h * 64;

#pragma unroll
  for (int it = 0; it < 10; ++it) {
    const int c = it * 256 + t;
    const int jj = c >> 3, c8 = c & 7;
    const int jg = jbase + jj;
    bf16x8 val;
#pragma unroll
    for (int e = 0; e < 8; ++e) val[e] = 0;
    if (jg >= 0) val = *(const bf16x8*)(kr + bh + (long)jg * 1024 + c8 * 8);
    *(bf16x8*)(&Ks[jj][c8 * 8]) = val;
  }
#pragma unroll
  for (int it = 0; it < 10; ++it) {
    const int c = it * 256 + t;
    const int jj = c % 320, c8 = c / 320;
    const int jg = jbase + jj;
    if (jg >= 0) {
      bf16x8 val = *(const bf16x8*)(vv + bh + (long)jg * 1024 + c8 * 8);
#pragma unroll
      for (int e = 0; e < 8; ++e) Vt[c8 * 8 + e][jj] = (u16)val[e];
    } else {
#pragma unroll
      for (int e = 0; e < 8; ++e) Vt[c8 * 8 + e][jj] = 0;
    }
  }

  const int wq0 = w * 16;
  const u16* qp = qr + bh + (long)(qs + wq0 + lr) * 1024 + lg * 8;
  const bf16x8 aq0 = *(const bf16x8*)qp;
  const bf16x8 aq1 = *(const bf16x8*)(qp + 32);

  __syncthreads();

  f32x4 oacc[4];
#pragma unroll
  for (int nt = 0; nt < 4; ++nt) { oacc[nt][0] = 0.f; oacc[nt][1] = 0.f; oacc[nt][2] = 0.f; oacc[nt][3] = 0.f; }
  float m_[4], ls[4];
#pragma unroll
  for (int r = 0; r < 4; ++r) { m_[r] = -1e30f; ls[r] = 0.f; }

  const int qmaxw = qs + wq0 + 15;
  for (int ch = 0; ch < 10; ++ch) {
    const int j0 = ch * 32;
    const int jg0 = jbase + j0;
    if (jg0 + 31 < 0) continue;
    if (jg0 > qmaxw) break;

    f32x4 s0, s1;
    {
      f32x4 z; z[0] = z[1] = z[2] = z[3] = 0.f;
      const u16* kp0 = &Ks[j0 + lr][lg * 8];
      bf16x8 b0 = *(const bf16x8*)kp0;
      bf16x8 b1 = *(const bf16x8*)(kp0 + 32);
      s0 = __builtin_amdgcn_mfma_f32_16x16x32_bf16(aq0, b0, z, 0, 0, 0);
      s0 = __builtin_amdgcn_mfma_f32_16x16x32_bf16(aq1, b1, s0, 0, 0, 0);
      const u16* kp1 = &Ks[j0 + 16 + lr][lg * 8];
      b0 = *(const bf16x8*)kp1;
      b1 = *(const bf16x8*)(kp1 + 32);
      s1 = __builtin_amdgcn_mfma_f32_16x16x32_bf16(aq0, b0, z, 0, 0, 0);
      s1 = __builtin_amdgcn_mfma_f32_16x16x32_bf16(aq1, b1, s1, 0, 0, 0);
    }
    const int jc0 = jg0 + lr;
    const int jc1 = jc0 + 16;
    float p0[4], p1[4], al[4];
#pragma unroll
    for (int r = 0; r < 4; ++r) {
      const int qg = qs + wq0 + lg * 4 + r;
      const bool v0 = (jc0 >= 0) & (jc0 <= qg) & (qg - jc0 <= 256);
      const bool v1 = (jc1 >= 0) & (jc1 <= qg) & (qg - jc1 <= 256);
      const float t0 = v0 ? s0[r] : -1e30f;
      const float t1 = v1 ? s1[r] : -1e30f;
      float mx = fmaxf(t0, t1);
      mx = fmaxf(mx, __shfl_xor(mx, 1));
      mx = fmaxf(mx, __shfl_xor(mx, 2));
      mx = fmaxf(mx, __shfl_xor(mx, 4));
      mx = fmaxf(mx, __shfl_xor(mx, 8));
      const float mn = fmaxf(m_[r], mx);
      if (mn < -1e29f) {
        al[r] = 1.f; p0[r] = 0.f; p1[r] = 0.f;
      } else {
        al[r] = __expf(m_[r] - mn);
        p0[r] = (t0 < -1e29f) ? 0.f : __expf(t0 - mn);
        p1[r] = (t1 < -1e29f) ? 0.f : __expf(t1 - mn);
      }
      m_[r] = mn;
      float rs = p0[r] + p1[r];
      rs += __shfl_xor(rs, 1);
      rs += __shfl_xor(rs, 2);
      rs += __shfl_xor(rs, 4);
      rs += __shfl_xor(rs, 8);
      ls[r] = ls[r] * al[r] + rs;
    }
#pragma unroll
    for (int r = 0; r < 4; ++r) {
      Pl[w][lg * 4 + r][lr] = f2bf(p0[r]);
      Pl[w][lg * 4 + r][lr + 16] = f2bf(p1[r]);
    }
    asm volatile("s_waitcnt lgkmcnt(0)" ::: "memory");
    const bf16x8 pa = *(const bf16x8*)(&Pl[w][lr][lg * 8]);
#pragma unroll
    for (int nt = 0; nt < 4; ++nt) {
      f32x4 oa = oacc[nt];
#pragma unroll
      for (int r = 0; r < 4; ++r) oa[r] *= al[r];
      const bf16x8 bv = *(const bf16x8*)(&Vt[nt * 16 + lr][j0 + lg * 8]);
      oacc[nt] = __builtin_amdgcn_mfma_f32_16x16x32_bf16(pa, bv, oa, 0, 0, 0);
    }
  }
#pragma unroll
  for (int nt = 0; nt < 4; ++nt)
#pragma unroll
    for (int r = 0; r < 4; ++r) {
      const long qg = qs + wq0 + lg * 4 + r;
      o[bh + qg * 1024 + nt * 16 + lr] = f2bf(oacc[nt][r] / ls[r]);
    }
}

// ------------- bf16 GEMM, B pre-transposed, f32 output, optional split-K via blockIdx.z -------------
// C[z][M,N] = A[M, koff:koff+Kl] * BT[N, koff:koff+Kl]^T, koff = z*Kl
__global__ __launch_bounds__(256) void gemm_bt(const u16* __restrict__ A,
                                               const u16* __restrict__ BT,
                                               float* __restrict__ Cf,
                                               int M, int N, int Kl, int lda, int ldb) {
  __shared__ __attribute__((aligned(16))) u16 As[128 * 32];
  __shared__ __attribute__((aligned(16))) u16 Bs[128 * 32];
  const int t = threadIdx.x;
  const int w = t >> 6, l = t & 63;
  const int lr = l & 15, lg = l >> 4;
  const int wm = (w >> 1) * 64, wn = (w & 1) * 64;
  const long m0 = (long)blockIdx.y * 128, n0 = (long)blockIdx.x * 128;
  const long koff = (long)blockIdx.z * Kl;
  Cf += (long)blockIdx.z * M * N;

  f32x4 acc[4][4];
#pragma unroll
  for (int i = 0; i < 4; ++i)
#pragma unroll
    for (int j = 0; j < 4; ++j) { acc[i][j][0] = 0.f; acc[i][j][1] = 0.f; acc[i][j][2] = 0.f; acc[i][j][3] = 0.f; }

  const int row0 = t >> 2, k80 = (t & 3) << 3;
  const int row1 = (256 + t) >> 2, k81 = ((256 + t) & 3) << 3;
  const u16* Ab = A + m0 * lda + koff;
  const u16* Bb = BT + n0 * ldb + koff;

  for (int kt = 0; kt < Kl; kt += 32) {
    __syncthreads();
    gload_lds16(Ab + (long)row0 * lda + kt + k80, (u16*)As + w * 512);
    gload_lds16(Ab + (long)row1 * lda + kt + k81, (u16*)As + 2048 + w * 512);
    gload_lds16(Bb + (long)row0 * ldb + kt + k80, (u16*)Bs + w * 512);
    gload_lds16(Bb + (long)row1 * ldb + kt + k81, (u16*)Bs + 2048 + w * 512);
    __syncthreads();
    bf16x8 af[4], bfr[4];
#pragma unroll
    for (int i = 0; i < 4; ++i)
      af[i] = *(const bf16x8*)(As + (wm + i * 16 + lr) * 32 + lg * 8);
#pragma unroll
    for (int j = 0; j < 4; ++j)
      bfr[j] = *(const bf16x8*)(Bs + (wn + j * 16 + lr) * 32 + lg * 8);
#pragma unroll
    for (int i = 0; i < 4; ++i)
#pragma unroll
      for (int j = 0; j < 4; ++j)
        acc[i][j] = __builtin_amdgcn_mfma_f32_16x16x32_bf16(af[i], bfr[j], acc[i][j], 0, 0, 0);
  }

#pragma unroll
  for (int i = 0; i < 4; ++i) {
    const long mr = m0 + wm + i * 16 + lg * 4;
#pragma unroll
    for (int j = 0; j < 4; ++j) {
      const long nc = n0 + wn + j * 16 + lr;
#pragma unroll
      for (int r = 0; r < 4; ++r)
        Cf[(mr + r) * N + nc] = acc[i][j][r];
    }
  }
}

// ------------- fused MLP dual GEMM: gated = (A*BgT+bg) * silu(A*BuT+bu), bf16 out -------------
__global__ __launch_bounds__(256) void gemm_mlp(const u16* __restrict__ A,
                                                const u16* __restrict__ BgT,
                                                const u16* __restrict__ BuT,
                                                const float* __restrict__ bg,
                                                const float* __restrict__ bu,
                                                u16* __restrict__ out,
                                                int N, int K) {
  __shared__ __attribute__((aligned(16))) u16 As[128 * 32];
  __shared__ __attribute__((aligned(16))) u16 Gs[128 * 32];
  __shared__ __attribute__((aligned(16))) u16 Us[128 * 32];
  const int t = threadIdx.x;
  const int w = t >> 6, l = t & 63;
  const int lr = l & 15, lg = l >> 4;
  const int wm = (w >> 1) * 64, wn = (w & 1) * 64;
  const long m0 = (long)blockIdx.y * 128, n0 = (long)blockIdx.x * 128;

  f32x4 ag[4][4], au[4][4];
#pragma unroll
  for (int i = 0; i < 4; ++i)
#pragma unroll
    for (int j = 0; j < 4; ++j) {
      ag[i][j][0] = 0.f; ag[i][j][1] = 0.f; ag[i][j][2] = 0.f; ag[i][j][3] = 0.f;
      au[i][j][0] = 0.f; au[i][j][1] = 0.f; au[i][j][2] = 0.f; au[i][j][3] = 0.f;
    }

  const int row0 = t >> 2, k80 = (t & 3) << 3;
  const int row1 = (256 + t) >> 2, k81 = ((256 + t) & 3) << 3;
  const u16* Ab = A + m0 * K;
  const u16* Gb = BgT + n0 * K;
  const u16* Ub = BuT + n0 * K;

  for (int kt = 0; kt < K; kt += 32) {
    __syncthreads();
    gload_lds16(Ab + (long)row0 * K + kt + k80, (u16*)As + w * 512);
    gload_lds16(Ab + (long)row1 * K + kt + k81, (u16*)As + 2048 + w * 512);
    gload_lds16(Gb + (long)row0 * K + kt + k80, (u16*)Gs + w * 512);
    gload_lds16(Gb + (long)row1 * K + kt + k81, (u16*)Gs + 2048 + w * 512);
    gload_lds16(Ub + (long)row0 * K + kt + k80, (u16*)Us + w * 512);
    gload_lds16(Ub + (long)row1 * K + kt + k81, (u16*)Us + 2048 + w * 512);
    __syncthreads();
    bf16x8 af[4], gf[4], uf[4];
#pragma unroll
    for (int i = 0; i < 4; ++i)
      af[i] = *(const bf16x8*)(As + (wm + i * 16 + lr) * 32 + lg * 8);
#pragma unroll
    for (int j = 0; j < 4; ++j) {
      gf[j] = *(const bf16x8*)(Gs + (wn + j * 16 + lr) * 32 + lg * 8);
      uf[j] = *(const bf16x8*)(Us + (wn + j * 16 + lr) * 32 + lg * 8);
    }
#pragma unroll
    for (int i = 0; i < 4; ++i)
#pragma unroll
      for (int j = 0; j < 4; ++j) {
        ag[i][j] = __builtin_amdgcn_mfma_f32_16x16x32_bf16(af[i], gf[j], ag[i][j], 0, 0, 0);
        au[i][j] = __builtin_amdgcn_mfma_f32_16x16x32_bf16(af[i], uf[j], au[i][j], 0, 0, 0);
      }
  }

#pragma unroll
  for (int i = 0; i < 4; ++i) {
    const long mr = m0 + wm + i * 16 + lg * 4;
#pragma unroll
    for (int j = 0; j < 4; ++j) {
      const long nc = n0 + wn + j * 16 + lr;
      const float bgv = bg[nc], buv = bu[nc];
#pragma unroll
      for (int r = 0; r < 4; ++r) {
        const float gv = ag[i][j][r] + bgv;
        const float uv = au[i][j][r] + buv;
        const float sg = 1.f / (1.f + __expf(-uv));
        out[(mr + r) * N + nc] = f2bf(gv * uv * sg);
      }
    }
  }
}

// ------------- split-K combine: out = p[0] + p[1] + res (+ bias), N=1024 -------------
__global__ __launch_bounds__(256) void combine_kernel(const float* __restrict__ p,
                                                      const float* __restrict__ res,
                                                      const float* __restrict__ bias,
                                                      float* __restrict__ out,
                                                      long total) {
  const long i = ((long)blockIdx.x * 256 + threadIdx.x) * 4;
  if (i >= total) return;
  const float4 a = *(const float4*)(p + i);
  const float4 b = *(const float4*)(p + total + i);
  const float4 r = *(const float4*)(res + i);
  float4 o;
  o.x = a.x + b.x + r.x;
  o.y = a.y + b.y + r.y;
  o.z = a.z + b.z + r.z;
  o.w = a.w + b.w + r.w;
  if (bias) {
    const float4 bb = *(const float4*)(bias + (int)(i & 1023));
    o.x += bb.x; o.y += bb.y; o.z += bb.z; o.w += bb.w;
  }
  *(float4*)(out + i) = o;
}

extern "C" void kernel_launch(void* const* d_in, const int* in_sizes, int n_in,
                              void* d_out, int out_size, void* d_ws, size_t ws_size,
                              hipStream_t stream) {
  (void)in_sizes; (void)n_in; (void)out_size; (void)ws_size;
  const float* x      = (const float*)d_in[0];
  const float* w_qkv  = (const float*)d_in[1];
  const float* w_out  = (const float*)d_in[2];
  const float* g1     = (const float*)d_in[3];
  const float* b1     = (const float*)d_in[4];
  const float* g2     = (const float*)d_in[5];
  const float* b2     = (const float*)d_in[6];
  const float* w_gate = (const float*)d_in[7];
  const float* b_gate = (const float*)d_in[8];
  const float* w_up   = (const float*)d_in[9];
  const float* b_up   = (const float*)d_in[10];
  const float* w_down = (const float*)d_in[11];
  const float* b_down = (const float*)d_in[12];
  float* out = (float*)d_out;

  const size_t MB = 1u << 20;
  char* ws = (char*)d_ws;
  u16*   y      = (u16*)(ws + 0 * MB);    // [4096][1024] bf16
  u16*   wqkvT  = (u16*)(ws + 8 * MB);    // [3072][1024]
  u16*   woutT  = (u16*)(ws + 14 * MB);   // [1024][1024]
  u16*   wgateT = (u16*)(ws + 16 * MB);   // [4096][1024]
  u16*   wupT   = (u16*)(ws + 24 * MB);   // [4096][1024]
  u16*   wdownT = (u16*)(ws + 32 * MB);   // [1024][4096]
  float* qkv    = (float*)(ws + 40 * MB); // [4096][3072] f32 (48MB), dead after rope
  float* part   = (float*)(ws + 40 * MB); // split-K partials [2][4096][1024] f32 (32MB), aliases qkv
  u16*   qr_    = (u16*)(ws + 88 * MB);   // [4096][1024]
  u16*   kr_    = (u16*)(ws + 96 * MB);
  u16*   vv_    = (u16*)(ws + 104 * MB);
  u16*   o_     = (u16*)(ws + 112 * MB);
  float* x1     = (float*)(ws + 120 * MB); // [4096][1024] f32 (16MB)
  u16*   gated  = (u16*)(ws + 88 * MB);    // [4096][4096] bf16, aliases qr/kr/vv/o (dead)

  const dim3 blk(256);
  // weight transposes (f32 [K,N] -> bf16 [N,K])
  transpose_bf16<<<dim3(3072 / 32, 1024 / 32), blk, 0, stream>>>(w_qkv, wqkvT, 1024, 3072);
  transpose_bf16<<<dim3(1024 / 32, 1024 / 32), blk, 0, stream>>>(w_out, woutT, 1024, 1024);
  transpose_bf16<<<dim3(4096 / 32, 1024 / 32), blk, 0, stream>>>(w_gate, wgateT, 1024, 4096);
  transpose_bf16<<<dim3(4096 / 32, 1024 / 32), blk, 0, stream>>>(w_up, wupT, 1024, 4096);
  transpose_bf16<<<dim3(1024 / 32, 4096 / 32), blk, 0, stream>>>(w_down, wdownT, 4096, 1024);

  // LN1
  ln_kernel<<<4096, blk, 0, stream>>>(x, g1, b1, y);
  // QKV projection (f32 out)
  gemm_bt<<<dim3(3072 / 128, 4096 / 128, 1), blk, 0, stream>>>(
      y, wqkvT, qkv, 4096, 3072, 1024, 1024, 1024);
  // RoPE + bf16 split
  rope_kernel<<<4096, blk, 0, stream>>>(qkv, qr_, kr_, vv_);
  // local-causal attention
  attn_kernel<<<1024, blk, 0, stream>>>(qr_, kr_, vv_, o_);
  // out-proj, split-K=2 (K=1024 -> 2x512), then combine with residual x -> x1
  gemm_bt<<<dim3(1024 / 128, 4096 / 128, 2), blk, 0, stream>>>(
      o_, woutT, part, 4096, 1024, 512, 1024, 1024);
  combine_kernel<<<4096, blk, 0, stream>>>(part, x, nullptr, x1, (long)4096 * 1024);
  // LN2
  ln_kernel<<<4096, blk, 0, stream>>>(x1, g2, b2, y);
  // fused gate/up dual GEMM -> gated (bf16)
  gemm_mlp<<<dim3(4096 / 128, 4096 / 128), blk, 0, stream>>>(
      y, wgateT, wupT, b_gate, b_up, gated, 4096, 1024);
  // down-proj, split-K=2 (K=4096 -> 2x2048), then combine with bias + residual x1 -> out
  gemm_bt<<<dim3(1024 / 128, 4096 / 128, 2), blk, 0, stream>>>(
      gated, wdownT, part, 4096, 1024, 2048, 4096, 4096);
  combine_kernel<<<4096, blk, 0, stream>>>(part, x1, b_down, out, (long)4096 * 1024);
}

// Round 4
// 361.300 us; speedup vs baseline: 1.2011x; 1.2011x over previous
//
#include <hip/hip_runtime.h>

typedef unsigned short u16;
typedef unsigned long long u64;
typedef __attribute__((ext_vector_type(8))) short bf16x8;
typedef __attribute__((ext_vector_type(4))) float f32x4;

__device__ inline u16 f2bf(float f) {
  unsigned int u = __float_as_uint(f);
  u += 0x7fffu + ((u >> 16) & 1u);
  return (u16)(u >> 16);
}
__device__ inline float bf2f(u16 h) { return __uint_as_float(((unsigned int)h) << 16); }

__device__ inline void gload_lds16(const void* gp, void* lp) {
  __builtin_amdgcn_global_load_lds(
      (const __attribute__((address_space(1))) unsigned int*)gp,
      (__attribute__((address_space(3))) unsigned int*)lp, 16, 0, 0);
}

// ---------------- LayerNorm: f32 [rows][1024] -> bf16 ----------------
__global__ __launch_bounds__(256) void ln_kernel(const float* __restrict__ x,
                                                 const float* __restrict__ g,
                                                 const float* __restrict__ beta,
                                                 u16* __restrict__ y) {
  __shared__ float red[8];
  const int row = blockIdx.x;
  const int t = threadIdx.x;
  const float4 xv = *(const float4*)(x + (long)row * 1024 + t * 4);
  float s = xv.x + xv.y + xv.z + xv.w;
  float sq = xv.x * xv.x + xv.y * xv.y + xv.z * xv.z + xv.w * xv.w;
#pragma unroll
  for (int d = 1; d < 64; d <<= 1) {
    s += __shfl_xor(s, d);
    sq += __shfl_xor(sq, d);
  }
  if ((t & 63) == 0) { red[t >> 6] = s; red[4 + (t >> 6)] = sq; }
  __syncthreads();
  s = red[0] + red[1] + red[2] + red[3];
  sq = red[4] + red[5] + red[6] + red[7];
  const float mean = s * (1.f / 1024.f);
  const float var = sq * (1.f / 1024.f) - mean * mean;
  const float inv = rsqrtf(var + 1e-5f);
  float xe[4] = {xv.x, xv.y, xv.z, xv.w};
  u16 ov[4];
#pragma unroll
  for (int e = 0; e < 4; ++e)
    ov[e] = f2bf((xe[e] - mean) * inv * g[t * 4 + e] + beta[t * 4 + e]);
  *(u64*)(y + (long)row * 1024 + t * 4) = *(u64*)ov;
}

// ------------- transpose + convert: f32 in[R][C] -> bf16 out[C][R] -------------
// 64(r) x 32(c) tile: 128B coalesced reads AND 128B coalesced bf16 writes
__global__ __launch_bounds__(256) void transpose_bf16(const float* __restrict__ in,
                                                      u16* __restrict__ out,
                                                      int R, int C) {
  __shared__ float tile[64][33];
  const int t = threadIdx.x;
  const int tx = t & 31, ty = t >> 5;        // read: 32 cols x 8 rows
  const int rx = t & 63, cy = t >> 6;        // write: 64 rows x 4 cols
  const long r0 = (long)blockIdx.y * 64, c0 = (long)blockIdx.x * 32;
#pragma unroll
  for (int i = 0; i < 8; ++i)
    tile[ty + i * 8][tx] = in[(r0 + ty + i * 8) * C + c0 + tx];
  __syncthreads();
#pragma unroll
  for (int i = 0; i < 8; ++i)
    out[(c0 + i * 4 + cy) * R + r0 + rx] = f2bf(tile[rx][i * 4 + cy]);
}

// ------------- RoPE + split: qkv bf16 [rows][3072] -> q,k (rotated, q scaled), v bf16 -------------
__global__ __launch_bounds__(256) void rope_kernel(const u16* __restrict__ qkv,
                                                   u16* __restrict__ qr,
                                                   u16* __restrict__ kr,
                                                   u16* __restrict__ vv) {
  const int row = blockIdx.x;            // b*2048 + s
  const int s = row & 2047;
  const int t = threadIdx.x;
  const u16* base = qkv + (long)row * 3072;
  const long orow = (long)row * 1024;
#pragma unroll
  for (int rep = 0; rep < 2; ++rep) {
    const int p = rep * 256 + t;         // 0..511 : h*32 + d0
    const int h = p >> 5, d0 = p & 31;
    const float inv = exp2f((float)d0 * (-13.287712379549449f / 32.f));
    const float ang = (float)s * inv;
    float sn, cs;
    sincosf(ang, &sn, &cs);
    const int c1 = h * 64 + d0, c2 = c1 + 32;
    float x1 = bf2f(base[c1]), x2 = bf2f(base[c2]);
    qr[orow + c1] = f2bf((x1 * cs - x2 * sn) * 0.125f);   // fold hd^-0.5
    qr[orow + c2] = f2bf((x2 * cs + x1 * sn) * 0.125f);
    float y1 = bf2f(base[1024 + c1]), y2 = bf2f(base[1024 + c2]);
    kr[orow + c1] = f2bf(y1 * cs - y2 * sn);
    kr[orow + c2] = f2bf(y2 * cs + y1 * sn);
  }
  // v: plain copy, vectorized 4 u16 per thread
  *(u64*)(vv + orow + t * 4) = *(const u64*)(base + 2048 + t * 4);
}

// ------------- local-causal flash attention, window 256, hd=64, H=16 -------------
__global__ __launch_bounds__(256) void attn_kernel(const u16* __restrict__ qr,
                                                   const u16* __restrict__ kr,
                                                   const u16* __restrict__ vv,
                                                   u16* __restrict__ o) {
  __shared__ __attribute__((aligned(16))) u16 Ks[320][72];
  __shared__ __attribute__((aligned(16))) u16 Vt[64][336];
  __shared__ __attribute__((aligned(16))) u16 Pl[4][16][40];

  const int blk = blockIdx.x;
  const int qt = blk & 31;
  const int h = (blk >> 5) & 15;
  const int b = blk >> 9;
  const int qs = qt * 64;
  const int jbase = qs - 256;
  const int t = threadIdx.x;
  const int w = t >> 6, l = t & 63;
  const int lr = l & 15, lg = l >> 4;
  const long bh = (long)b * 2048 * 1024 + h * 64;

#pragma unroll
  for (int it = 0; it < 10; ++it) {
    const int c = it * 256 + t;
    const int jj = c >> 3, c8 = c & 7;
    const int jg = jbase + jj;
    bf16x8 val;
#pragma unroll
    for (int e = 0; e < 8; ++e) val[e] = 0;
    if (jg >= 0) val = *(const bf16x8*)(kr + bh + (long)jg * 1024 + c8 * 8);
    *(bf16x8*)(&Ks[jj][c8 * 8]) = val;
  }
#pragma unroll
  for (int it = 0; it < 10; ++it) {
    const int c = it * 256 + t;
    const int jj = c % 320, c8 = c / 320;
    const int jg = jbase + jj;
    if (jg >= 0) {
      bf16x8 val = *(const bf16x8*)(vv + bh + (long)jg * 1024 + c8 * 8);
#pragma unroll
      for (int e = 0; e < 8; ++e) Vt[c8 * 8 + e][jj] = (u16)val[e];
    } else {
#pragma unroll
      for (int e = 0; e < 8; ++e) Vt[c8 * 8 + e][jj] = 0;
    }
  }

  const int wq0 = w * 16;
  const u16* qp = qr + bh + (long)(qs + wq0 + lr) * 1024 + lg * 8;
  const bf16x8 aq0 = *(const bf16x8*)qp;
  const bf16x8 aq1 = *(const bf16x8*)(qp + 32);

  __syncthreads();

  f32x4 oacc[4];
#pragma unroll
  for (int nt = 0; nt < 4; ++nt) { oacc[nt][0] = 0.f; oacc[nt][1] = 0.f; oacc[nt][2] = 0.f; oacc[nt][3] = 0.f; }
  float m_[4], ls[4];
#pragma unroll
  for (int r = 0; r < 4; ++r) { m_[r] = -1e30f; ls[r] = 0.f; }

  const int qmaxw = qs + wq0 + 15;
  for (int ch = 0; ch < 10; ++ch) {
    const int j0 = ch * 32;
    const int jg0 = jbase + j0;
    if (jg0 + 31 < 0) continue;
    if (jg0 > qmaxw) break;

    f32x4 s0, s1;
    {
      f32x4 z; z[0] = z[1] = z[2] = z[3] = 0.f;
      const u16* kp0 = &Ks[j0 + lr][lg * 8];
      bf16x8 b0 = *(const bf16x8*)kp0;
      bf16x8 b1 = *(const bf16x8*)(kp0 + 32);
      s0 = __builtin_amdgcn_mfma_f32_16x16x32_bf16(aq0, b0, z, 0, 0, 0);
      s0 = __builtin_amdgcn_mfma_f32_16x16x32_bf16(aq1, b1, s0, 0, 0, 0);
      const u16* kp1 = &Ks[j0 + 16 + lr][lg * 8];
      b0 = *(const bf16x8*)kp1;
      b1 = *(const bf16x8*)(kp1 + 32);
      s1 = __builtin_amdgcn_mfma_f32_16x16x32_bf16(aq0, b0, z, 0, 0, 0);
      s1 = __builtin_amdgcn_mfma_f32_16x16x32_bf16(aq1, b1, s1, 0, 0, 0);
    }
    const int jc0 = jg0 + lr;
    const int jc1 = jc0 + 16;
    float p0[4], p1[4], al[4];
#pragma unroll
    for (int r = 0; r < 4; ++r) {
      const int qg = qs + wq0 + lg * 4 + r;
      const bool v0 = (jc0 >= 0) & (jc0 <= qg) & (qg - jc0 <= 256);
      const bool v1 = (jc1 >= 0) & (jc1 <= qg) & (qg - jc1 <= 256);
      const float t0 = v0 ? s0[r] : -1e30f;
      const float t1 = v1 ? s1[r] : -1e30f;
      float mx = fmaxf(t0, t1);
      mx = fmaxf(mx, __shfl_xor(mx, 1));
      mx = fmaxf(mx, __shfl_xor(mx, 2));
      mx = fmaxf(mx, __shfl_xor(mx, 4));
      mx = fmaxf(mx, __shfl_xor(mx, 8));
      const float mn = fmaxf(m_[r], mx);
      if (mn < -1e29f) {
        al[r] = 1.f; p0[r] = 0.f; p1[r] = 0.f;
      } else {
        al[r] = __expf(m_[r] - mn);
        p0[r] = (t0 < -1e29f) ? 0.f : __expf(t0 - mn);
        p1[r] = (t1 < -1e29f) ? 0.f : __expf(t1 - mn);
      }
      m_[r] = mn;
      float rs = p0[r] + p1[r];
      rs += __shfl_xor(rs, 1);
      rs += __shfl_xor(rs, 2);
      rs += __shfl_xor(rs, 4);
      rs += __shfl_xor(rs, 8);
      ls[r] = ls[r] * al[r] + rs;
    }
#pragma unroll
    for (int r = 0; r < 4; ++r) {
      Pl[w][lg * 4 + r][lr] = f2bf(p0[r]);
      Pl[w][lg * 4 + r][lr + 16] = f2bf(p1[r]);
    }
    asm volatile("s_waitcnt lgkmcnt(0)" ::: "memory");
    const bf16x8 pa = *(const bf16x8*)(&Pl[w][lr][lg * 8]);
#pragma unroll
    for (int nt = 0; nt < 4; ++nt) {
      f32x4 oa = oacc[nt];
#pragma unroll
      for (int r = 0; r < 4; ++r) oa[r] *= al[r];
      const bf16x8 bv = *(const bf16x8*)(&Vt[nt * 16 + lr][j0 + lg * 8]);
      oacc[nt] = __builtin_amdgcn_mfma_f32_16x16x32_bf16(pa, bv, oa, 0, 0, 0);
    }
  }
#pragma unroll
  for (int nt = 0; nt < 4; ++nt)
#pragma unroll
    for (int r = 0; r < 4; ++r) {
      const long qg = qs + wq0 + lg * 4 + r;
      o[bh + qg * 1024 + nt * 16 + lr] = f2bf(oacc[nt][r] / ls[r]);
    }
}

// ------------- bf16 GEMM, B pre-transposed, 2-phase double-buffered LDS -------------
// EPI: 0=f32 store (split-K partials via blockIdx.z), 1=f32 +res,
//      2=bf16 +bias, 3=bf16 gate*silu(acc+bias), 5=bf16 plain
template <int EPI>
__global__ __launch_bounds__(256) void gemm_bt(const u16* __restrict__ A,
                                               const u16* __restrict__ BT,
                                               float* __restrict__ Cf,
                                               u16* __restrict__ Cb,
                                               const float* __restrict__ bias,
                                               const float* __restrict__ res,
                                               const u16* __restrict__ gate,
                                               int M, int N, int Kl, int lda, int ldb) {
  __shared__ __attribute__((aligned(16))) u16 As[2][128 * 32];
  __shared__ __attribute__((aligned(16))) u16 Bs[2][128 * 32];
  const int t = threadIdx.x;
  const int w = t >> 6, l = t & 63;
  const int lr = l & 15, lg = l >> 4;
  const int wm = (w >> 1) * 64, wn = (w & 1) * 64;
  const long m0 = (long)blockIdx.y * 128, n0 = (long)blockIdx.x * 128;
  const long koff = (long)blockIdx.z * Kl;
  if constexpr (EPI == 0) Cf += (long)blockIdx.z * M * N;

  f32x4 acc[4][4];
#pragma unroll
  for (int i = 0; i < 4; ++i)
#pragma unroll
    for (int j = 0; j < 4; ++j) { acc[i][j][0] = 0.f; acc[i][j][1] = 0.f; acc[i][j][2] = 0.f; acc[i][j][3] = 0.f; }

  const int row0 = t >> 2, k80 = (t & 3) << 3;
  const int row1 = (256 + t) >> 2, k81 = ((256 + t) & 3) << 3;
  const u16* Ab = A + m0 * lda + koff;
  const u16* Bb = BT + n0 * ldb + koff;

  // stage tile 0 into buffer 0
  gload_lds16(Ab + (long)row0 * lda + k80, (u16*)As[0] + w * 512);
  gload_lds16(Ab + (long)row1 * lda + k81, (u16*)As[0] + 2048 + w * 512);
  gload_lds16(Bb + (long)row0 * ldb + k80, (u16*)Bs[0] + w * 512);
  gload_lds16(Bb + (long)row1 * ldb + k81, (u16*)Bs[0] + 2048 + w * 512);
  __syncthreads();

  int cur = 0;
  for (int kt = 0; kt < Kl; kt += 32) {
    // prefetch next tile into the other buffer (overlaps with MFMA below)
    if (kt + 32 < Kl) {
      const int nxt = cur ^ 1;
      gload_lds16(Ab + (long)row0 * lda + kt + 32 + k80, (u16*)As[nxt] + w * 512);
      gload_lds16(Ab + (long)row1 * lda + kt + 32 + k81, (u16*)As[nxt] + 2048 + w * 512);
      gload_lds16(Bb + (long)row0 * ldb + kt + 32 + k80, (u16*)Bs[nxt] + w * 512);
      gload_lds16(Bb + (long)row1 * ldb + kt + 32 + k81, (u16*)Bs[nxt] + 2048 + w * 512);
    }
    bf16x8 af[4], bfr[4];
#pragma unroll
    for (int i = 0; i < 4; ++i)
      af[i] = *(const bf16x8*)(As[cur] + (wm + i * 16 + lr) * 32 + lg * 8);
#pragma unroll
    for (int j = 0; j < 4; ++j)
      bfr[j] = *(const bf16x8*)(Bs[cur] + (wn + j * 16 + lr) * 32 + lg * 8);
#pragma unroll
    for (int i = 0; i < 4; ++i)
#pragma unroll
      for (int j = 0; j < 4; ++j)
        acc[i][j] = __builtin_amdgcn_mfma_f32_16x16x32_bf16(af[i], bfr[j], acc[i][j], 0, 0, 0);
    __syncthreads();   // implicit vmcnt drain: prefetch had the whole MFMA block to land
    cur ^= 1;
  }

#pragma unroll
  for (int i = 0; i < 4; ++i) {
    const long mr = m0 + wm + i * 16 + lg * 4;
#pragma unroll
    for (int j = 0; j < 4; ++j) {
      const long nc = n0 + wn + j * 16 + lr;
#pragma unroll
      for (int r = 0; r < 4; ++r) {
        const long idx = (mr + r) * N + nc;
        const float v = acc[i][j][r];
        if constexpr (EPI == 0) {
          Cf[idx] = v;
        } else if constexpr (EPI == 1) {
          Cf[idx] = v + res[idx];
        } else if constexpr (EPI == 2) {
          Cb[idx] = f2bf(v + bias[nc]);
        } else if constexpr (EPI == 3) {
          const float u = v + bias[nc];
          const float sg = 1.f / (1.f + __expf(-u));
          Cb[idx] = f2bf(bf2f(gate[idx]) * u * sg);
        } else {
          Cb[idx] = f2bf(v);
        }
      }
    }
  }
}

// ------------- split-K combine: out = p[0] + p[1] + res (+ bias), N=1024 -------------
__global__ __launch_bounds__(256) void combine_kernel(const float* __restrict__ p,
                                                      const float* __restrict__ res,
                                                      const float* __restrict__ bias,
                                                      float* __restrict__ out,
                                                      long total) {
  const long i = ((long)blockIdx.x * 256 + threadIdx.x) * 4;
  if (i >= total) return;
  const float4 a = *(const float4*)(p + i);
  const float4 b = *(const float4*)(p + total + i);
  const float4 r = *(const float4*)(res + i);
  float4 o;
  o.x = a.x + b.x + r.x;
  o.y = a.y + b.y + r.y;
  o.z = a.z + b.z + r.z;
  o.w = a.w + b.w + r.w;
  if (bias) {
    const float4 bb = *(const float4*)(bias + (int)(i & 1023));
    o.x += bb.x; o.y += bb.y; o.z += bb.z; o.w += bb.w;
  }
  *(float4*)(out + i) = o;
}

extern "C" void kernel_launch(void* const* d_in, const int* in_sizes, int n_in,
                              void* d_out, int out_size, void* d_ws, size_t ws_size,
                              hipStream_t stream) {
  (void)in_sizes; (void)n_in; (void)out_size; (void)ws_size;
  const float* x      = (const float*)d_in[0];
  const float* w_qkv  = (const float*)d_in[1];
  const float* w_out  = (const float*)d_in[2];
  const float* g1     = (const float*)d_in[3];
  const float* b1     = (const float*)d_in[4];
  const float* g2     = (const float*)d_in[5];
  const float* b2     = (const float*)d_in[6];
  const float* w_gate = (const float*)d_in[7];
  const float* b_gate = (const float*)d_in[8];
  const float* w_up   = (const float*)d_in[9];
  const float* b_up   = (const float*)d_in[10];
  const float* w_down = (const float*)d_in[11];
  const float* b_down = (const float*)d_in[12];
  float* out = (float*)d_out;

  const size_t MB = 1u << 20;
  char* ws = (char*)d_ws;
  u16*   y      = (u16*)(ws + 0 * MB);    // [4096][1024] bf16
  u16*   wqkvT  = (u16*)(ws + 8 * MB);    // [3072][1024]
  u16*   woutT  = (u16*)(ws + 14 * MB);   // [1024][1024]
  u16*   wgateT = (u16*)(ws + 16 * MB);   // [4096][1024]
  u16*   wupT   = (u16*)(ws + 24 * MB);   // [4096][1024]
  u16*   wdownT = (u16*)(ws + 32 * MB);   // [1024][4096]
  u16*   qkv    = (u16*)(ws + 40 * MB);   // [4096][3072] bf16 (24MB), dead after rope
  u16*   gbuf   = (u16*)(ws + 40 * MB);   // gate bf16 [4096][4096] (32MB), alias qkv; dead after up-GEMM
  float* part   = (float*)(ws + 40 * MB); // down split-K partials [2][4096][1024] f32 (32MB), after up-GEMM
  u16*   qr_    = (u16*)(ws + 88 * MB);   // [4096][1024]
  u16*   kr_    = (u16*)(ws + 96 * MB);
  u16*   vv_    = (u16*)(ws + 104 * MB);
  u16*   o_     = (u16*)(ws + 112 * MB);
  float* x1     = (float*)(ws + 120 * MB); // [4096][1024] f32 (16MB)
  u16*   gated  = (u16*)(ws + 88 * MB);    // [4096][4096] bf16, aliases qr/kr/vv/o (dead)

  const dim3 blk(256);
  // weight transposes (f32 [K,N] -> bf16 [N,K])
  transpose_bf16<<<dim3(3072 / 32, 1024 / 64), blk, 0, stream>>>(w_qkv, wqkvT, 1024, 3072);
  transpose_bf16<<<dim3(1024 / 32, 1024 / 64), blk, 0, stream>>>(w_out, woutT, 1024, 1024);
  transpose_bf16<<<dim3(4096 / 32, 1024 / 64), blk, 0, stream>>>(w_gate, wgateT, 1024, 4096);
  transpose_bf16<<<dim3(4096 / 32, 1024 / 64), blk, 0, stream>>>(w_up, wupT, 1024, 4096);
  transpose_bf16<<<dim3(1024 / 32, 4096 / 64), blk, 0, stream>>>(w_down, wdownT, 4096, 1024);

  // LN1
  ln_kernel<<<4096, blk, 0, stream>>>(x, g1, b1, y);
  // QKV projection (bf16 out)
  gemm_bt<5><<<dim3(3072 / 128, 4096 / 128, 1), blk, 0, stream>>>(
      y, wqkvT, nullptr, qkv, nullptr, nullptr, nullptr, 4096, 3072, 1024, 1024, 1024);
  // RoPE + split
  rope_kernel<<<4096, blk, 0, stream>>>(qkv, qr_, kr_, vv_);
  // local-causal attention
  attn_kernel<<<1024, blk, 0, stream>>>(qr_, kr_, vv_, o_);
  // out-proj + residual (f32), plain
  gemm_bt<1><<<dim3(1024 / 128, 4096 / 128, 1), blk, 0, stream>>>(
      o_, woutT, x1, nullptr, nullptr, x, nullptr, 4096, 1024, 1024, 1024, 1024);
  // LN2
  ln_kernel<<<4096, blk, 0, stream>>>(x1, g2, b2, y);
  // gate = y*w_gate + b_gate (bf16)
  gemm_bt<2><<<dim3(4096 / 128, 4096 / 128, 1), blk, 0, stream>>>(
      y, wgateT, nullptr, gbuf, b_gate, nullptr, nullptr, 4096, 4096, 1024, 1024, 1024);
  // gated = gate * silu(y*w_up + b_up) (bf16)
  gemm_bt<3><<<dim3(4096 / 128, 4096 / 128, 1), blk, 0, stream>>>(
      y, wupT, nullptr, gated, b_up, nullptr, gbuf, 4096, 4096, 1024, 1024, 1024);
  // down-proj, split-K=2 (K=4096 -> 2x2048), then combine with bias + residual x1 -> out
  gemm_bt<0><<<dim3(1024 / 128, 4096 / 128, 2), blk, 0, stream>>>(
      gated, wdownT, part, nullptr, nullptr, nullptr, nullptr, 4096, 1024, 2048, 4096, 4096);
  combine_kernel<<<4096, blk, 0, stream>>>(part, x1, b_down, out, (long)4096 * 1024);
}

// Round 5
// 325.483 us; speedup vs baseline: 1.3333x; 1.1100x over previous
//
#include <hip/hip_runtime.h>

typedef unsigned short u16;
typedef unsigned long long u64;
typedef __attribute__((ext_vector_type(8))) short bf16x8;
typedef __attribute__((ext_vector_type(4))) float f32x4;

__device__ inline u16 f2bf(float f) {
  unsigned int u = __float_as_uint(f);
  u += 0x7fffu + ((u >> 16) & 1u);
  return (u16)(u >> 16);
}
__device__ inline float bf2f(u16 h) { return __uint_as_float(((unsigned int)h) << 16); }

__device__ inline void gload_lds16(const void* gp, void* lp) {
  __builtin_amdgcn_global_load_lds(
      (const __attribute__((address_space(1))) unsigned int*)gp,
      (__attribute__((address_space(3))) unsigned int*)lp, 16, 0, 0);
}

// ---------------- LayerNorm: f32 [rows][1024] -> bf16 ----------------
__global__ __launch_bounds__(256) void ln_kernel(const float* __restrict__ x,
                                                 const float* __restrict__ g,
                                                 const float* __restrict__ beta,
                                                 u16* __restrict__ y) {
  __shared__ float red[8];
  const int row = blockIdx.x;
  const int t = threadIdx.x;
  const float4 xv = *(const float4*)(x + (long)row * 1024 + t * 4);
  float s = xv.x + xv.y + xv.z + xv.w;
  float sq = xv.x * xv.x + xv.y * xv.y + xv.z * xv.z + xv.w * xv.w;
#pragma unroll
  for (int d = 1; d < 64; d <<= 1) {
    s += __shfl_xor(s, d);
    sq += __shfl_xor(sq, d);
  }
  if ((t & 63) == 0) { red[t >> 6] = s; red[4 + (t >> 6)] = sq; }
  __syncthreads();
  s = red[0] + red[1] + red[2] + red[3];
  sq = red[4] + red[5] + red[6] + red[7];
  const float mean = s * (1.f / 1024.f);
  const float var = sq * (1.f / 1024.f) - mean * mean;
  const float inv = rsqrtf(var + 1e-5f);
  float xe[4] = {xv.x, xv.y, xv.z, xv.w};
  u16 ov[4];
#pragma unroll
  for (int e = 0; e < 4; ++e)
    ov[e] = f2bf((xe[e] - mean) * inv * g[t * 4 + e] + beta[t * 4 + e]);
  *(u64*)(y + (long)row * 1024 + t * 4) = *(u64*)ov;
}

// ------------- transpose + convert: f32 in[R][C] -> bf16 out[C][R] -------------
__global__ __launch_bounds__(256) void transpose_bf16(const float* __restrict__ in,
                                                      u16* __restrict__ out,
                                                      int R, int C) {
  __shared__ float tile[64][33];
  const int t = threadIdx.x;
  const int tx = t & 31, ty = t >> 5;        // read: 32 cols x 8 rows
  const int rx = t & 63, cy = t >> 6;        // write: 64 rows x 4 cols
  const long r0 = (long)blockIdx.y * 64, c0 = (long)blockIdx.x * 32;
#pragma unroll
  for (int i = 0; i < 8; ++i)
    tile[ty + i * 8][tx] = in[(r0 + ty + i * 8) * C + c0 + tx];
  __syncthreads();
#pragma unroll
  for (int i = 0; i < 8; ++i)
    out[(c0 + i * 4 + cy) * R + r0 + rx] = f2bf(tile[rx][i * 4 + cy]);
}

// ------------- V transpose: vv bf16 [b*2048+s][1024] -> vt [bh][64][2048] -------------
__global__ __launch_bounds__(256) void transpose_v(const u16* __restrict__ vv,
                                                   u16* __restrict__ vt) {
  __shared__ u16 tile[64][72];
  const int bh = blockIdx.y;            // b*16+h
  const long s0 = (long)blockIdx.x * 64;
  const int t = threadIdx.x;
  const int r = t >> 3, cc = (t & 7) * 8;   // r: 0..31
  const long src = ((long)(bh >> 4) * 2048 + s0) * 1024 + (bh & 15) * 64;
  *(bf16x8*)&tile[r][cc] = *(const bf16x8*)(vv + src + (long)r * 1024 + cc);
  *(bf16x8*)&tile[r + 32][cc] = *(const bf16x8*)(vv + src + (long)(r + 32) * 1024 + cc);
  __syncthreads();
  const int d = t >> 3, sx = (t & 7) * 8;   // d: 0..31
  u16 o0[8], o1[8];
#pragma unroll
  for (int e = 0; e < 8; ++e) { o0[e] = tile[sx + e][d]; o1[e] = tile[sx + e][d + 32]; }
  const long dst = (long)bh * 64 * 2048 + s0;
  *(bf16x8*)(vt + dst + (long)d * 2048 + sx) = *(bf16x8*)o0;
  *(bf16x8*)(vt + dst + (long)(d + 32) * 2048 + sx) = *(bf16x8*)o1;
}

// ------------- RoPE + split: qkv bf16 [rows][3072] -> q,k (rotated, q scaled), v bf16 -------------
__global__ __launch_bounds__(256) void rope_kernel(const u16* __restrict__ qkv,
                                                   u16* __restrict__ qr,
                                                   u16* __restrict__ kr,
                                                   u16* __restrict__ vv) {
  const int row = blockIdx.x;            // b*2048 + s
  const int s = row & 2047;
  const int t = threadIdx.x;
  const u16* base = qkv + (long)row * 3072;
  const long orow = (long)row * 1024;
#pragma unroll
  for (int rep = 0; rep < 2; ++rep) {
    const int p = rep * 256 + t;         // 0..511 : h*32 + d0
    const int h = p >> 5, d0 = p & 31;
    const float inv = exp2f((float)d0 * (-13.287712379549449f / 32.f));
    const float ang = (float)s * inv;
    float sn, cs;
    sincosf(ang, &sn, &cs);
    const int c1 = h * 64 + d0, c2 = c1 + 32;
    float x1 = bf2f(base[c1]), x2 = bf2f(base[c2]);
    qr[orow + c1] = f2bf((x1 * cs - x2 * sn) * 0.125f);   // fold hd^-0.5
    qr[orow + c2] = f2bf((x2 * cs + x1 * sn) * 0.125f);
    float y1 = bf2f(base[1024 + c1]), y2 = bf2f(base[1024 + c2]);
    kr[orow + c1] = f2bf(y1 * cs - y2 * sn);
    kr[orow + c2] = f2bf(y2 * cs + y1 * sn);
  }
  *(u64*)(vv + orow + t * 4) = *(const u64*)(base + 2048 + t * 4);
}

// ------------- local-causal flash attention, window 256, hd=64, H=16 -------------
// 1 wave per block, 16 queries; K and V^T read directly from global (L2-resident)
__global__ __launch_bounds__(64, 4) void attn_kernel(const u16* __restrict__ qr,
                                                     const u16* __restrict__ kr,
                                                     const u16* __restrict__ vt,
                                                     u16* __restrict__ o) {
  __shared__ __attribute__((aligned(16))) u16 Pl[16][40];
  int wg = blockIdx.x;                       // 4096 blocks
  wg = (wg & 7) * 512 + (wg >> 3);           // XCD-contiguous swizzle
  const int qt = wg & 127;
  const int bh = wg >> 7;                    // b*16+h
  const int qs = qt * 16;
  const int l = threadIdx.x;
  const int lr = l & 15, lg = l >> 4;
  const long bho = (long)(bh >> 4) * 2048 * 1024 + (long)(bh & 15) * 64;
  const long vtb = (long)bh * 64 * 2048;

  const u16* qp = qr + bho + (long)(qs + lr) * 1024 + lg * 8;
  const bf16x8 aq0 = *(const bf16x8*)qp;
  const bf16x8 aq1 = *(const bf16x8*)(qp + 32);

  f32x4 oacc[4];
#pragma unroll
  for (int nt = 0; nt < 4; ++nt) { oacc[nt][0] = 0.f; oacc[nt][1] = 0.f; oacc[nt][2] = 0.f; oacc[nt][3] = 0.f; }
  float m_[4], ls[4];
#pragma unroll
  for (int r = 0; r < 4; ++r) { m_[r] = -1e30f; ls[r] = 0.f; }

  for (int ch = 0; ch < 9; ++ch) {
    const int j0 = qs - 256 + ch * 32;
    if (j0 + 32 <= 0) continue;              // entire chunk below j=0

    // K fragments direct from global (clamped rows; invalid j masked below)
    const int jc0u = j0 + lr;
    const int jc1u = j0 + 16 + lr;
    const int jc0 = min(max(jc0u, 0), 2047);
    const int jc1 = min(max(jc1u, 0), 2047);
    const u16* kp0 = kr + bho + (long)jc0 * 1024 + lg * 8;
    const u16* kp1 = kr + bho + (long)jc1 * 1024 + lg * 8;
    const bf16x8 b00 = *(const bf16x8*)kp0;
    const bf16x8 b01 = *(const bf16x8*)(kp0 + 32);
    const bf16x8 b10 = *(const bf16x8*)kp1;
    const bf16x8 b11 = *(const bf16x8*)(kp1 + 32);

    f32x4 z; z[0] = 0.f; z[1] = 0.f; z[2] = 0.f; z[3] = 0.f;
    f32x4 s0 = __builtin_amdgcn_mfma_f32_16x16x32_bf16(aq0, b00, z, 0, 0, 0);
    s0 = __builtin_amdgcn_mfma_f32_16x16x32_bf16(aq1, b01, s0, 0, 0, 0);
    f32x4 s1 = __builtin_amdgcn_mfma_f32_16x16x32_bf16(aq0, b10, z, 0, 0, 0);
    s1 = __builtin_amdgcn_mfma_f32_16x16x32_bf16(aq1, b11, s1, 0, 0, 0);

    float p0[4], p1[4], al[4];
#pragma unroll
    for (int r = 0; r < 4; ++r) {
      const int qg = qs + lg * 4 + r;
      const bool v0 = (jc0u >= 0) & (jc0u <= qg) & (qg - jc0u <= 256);
      const bool v1 = (jc1u >= 0) & (jc1u <= qg) & (qg - jc1u <= 256);
      const float t0 = v0 ? s0[r] : -1e30f;
      const float t1 = v1 ? s1[r] : -1e30f;
      float mx = fmaxf(t0, t1);
      mx = fmaxf(mx, __shfl_xor(mx, 1));
      mx = fmaxf(mx, __shfl_xor(mx, 2));
      mx = fmaxf(mx, __shfl_xor(mx, 4));
      mx = fmaxf(mx, __shfl_xor(mx, 8));
      const float mn = fmaxf(m_[r], mx);
      if (mn < -1e29f) {
        al[r] = 1.f; p0[r] = 0.f; p1[r] = 0.f;
      } else {
        al[r] = __expf(m_[r] - mn);
        p0[r] = (t0 < -1e29f) ? 0.f : __expf(t0 - mn);
        p1[r] = (t1 < -1e29f) ? 0.f : __expf(t1 - mn);
      }
      m_[r] = mn;
      float rs = p0[r] + p1[r];
      rs += __shfl_xor(rs, 1);
      rs += __shfl_xor(rs, 2);
      rs += __shfl_xor(rs, 4);
      rs += __shfl_xor(rs, 8);
      ls[r] = ls[r] * al[r] + rs;
    }
#pragma unroll
    for (int r = 0; r < 4; ++r) {
      Pl[lg * 4 + r][lr] = f2bf(p0[r]);
      Pl[lg * 4 + r][lr + 16] = f2bf(p1[r]);
    }
    asm volatile("s_waitcnt lgkmcnt(0)" ::: "memory");
    const bf16x8 pa = *(const bf16x8*)(&Pl[lr][lg * 8]);

    // V^T fragments direct from global: row d = nt*16+lr, cols j0+lg*8..+8
    const int jb = min(max(j0 + lg * 8, 0), 2040);
    const u16* vp = vt + vtb + (long)lr * 2048 + jb;
#pragma unroll
    for (int nt = 0; nt < 4; ++nt) {
      const bf16x8 bv = *(const bf16x8*)(vp + (long)(nt * 16) * 2048);
      f32x4 oa = oacc[nt];
#pragma unroll
      for (int r = 0; r < 4; ++r) oa[r] *= al[r];
      oacc[nt] = __builtin_amdgcn_mfma_f32_16x16x32_bf16(pa, bv, oa, 0, 0, 0);
    }
  }
#pragma unroll
  for (int nt = 0; nt < 4; ++nt)
#pragma unroll
    for (int r = 0; r < 4; ++r) {
      const long qg = qs + lg * 4 + r;
      o[bho + qg * 1024 + nt * 16 + lr] = f2bf(oacc[nt][r] / ls[r]);
    }
}

// ------------- bf16 GEMM, B pre-transposed, 2-phase double-buffered LDS -------------
// EPI: 0=f32 store (split-K partials via blockIdx.z), 1=f32 +res,
//      2=bf16 +bias, 3=bf16 gate*silu(acc+bias), 5=bf16 plain
template <int EPI>
__global__ __launch_bounds__(256) void gemm_bt(const u16* __restrict__ A,
                                               const u16* __restrict__ BT,
                                               float* __restrict__ Cf,
                                               u16* __restrict__ Cb,
                                               const float* __restrict__ bias,
                                               const float* __restrict__ res,
                                               const u16* __restrict__ gate,
                                               int M, int N, int Kl, int lda, int ldb) {
  __shared__ __attribute__((aligned(16))) u16 As[2][128 * 32];
  __shared__ __attribute__((aligned(16))) u16 Bs[2][128 * 32];
  const int t = threadIdx.x;
  const int w = t >> 6, l = t & 63;
  const int lr = l & 15, lg = l >> 4;
  const int wm = (w >> 1) * 64, wn = (w & 1) * 64;
  const long m0 = (long)blockIdx.y * 128, n0 = (long)blockIdx.x * 128;
  const long koff = (long)blockIdx.z * Kl;
  if constexpr (EPI == 0) Cf += (long)blockIdx.z * M * N;

  f32x4 acc[4][4];
#pragma unroll
  for (int i = 0; i < 4; ++i)
#pragma unroll
    for (int j = 0; j < 4; ++j) { acc[i][j][0] = 0.f; acc[i][j][1] = 0.f; acc[i][j][2] = 0.f; acc[i][j][3] = 0.f; }

  const int row0 = t >> 2, k80 = (t & 3) << 3;
  const int row1 = (256 + t) >> 2, k81 = ((256 + t) & 3) << 3;
  const u16* Ab = A + m0 * lda + koff;
  const u16* Bb = BT + n0 * ldb + koff;

  gload_lds16(Ab + (long)row0 * lda + k80, (u16*)As[0] + w * 512);
  gload_lds16(Ab + (long)row1 * lda + k81, (u16*)As[0] + 2048 + w * 512);
  gload_lds16(Bb + (long)row0 * ldb + k80, (u16*)Bs[0] + w * 512);
  gload_lds16(Bb + (long)row1 * ldb + k81, (u16*)Bs[0] + 2048 + w * 512);
  __syncthreads();

  int cur = 0;
  for (int kt = 0; kt < Kl; kt += 32) {
    if (kt + 32 < Kl) {
      const int nxt = cur ^ 1;
      gload_lds16(Ab + (long)row0 * lda + kt + 32 + k80, (u16*)As[nxt] + w * 512);
      gload_lds16(Ab + (long)row1 * lda + kt + 32 + k81, (u16*)As[nxt] + 2048 + w * 512);
      gload_lds16(Bb + (long)row0 * ldb + kt + 32 + k80, (u16*)Bs[nxt] + w * 512);
      gload_lds16(Bb + (long)row1 * ldb + kt + 32 + k81, (u16*)Bs[nxt] + 2048 + w * 512);
    }
    bf16x8 af[4], bfr[4];
#pragma unroll
    for (int i = 0; i < 4; ++i)
      af[i] = *(const bf16x8*)(As[cur] + (wm + i * 16 + lr) * 32 + lg * 8);
#pragma unroll
    for (int j = 0; j < 4; ++j)
      bfr[j] = *(const bf16x8*)(Bs[cur] + (wn + j * 16 + lr) * 32 + lg * 8);
#pragma unroll
    for (int i = 0; i < 4; ++i)
#pragma unroll
      for (int j = 0; j < 4; ++j)
        acc[i][j] = __builtin_amdgcn_mfma_f32_16x16x32_bf16(af[i], bfr[j], acc[i][j], 0, 0, 0);
    __syncthreads();
    cur ^= 1;
  }

#pragma unroll
  for (int i = 0; i < 4; ++i) {
    const long mr = m0 + wm + i * 16 + lg * 4;
#pragma unroll
    for (int j = 0; j < 4; ++j) {
      const long nc = n0 + wn + j * 16 + lr;
#pragma unroll
      for (int r = 0; r < 4; ++r) {
        const long idx = (mr + r) * N + nc;
        const float v = acc[i][j][r];
        if constexpr (EPI == 0) {
          Cf[idx] = v;
        } else if constexpr (EPI == 1) {
          Cf[idx] = v + res[idx];
        } else if constexpr (EPI == 2) {
          Cb[idx] = f2bf(v + bias[nc]);
        } else if constexpr (EPI == 3) {
          const float u = v + bias[nc];
          const float sg = 1.f / (1.f + __expf(-u));
          Cb[idx] = f2bf(bf2f(gate[idx]) * u * sg);
        } else {
          Cb[idx] = f2bf(v);
        }
      }
    }
  }
}

// ------------- split-K combine: out = p[0] + p[1] + res (+ bias), N=1024 -------------
__global__ __launch_bounds__(256) void combine_kernel(const float* __restrict__ p,
                                                      const float* __restrict__ res,
                                                      const float* __restrict__ bias,
                                                      float* __restrict__ out,
                                                      long total) {
  const long i = ((long)blockIdx.x * 256 + threadIdx.x) * 4;
  if (i >= total) return;
  const float4 a = *(const float4*)(p + i);
  const float4 b = *(const float4*)(p + total + i);
  const float4 r = *(const float4*)(res + i);
  float4 o;
  o.x = a.x + b.x + r.x;
  o.y = a.y + b.y + r.y;
  o.z = a.z + b.z + r.z;
  o.w = a.w + b.w + r.w;
  if (bias) {
    const float4 bb = *(const float4*)(bias + (int)(i & 1023));
    o.x += bb.x; o.y += bb.y; o.z += bb.z; o.w += bb.w;
  }
  *(float4*)(out + i) = o;
}

extern "C" void kernel_launch(void* const* d_in, const int* in_sizes, int n_in,
                              void* d_out, int out_size, void* d_ws, size_t ws_size,
                              hipStream_t stream) {
  (void)in_sizes; (void)n_in; (void)out_size; (void)ws_size;
  const float* x      = (const float*)d_in[0];
  const float* w_qkv  = (const float*)d_in[1];
  const float* w_out  = (const float*)d_in[2];
  const float* g1     = (const float*)d_in[3];
  const float* b1     = (const float*)d_in[4];
  const float* g2     = (const float*)d_in[5];
  const float* b2     = (const float*)d_in[6];
  const float* w_gate = (const float*)d_in[7];
  const float* b_gate = (const float*)d_in[8];
  const float* w_up   = (const float*)d_in[9];
  const float* b_up   = (const float*)d_in[10];
  const float* w_down = (const float*)d_in[11];
  const float* b_down = (const float*)d_in[12];
  float* out = (float*)d_out;

  const size_t MB = 1u << 20;
  char* ws = (char*)d_ws;
  u16*   y      = (u16*)(ws + 0 * MB);    // [4096][1024] bf16
  u16*   wqkvT  = (u16*)(ws + 8 * MB);    // [3072][1024]
  u16*   woutT  = (u16*)(ws + 14 * MB);   // [1024][1024]
  u16*   wgateT = (u16*)(ws + 16 * MB);   // [4096][1024]
  u16*   wupT   = (u16*)(ws + 24 * MB);   // [4096][1024]
  u16*   wdownT = (u16*)(ws + 32 * MB);   // [1024][4096]
  u16*   qkv    = (u16*)(ws + 40 * MB);   // [4096][3072] bf16 (24MB), dead after rope
  u16*   vt     = (u16*)(ws + 40 * MB);   // V^T [32][64][2048] (16MB), alias qkv? NO - see below
  float* part   = (float*)(ws + 40 * MB); // split-K partials [2][4096][1024] f32 (32MB)
  u16*   gbuf   = (u16*)(ws + 40 * MB);   // gate bf16 [4096][4096] (32MB)
  u16*   qr_    = (u16*)(ws + 88 * MB);   // [4096][1024]
  u16*   kr_    = (u16*)(ws + 96 * MB);
  u16*   vv_    = (u16*)(ws + 104 * MB);
  u16*   o_     = (u16*)(ws + 112 * MB);
  float* x1     = (float*)(ws + 120 * MB); // [4096][1024] f32 (16MB)
  u16*   gated  = (u16*)(ws + 88 * MB);    // [4096][4096] bf16, aliases qr/kr/vv/o (dead)
  // NOTE: vt aliases qkv region but transpose_v runs AFTER rope (qkv dead).
  // part (out-proj) aliases vt but runs AFTER attention (vt dead).
  // gbuf aliases part after the out-proj combine. Down-proj partials reuse
  // the same region after gbuf is dead (up-GEMM consumed it).

  const dim3 blk(256);
  transpose_bf16<<<dim3(3072 / 32, 1024 / 64), blk, 0, stream>>>(w_qkv, wqkvT, 1024, 3072);
  transpose_bf16<<<dim3(1024 / 32, 1024 / 64), blk, 0, stream>>>(w_out, woutT, 1024, 1024);
  transpose_bf16<<<dim3(4096 / 32, 1024 / 64), blk, 0, stream>>>(w_gate, wgateT, 1024, 4096);
  transpose_bf16<<<dim3(4096 / 32, 1024 / 64), blk, 0, stream>>>(w_up, wupT, 1024, 4096);
  transpose_bf16<<<dim3(1024 / 32, 4096 / 64), blk, 0, stream>>>(w_down, wdownT, 4096, 1024);

  // LN1
  ln_kernel<<<4096, blk, 0, stream>>>(x, g1, b1, y);
  // QKV projection (bf16 out)
  gemm_bt<5><<<dim3(3072 / 128, 4096 / 128, 1), blk, 0, stream>>>(
      y, wqkvT, nullptr, qkv, nullptr, nullptr, nullptr, 4096, 3072, 1024, 1024, 1024);
  // RoPE + split
  rope_kernel<<<4096, blk, 0, stream>>>(qkv, qr_, kr_, vv_);
  // V transpose (qkv dead -> vt)
  transpose_v<<<dim3(32, 32), blk, 0, stream>>>(vv_, vt);
  // local-causal attention (1 wave / 16 queries per block)
  attn_kernel<<<4096, dim3(64), 0, stream>>>(qr_, kr_, vt, o_);
  // out-proj split-K=2 (vt dead -> part), combine with residual x -> x1
  gemm_bt<0><<<dim3(1024 / 128, 4096 / 128, 2), blk, 0, stream>>>(
      o_, woutT, part, nullptr, nullptr, nullptr, nullptr, 4096, 1024, 512, 1024, 1024);
  combine_kernel<<<4096, blk, 0, stream>>>(part, x, nullptr, x1, (long)4096 * 1024);
  // LN2
  ln_kernel<<<4096, blk, 0, stream>>>(x1, g2, b2, y);
  // gate = y*w_gate + b_gate (bf16) (part dead -> gbuf)
  gemm_bt<2><<<dim3(4096 / 128, 4096 / 128, 1), blk, 0, stream>>>(
      y, wgateT, nullptr, gbuf, b_gate, nullptr, nullptr, 4096, 4096, 1024, 1024, 1024);
  // gated = gate * silu(y*w_up + b_up) (bf16)
  gemm_bt<3><<<dim3(4096 / 128, 4096 / 128, 1), blk, 0, stream>>>(
      y, wupT, nullptr, gated, b_up, nullptr, gbuf, 4096, 4096, 1024, 1024, 1024);
  // down-proj split-K=2 (gbuf dead -> part), combine with bias + residual x1 -> out
  gemm_bt<0><<<dim3(1024 / 128, 4096 / 128, 2), blk, 0, stream>>>(
      gated, wdownT, part, nullptr, nullptr, nullptr, nullptr, 4096, 1024, 2048, 4096, 4096);
  combine_kernel<<<4096, blk, 0, stream>>>(part, x1, b_down, out, (long)4096 * 1024);
}

// Round 6
// 295.321 us; speedup vs baseline: 1.4694x; 1.1021x over previous
//
#include <hip/hip_runtime.h>

typedef unsigned short u16;
typedef unsigned long long u64;
typedef __attribute__((ext_vector_type(8))) short bf16x8;
typedef __attribute__((ext_vector_type(4))) float f32x4;

__device__ inline u16 f2bf(float f) {
  unsigned int u = __float_as_uint(f);
  u += 0x7fffu + ((u >> 16) & 1u);
  return (u16)(u >> 16);
}
__device__ inline float bf2f(u16 h) { return __uint_as_float(((unsigned int)h) << 16); }

__device__ inline void gload_lds16(const void* gp, void* lp) {
  __builtin_amdgcn_global_load_lds(
      (const __attribute__((address_space(1))) unsigned int*)gp,
      (__attribute__((address_space(3))) unsigned int*)lp, 16, 0, 0);
}

// ---------------- LayerNorm: f32 [rows][1024] -> bf16 ----------------
__global__ __launch_bounds__(256) void ln_kernel(const float* __restrict__ x,
                                                 const float* __restrict__ g,
                                                 const float* __restrict__ beta,
                                                 u16* __restrict__ y) {
  __shared__ float red[8];
  const int row = blockIdx.x;
  const int t = threadIdx.x;
  const float4 xv = *(const float4*)(x + (long)row * 1024 + t * 4);
  float s = xv.x + xv.y + xv.z + xv.w;
  float sq = xv.x * xv.x + xv.y * xv.y + xv.z * xv.z + xv.w * xv.w;
#pragma unroll
  for (int d = 1; d < 64; d <<= 1) {
    s += __shfl_xor(s, d);
    sq += __shfl_xor(sq, d);
  }
  if ((t & 63) == 0) { red[t >> 6] = s; red[4 + (t >> 6)] = sq; }
  __syncthreads();
  s = red[0] + red[1] + red[2] + red[3];
  sq = red[4] + red[5] + red[6] + red[7];
  const float mean = s * (1.f / 1024.f);
  const float var = sq * (1.f / 1024.f) - mean * mean;
  const float inv = rsqrtf(var + 1e-5f);
  float xe[4] = {xv.x, xv.y, xv.z, xv.w};
  u16 ov[4];
#pragma unroll
  for (int e = 0; e < 4; ++e)
    ov[e] = f2bf((xe[e] - mean) * inv * g[t * 4 + e] + beta[t * 4 + e]);
  *(u64*)(y + (long)row * 1024 + t * 4) = *(u64*)ov;
}

// ------------- transpose + convert: f32 in[R][C] -> bf16 out[C][R] -------------
__global__ __launch_bounds__(256) void transpose_bf16(const float* __restrict__ in,
                                                      u16* __restrict__ out,
                                                      int R, int C) {
  __shared__ float tile[64][33];
  const int t = threadIdx.x;
  const int tx = t & 31, ty = t >> 5;
  const int rx = t & 63, cy = t >> 6;
  const long r0 = (long)blockIdx.y * 64, c0 = (long)blockIdx.x * 32;
#pragma unroll
  for (int i = 0; i < 8; ++i)
    tile[ty + i * 8][tx] = in[(r0 + ty + i * 8) * C + c0 + tx];
  __syncthreads();
#pragma unroll
  for (int i = 0; i < 8; ++i)
    out[(c0 + i * 4 + cy) * R + r0 + rx] = f2bf(tile[rx][i * 4 + cy]);
}

// ------------- V transpose: vv bf16 [b*2048+s][1024] -> vt [bh][64][2048] -------------
__global__ __launch_bounds__(256) void transpose_v(const u16* __restrict__ vv,
                                                   u16* __restrict__ vt) {
  __shared__ u16 tile[64][72];
  const int bh = blockIdx.y;
  const long s0 = (long)blockIdx.x * 64;
  const int t = threadIdx.x;
  const int r = t >> 3, cc = (t & 7) * 8;
  const long src = ((long)(bh >> 4) * 2048 + s0) * 1024 + (bh & 15) * 64;
  *(bf16x8*)&tile[r][cc] = *(const bf16x8*)(vv + src + (long)r * 1024 + cc);
  *(bf16x8*)&tile[r + 32][cc] = *(const bf16x8*)(vv + src + (long)(r + 32) * 1024 + cc);
  __syncthreads();
  const int d = t >> 3, sx = (t & 7) * 8;
  u16 o0[8], o1[8];
#pragma unroll
  for (int e = 0; e < 8; ++e) { o0[e] = tile[sx + e][d]; o1[e] = tile[sx + e][d + 32]; }
  const long dst = (long)bh * 64 * 2048 + s0;
  *(bf16x8*)(vt + dst + (long)d * 2048 + sx) = *(bf16x8*)o0;
  *(bf16x8*)(vt + dst + (long)(d + 32) * 2048 + sx) = *(bf16x8*)o1;
}

// ------------- RoPE + split -------------
__global__ __launch_bounds__(256) void rope_kernel(const u16* __restrict__ qkv,
                                                   u16* __restrict__ qr,
                                                   u16* __restrict__ kr,
                                                   u16* __restrict__ vv) {
  const int row = blockIdx.x;
  const int s = row & 2047;
  const int t = threadIdx.x;
  const u16* base = qkv + (long)row * 3072;
  const long orow = (long)row * 1024;
#pragma unroll
  for (int rep = 0; rep < 2; ++rep) {
    const int p = rep * 256 + t;
    const int h = p >> 5, d0 = p & 31;
    const float inv = exp2f((float)d0 * (-13.287712379549449f / 32.f));
    const float ang = (float)s * inv;
    float sn, cs;
    sincosf(ang, &sn, &cs);
    const int c1 = h * 64 + d0, c2 = c1 + 32;
    float x1 = bf2f(base[c1]), x2 = bf2f(base[c2]);
    qr[orow + c1] = f2bf((x1 * cs - x2 * sn) * 0.125f);
    qr[orow + c2] = f2bf((x2 * cs + x1 * sn) * 0.125f);
    float y1 = bf2f(base[1024 + c1]), y2 = bf2f(base[1024 + c2]);
    kr[orow + c1] = f2bf(y1 * cs - y2 * sn);
    kr[orow + c2] = f2bf(y2 * cs + y1 * sn);
  }
  *(u64*)(vv + orow + t * 4) = *(const u64*)(base + 2048 + t * 4);
}

// ------------- local-causal flash attention, window 256, hd=64, H=16 -------------
__global__ __launch_bounds__(64, 4) void attn_kernel(const u16* __restrict__ qr,
                                                     const u16* __restrict__ kr,
                                                     const u16* __restrict__ vt,
                                                     u16* __restrict__ o) {
  __shared__ __attribute__((aligned(16))) u16 Pl[16][40];
  int wg = blockIdx.x;
  wg = (wg & 7) * 512 + (wg >> 3);
  const int qt = wg & 127;
  const int bh = wg >> 7;
  const int qs = qt * 16;
  const int l = threadIdx.x;
  const int lr = l & 15, lg = l >> 4;
  const long bho = (long)(bh >> 4) * 2048 * 1024 + (long)(bh & 15) * 64;
  const long vtb = (long)bh * 64 * 2048;

  const u16* qp = qr + bho + (long)(qs + lr) * 1024 + lg * 8;
  const bf16x8 aq0 = *(const bf16x8*)qp;
  const bf16x8 aq1 = *(const bf16x8*)(qp + 32);

  f32x4 oacc[4];
#pragma unroll
  for (int nt = 0; nt < 4; ++nt) { oacc[nt][0] = 0.f; oacc[nt][1] = 0.f; oacc[nt][2] = 0.f; oacc[nt][3] = 0.f; }
  float m_[4], ls[4];
#pragma unroll
  for (int r = 0; r < 4; ++r) { m_[r] = -1e30f; ls[r] = 0.f; }

  for (int ch = 0; ch < 9; ++ch) {
    const int j0 = qs - 256 + ch * 32;
    if (j0 + 32 <= 0) continue;

    const int jc0u = j0 + lr;
    const int jc1u = j0 + 16 + lr;
    const int jc0 = min(max(jc0u, 0), 2047);
    const int jc1 = min(max(jc1u, 0), 2047);
    const u16* kp0 = kr + bho + (long)jc0 * 1024 + lg * 8;
    const u16* kp1 = kr + bho + (long)jc1 * 1024 + lg * 8;
    const bf16x8 b00 = *(const bf16x8*)kp0;
    const bf16x8 b01 = *(const bf16x8*)(kp0 + 32);
    const bf16x8 b10 = *(const bf16x8*)kp1;
    const bf16x8 b11 = *(const bf16x8*)(kp1 + 32);

    f32x4 z; z[0] = 0.f; z[1] = 0.f; z[2] = 0.f; z[3] = 0.f;
    f32x4 s0 = __builtin_amdgcn_mfma_f32_16x16x32_bf16(aq0, b00, z, 0, 0, 0);
    s0 = __builtin_amdgcn_mfma_f32_16x16x32_bf16(aq1, b01, s0, 0, 0, 0);
    f32x4 s1 = __builtin_amdgcn_mfma_f32_16x16x32_bf16(aq0, b10, z, 0, 0, 0);
    s1 = __builtin_amdgcn_mfma_f32_16x16x32_bf16(aq1, b11, s1, 0, 0, 0);

    float p0[4], p1[4], al[4];
#pragma unroll
    for (int r = 0; r < 4; ++r) {
      const int qg = qs + lg * 4 + r;
      const bool v0 = (jc0u >= 0) & (jc0u <= qg) & (qg - jc0u <= 256);
      const bool v1 = (jc1u >= 0) & (jc1u <= qg) & (qg - jc1u <= 256);
      const float t0 = v0 ? s0[r] : -1e30f;
      const float t1 = v1 ? s1[r] : -1e30f;
      float mx = fmaxf(t0, t1);
      mx = fmaxf(mx, __shfl_xor(mx, 1));
      mx = fmaxf(mx, __shfl_xor(mx, 2));
      mx = fmaxf(mx, __shfl_xor(mx, 4));
      mx = fmaxf(mx, __shfl_xor(mx, 8));
      const float mn = fmaxf(m_[r], mx);
      if (mn < -1e29f) {
        al[r] = 1.f; p0[r] = 0.f; p1[r] = 0.f;
      } else {
        al[r] = __expf(m_[r] - mn);
        p0[r] = (t0 < -1e29f) ? 0.f : __expf(t0 - mn);
        p1[r] = (t1 < -1e29f) ? 0.f : __expf(t1 - mn);
      }
      m_[r] = mn;
      float rs = p0[r] + p1[r];
      rs += __shfl_xor(rs, 1);
      rs += __shfl_xor(rs, 2);
      rs += __shfl_xor(rs, 4);
      rs += __shfl_xor(rs, 8);
      ls[r] = ls[r] * al[r] + rs;
    }
#pragma unroll
    for (int r = 0; r < 4; ++r) {
      Pl[lg * 4 + r][lr] = f2bf(p0[r]);
      Pl[lg * 4 + r][lr + 16] = f2bf(p1[r]);
    }
    asm volatile("s_waitcnt lgkmcnt(0)" ::: "memory");
    const bf16x8 pa = *(const bf16x8*)(&Pl[lr][lg * 8]);

    const int jb = min(max(j0 + lg * 8, 0), 2040);
    const u16* vp = vt + vtb + (long)lr * 2048 + jb;
#pragma unroll
    for (int nt = 0; nt < 4; ++nt) {
      const bf16x8 bv = *(const bf16x8*)(vp + (long)(nt * 16) * 2048);
      f32x4 oa = oacc[nt];
#pragma unroll
      for (int r = 0; r < 4; ++r) oa[r] *= al[r];
      oacc[nt] = __builtin_amdgcn_mfma_f32_16x16x32_bf16(pa, bv, oa, 0, 0, 0);
    }
  }
#pragma unroll
  for (int nt = 0; nt < 4; ++nt)
#pragma unroll
    for (int r = 0; r < 4; ++r) {
      const long qg = qs + lg * 4 + r;
      o[bho + qg * 1024 + nt * 16 + lr] = f2bf(oacc[nt][r] / ls[r]);
    }
}

// ================= 256x256 8-phase GEMM (T2+T3+T4+T5), BK=64, K mult of 64 =================
// C[M,N] = A[M,K] * BT[N,K]^T.  EPI: 5=bf16 plain, 2=bf16 +bias, 3=bf16 gate*silu(acc+bias)
// LDS (u16 idx): A[buf][half] at (buf*2+half)*8192 ; B same +32768. Swizzle: slot8 ^= row&7.
__device__ __forceinline__ void stage_half(u16* lds, int ldsbase,
                                           const u16* gp, int ld, int col,
                                           int tid, int w) {
  const int r0 = tid >> 3;
  const int sw = ((tid & 7) ^ (r0 & 7)) << 3;
  gload_lds16(gp + (long)r0 * ld + col + sw, lds + ldsbase + w * 512);
  gload_lds16(gp + (long)(r0 + 64) * ld + col + sw, lds + ldsbase + 4096 + w * 512);
}

template <int EPI>
__global__ __launch_bounds__(512, 2) void gemm8p(const u16* __restrict__ A,
                                                 const u16* __restrict__ BT,
                                                 u16* __restrict__ Cb,
                                                 const float* __restrict__ bias,
                                                 const u16* __restrict__ gate,
                                                 int M, int N, int K) {
  __shared__ __attribute__((aligned(16))) u16 lds[65536];   // 128 KB
  const int tid = threadIdx.x;
  const int w = tid >> 6, l = tid & 63;
  const int lr = l & 15, lg = l >> 4;
  const int l7 = l & 7;
  const int wr = w >> 2, wc = w & 3;
  const int nbx = N >> 8;
  int wg = blockIdx.x;
  { const int cpx = gridDim.x >> 3; wg = (wg & 7) * cpx + (wg >> 3); }
  const long m0 = (long)(wg / nbx) * 256;
  const long n0 = (long)(wg % nbx) * 256;
  const int NT = K >> 6;

  f32x4 acc[8][4];
#pragma unroll
  for (int i = 0; i < 8; ++i)
#pragma unroll
    for (int j = 0; j < 4; ++j) { acc[i][j][0] = 0.f; acc[i][j][1] = 0.f; acc[i][j][2] = 0.f; acc[i][j][3] = 0.f; }

  const u16* Alo = A + m0 * K;
  const u16* Ahi = A + (m0 + 128) * K;
  const u16* Blo = BT + n0 * K;
  const u16* Bhi = BT + (n0 + 128) * K;

  // prologue: A(0) lo/hi, B(0) lo/hi, B(1) lo/hi
  stage_half(lds, 0, Alo, K, 0, tid, w);              // A buf0 lo
  stage_half(lds, 8192, Ahi, K, 0, tid, w);           // A buf0 hi
  stage_half(lds, 32768, Blo, K, 0, tid, w);          // B buf0 lo
  stage_half(lds, 40960, Bhi, K, 0, tid, w);          // B buf0 hi
  stage_half(lds, 49152, Blo, K, 64, tid, w);         // B buf1 lo (tile 1)
  stage_half(lds, 57344, Bhi, K, 64, tid, w);         // B buf1 hi (tile 1)
  asm volatile("s_waitcnt vmcnt(4)" ::: "memory");
  __builtin_amdgcn_s_barrier();

  for (int t = 0; t < NT; ++t) {
    const int p = t & 1;
    const int baA = (p * 2 + wr) * 8192;               // this wave's A half
    const int bB = 32768 + p * 16384;                  // B base of buf p
    bf16x8 b[4][2];
#pragma unroll
    for (int q = 0; q < 4; ++q) {
      // --- ds reads for this phase ---
      bf16x8 a[2][2];
#pragma unroll
      for (int m2 = 0; m2 < 2; ++m2) {
        const int rowA = (q * 2 + m2) * 16 + lr;
#pragma unroll
        for (int kh = 0; kh < 2; ++kh)
          a[m2][kh] = *(const bf16x8*)(lds + baA + rowA * 64 + (((kh * 4 + lg) ^ l7) << 3));
      }
      if (q == 0) {
#pragma unroll
        for (int fn = 0; fn < 4; ++fn) {
          const int rb = wc * 64 + fn * 16 + lr;
#pragma unroll
          for (int kh = 0; kh < 2; ++kh)
            b[fn][kh] = *(const bf16x8*)(lds + bB + (rb >> 7) * 8192 + (rb & 127) * 64 + (((kh * 4 + lg) ^ l7) << 3));
        }
      }
      // --- stage one half-tile (schedule: A-lo(t+1), A-hi(t+1), B-lo(t+2), B-hi(t+2)) ---
      if (q == 0 && t + 1 < NT) stage_half(lds, ((p ^ 1) * 2 + 0) * 8192, Alo, K, (t + 1) * 64, tid, w);
      if (q == 1 && t + 1 < NT) stage_half(lds, ((p ^ 1) * 2 + 1) * 8192, Ahi, K, (t + 1) * 64, tid, w);
      if (q == 2 && t + 2 < NT) stage_half(lds, 32768 + (p * 2 + 0) * 8192, Blo, K, (t + 2) * 64, tid, w);
      if (q == 3 && t + 2 < NT) stage_half(lds, 32768 + (p * 2 + 1) * 8192, Bhi, K, (t + 2) * 64, tid, w);

      __builtin_amdgcn_s_barrier();
      asm volatile("s_waitcnt lgkmcnt(0)" ::: "memory");
      __builtin_amdgcn_s_setprio(1);
#pragma unroll
      for (int m2 = 0; m2 < 2; ++m2)
#pragma unroll
        for (int fn = 0; fn < 4; ++fn)
#pragma unroll
          for (int kh = 0; kh < 2; ++kh)
            acc[q * 2 + m2][fn] = __builtin_amdgcn_mfma_f32_16x16x32_bf16(a[m2][kh], b[fn][kh], acc[q * 2 + m2][fn], 0, 0, 0);
      __builtin_amdgcn_s_setprio(0);
      if (q == 3) {
        if (t + 2 < NT) { asm volatile("s_waitcnt vmcnt(4)" ::: "memory"); }
        else            { asm volatile("s_waitcnt vmcnt(0)" ::: "memory"); }
      }
      __builtin_amdgcn_s_barrier();
    }
  }

  // epilogue
#pragma unroll
  for (int fm = 0; fm < 8; ++fm) {
    const long mr = m0 + wr * 128 + fm * 16 + lg * 4;
#pragma unroll
    for (int fn = 0; fn < 4; ++fn) {
      const long nc = n0 + wc * 64 + fn * 16 + lr;
#pragma unroll
      for (int r = 0; r < 4; ++r) {
        const long idx = (mr + r) * N + nc;
        const float v = acc[fm][fn][r];
        if constexpr (EPI == 5) {
          Cb[idx] = f2bf(v);
        } else if constexpr (EPI == 2) {
          Cb[idx] = f2bf(v + bias[nc]);
        } else {
          const float u = v + bias[nc];
          const float sg = 1.f / (1.f + __expf(-u));
          Cb[idx] = f2bf(bf2f(gate[idx]) * u * sg);
        }
      }
    }
  }
}

// ------------- bf16 GEMM, B pre-transposed, 2-phase dbuf (for N=1024 shapes) -------------
// EPI: 0=f32 store (split-K via blockIdx.z), 1=f32 +res
template <int EPI>
__global__ __launch_bounds__(256) void gemm_bt(const u16* __restrict__ A,
                                               const u16* __restrict__ BT,
                                               float* __restrict__ Cf,
                                               const float* __restrict__ res,
                                               int M, int N, int Kl, int lda, int ldb) {
  __shared__ __attribute__((aligned(16))) u16 As[2][128 * 32];
  __shared__ __attribute__((aligned(16))) u16 Bs[2][128 * 32];
  const int t = threadIdx.x;
  const int w = t >> 6, l = t & 63;
  const int lr = l & 15, lg = l >> 4;
  const int wm = (w >> 1) * 64, wn = (w & 1) * 64;
  const long m0 = (long)blockIdx.y * 128, n0 = (long)blockIdx.x * 128;
  const long koff = (long)blockIdx.z * Kl;
  if constexpr (EPI == 0) Cf += (long)blockIdx.z * M * N;

  f32x4 acc[4][4];
#pragma unroll
  for (int i = 0; i < 4; ++i)
#pragma unroll
    for (int j = 0; j < 4; ++j) { acc[i][j][0] = 0.f; acc[i][j][1] = 0.f; acc[i][j][2] = 0.f; acc[i][j][3] = 0.f; }

  const int row0 = t >> 2, k80 = (t & 3) << 3;
  const int row1 = (256 + t) >> 2, k81 = ((256 + t) & 3) << 3;
  const u16* Ab = A + m0 * lda + koff;
  const u16* Bb = BT + n0 * ldb + koff;

  gload_lds16(Ab + (long)row0 * lda + k80, (u16*)As[0] + w * 512);
  gload_lds16(Ab + (long)row1 * lda + k81, (u16*)As[0] + 2048 + w * 512);
  gload_lds16(Bb + (long)row0 * ldb + k80, (u16*)Bs[0] + w * 512);
  gload_lds16(Bb + (long)row1 * ldb + k81, (u16*)Bs[0] + 2048 + w * 512);
  __syncthreads();

  int cur = 0;
  for (int kt = 0; kt < Kl; kt += 32) {
    if (kt + 32 < Kl) {
      const int nxt = cur ^ 1;
      gload_lds16(Ab + (long)row0 * lda + kt + 32 + k80, (u16*)As[nxt] + w * 512);
      gload_lds16(Ab + (long)row1 * lda + kt + 32 + k81, (u16*)As[nxt] + 2048 + w * 512);
      gload_lds16(Bb + (long)row0 * ldb + kt + 32 + k80, (u16*)Bs[nxt] + w * 512);
      gload_lds16(Bb + (long)row1 * ldb + kt + 32 + k81, (u16*)Bs[nxt] + 2048 + w * 512);
    }
    bf16x8 af[4], bfr[4];
#pragma unroll
    for (int i = 0; i < 4; ++i)
      af[i] = *(const bf16x8*)(As[cur] + (wm + i * 16 + lr) * 32 + lg * 8);
#pragma unroll
    for (int j = 0; j < 4; ++j)
      bfr[j] = *(const bf16x8*)(Bs[cur] + (wn + j * 16 + lr) * 32 + lg * 8);
#pragma unroll
    for (int i = 0; i < 4; ++i)
#pragma unroll
      for (int j = 0; j < 4; ++j)
        acc[i][j] = __builtin_amdgcn_mfma_f32_16x16x32_bf16(af[i], bfr[j], acc[i][j], 0, 0, 0);
    __syncthreads();
    cur ^= 1;
  }

#pragma unroll
  for (int i = 0; i < 4; ++i) {
    const long mr = m0 + wm + i * 16 + lg * 4;
#pragma unroll
    for (int j = 0; j < 4; ++j) {
      const long nc = n0 + wn + j * 16 + lr;
#pragma unroll
      for (int r = 0; r < 4; ++r) {
        const long idx = (mr + r) * N + nc;
        if constexpr (EPI == 0) Cf[idx] = acc[i][j][r];
        else                    Cf[idx] = acc[i][j][r] + res[idx];
      }
    }
  }
}

// ------------- split-K combine: out = p[0] + p[1] + res (+ bias) -------------
__global__ __launch_bounds__(256) void combine_kernel(const float* __restrict__ p,
                                                      const float* __restrict__ res,
                                                      const float* __restrict__ bias,
                                                      float* __restrict__ out,
                                                      long total) {
  const long i = ((long)blockIdx.x * 256 + threadIdx.x) * 4;
  if (i >= total) return;
  const float4 a = *(const float4*)(p + i);
  const float4 b = *(const float4*)(p + total + i);
  const float4 r = *(const float4*)(res + i);
  float4 o;
  o.x = a.x + b.x + r.x;
  o.y = a.y + b.y + r.y;
  o.z = a.z + b.z + r.z;
  o.w = a.w + b.w + r.w;
  if (bias) {
    const float4 bb = *(const float4*)(bias + (int)(i & 1023));
    o.x += bb.x; o.y += bb.y; o.z += bb.z; o.w += bb.w;
  }
  *(float4*)(out + i) = o;
}

extern "C" void kernel_launch(void* const* d_in, const int* in_sizes, int n_in,
                              void* d_out, int out_size, void* d_ws, size_t ws_size,
                              hipStream_t stream) {
  (void)in_sizes; (void)n_in; (void)out_size; (void)ws_size;
  const float* x      = (const float*)d_in[0];
  const float* w_qkv  = (const float*)d_in[1];
  const float* w_out  = (const float*)d_in[2];
  const float* g1     = (const float*)d_in[3];
  const float* b1     = (const float*)d_in[4];
  const float* g2     = (const float*)d_in[5];
  const float* b2     = (const float*)d_in[6];
  const float* w_gate = (const float*)d_in[7];
  const float* b_gate = (const float*)d_in[8];
  const float* b_up   = (const float*)d_in[10];
  const float* w_up   = (const float*)d_in[9];
  const float* w_down = (const float*)d_in[11];
  const float* b_down = (const float*)d_in[12];
  float* out = (float*)d_out;

  const size_t MB = 1u << 20;
  char* ws = (char*)d_ws;
  u16*   y      = (u16*)(ws + 0 * MB);    // [4096][1024] bf16
  u16*   wqkvT  = (u16*)(ws + 8 * MB);    // [3072][1024]
  u16*   woutT  = (u16*)(ws + 14 * MB);   // [1024][1024]
  u16*   wgateT = (u16*)(ws + 16 * MB);   // [4096][1024]
  u16*   wupT   = (u16*)(ws + 24 * MB);   // [4096][1024]
  u16*   wdownT = (u16*)(ws + 32 * MB);   // [1024][4096]
  u16*   qkv    = (u16*)(ws + 40 * MB);   // [4096][3072] bf16, dead after rope
  u16*   vt     = (u16*)(ws + 40 * MB);   // V^T [32][64][2048] (16MB), after rope
  float* part   = (float*)(ws + 40 * MB); // split-K partials [2][4096][1024] f32 (32MB)
  u16*   gbuf   = (u16*)(ws + 40 * MB);   // gate bf16 [4096][4096] (32MB)
  u16*   qr_    = (u16*)(ws + 88 * MB);
  u16*   kr_    = (u16*)(ws + 96 * MB);
  u16*   vv_    = (u16*)(ws + 104 * MB);
  u16*   o_     = (u16*)(ws + 112 * MB);
  float* x1     = (float*)(ws + 120 * MB);
  u16*   gated  = (u16*)(ws + 88 * MB);   // [4096][4096] bf16, aliases qr/kr/vv/o

  const dim3 blk(256);
  transpose_bf16<<<dim3(3072 / 32, 1024 / 64), blk, 0, stream>>>(w_qkv, wqkvT, 1024, 3072);
  transpose_bf16<<<dim3(1024 / 32, 1024 / 64), blk, 0, stream>>>(w_out, woutT, 1024, 1024);
  transpose_bf16<<<dim3(4096 / 32, 1024 / 64), blk, 0, stream>>>(w_gate, wgateT, 1024, 4096);
  transpose_bf16<<<dim3(4096 / 32, 1024 / 64), blk, 0, stream>>>(w_up, wupT, 1024, 4096);
  transpose_bf16<<<dim3(1024 / 32, 4096 / 64), blk, 0, stream>>>(w_down, wdownT, 4096, 1024);

  // LN1
  ln_kernel<<<4096, blk, 0, stream>>>(x, g1, b1, y);
  // QKV projection (8-phase 256^2, bf16 out)
  gemm8p<5><<<dim3((3072 / 256) * (4096 / 256)), dim3(512), 0, stream>>>(
      y, wqkvT, qkv, nullptr, nullptr, 4096, 3072, 1024);
  // RoPE + split
  rope_kernel<<<4096, blk, 0, stream>>>(qkv, qr_, kr_, vv_);
  // V transpose (qkv dead -> vt)
  transpose_v<<<dim3(32, 32), blk, 0, stream>>>(vv_, vt);
  // local-causal attention
  attn_kernel<<<4096, dim3(64), 0, stream>>>(qr_, kr_, vt, o_);
  // out-proj split-K=2 (vt dead -> part), combine with residual x -> x1
  gemm_bt<0><<<dim3(1024 / 128, 4096 / 128, 2), blk, 0, stream>>>(
      o_, woutT, part, nullptr, 4096, 1024, 512, 1024, 1024);
  combine_kernel<<<4096, blk, 0, stream>>>(part, x, nullptr, x1, (long)4096 * 1024);
  // LN2
  ln_kernel<<<4096, blk, 0, stream>>>(x1, g2, b2, y);
  // gate = y*w_gate + b_gate (8-phase, bf16; part dead -> gbuf)
  gemm8p<2><<<dim3((4096 / 256) * (4096 / 256)), dim3(512), 0, stream>>>(
      y, wgateT, gbuf, b_gate, nullptr, 4096, 4096, 1024);
  // gated = gate * silu(y*w_up + b_up) (8-phase, bf16)
  gemm8p<3><<<dim3((4096 / 256) * (4096 / 256)), dim3(512), 0, stream>>>(
      y, wupT, gated, b_up, gbuf, 4096, 4096, 1024);
  // down-proj split-K=2 (gbuf dead -> part), combine with bias + residual x1 -> out
  gemm_bt<0><<<dim3(1024 / 128, 4096 / 128, 2), blk, 0, stream>>>(
      gated, wdownT, part, nullptr, 4096, 1024, 2048, 4096, 4096);
  combine_kernel<<<4096, blk, 0, stream>>>(part, x1, b_down, out, (long)4096 * 1024);
}

// Round 7
// 287.277 us; speedup vs baseline: 1.5106x; 1.0280x over previous
//
#include <hip/hip_runtime.h>

typedef unsigned short u16;
typedef unsigned long long u64;
typedef __attribute__((ext_vector_type(8))) short bf16x8;
typedef __attribute__((ext_vector_type(4))) float f32x4;

__device__ inline u16 f2bf(float f) {
  unsigned int u = __float_as_uint(f);
  u += 0x7fffu + ((u >> 16) & 1u);
  return (u16)(u >> 16);
}
__device__ inline float bf2f(u16 h) { return __uint_as_float(((unsigned int)h) << 16); }

__device__ inline void gload_lds16(const void* gp, void* lp) {
  __builtin_amdgcn_global_load_lds(
      (const __attribute__((address_space(1))) unsigned int*)gp,
      (__attribute__((address_space(3))) unsigned int*)lp, 16, 0, 0);
}

// ---------------- LayerNorm: f32 [rows][1024] -> bf16 ----------------
__global__ __launch_bounds__(256) void ln_kernel(const float* __restrict__ x,
                                                 const float* __restrict__ g,
                                                 const float* __restrict__ beta,
                                                 u16* __restrict__ y) {
  __shared__ float red[8];
  const int row = blockIdx.x;
  const int t = threadIdx.x;
  const float4 xv = *(const float4*)(x + (long)row * 1024 + t * 4);
  float s = xv.x + xv.y + xv.z + xv.w;
  float sq = xv.x * xv.x + xv.y * xv.y + xv.z * xv.z + xv.w * xv.w;
#pragma unroll
  for (int d = 1; d < 64; d <<= 1) {
    s += __shfl_xor(s, d);
    sq += __shfl_xor(sq, d);
  }
  if ((t & 63) == 0) { red[t >> 6] = s; red[4 + (t >> 6)] = sq; }
  __syncthreads();
  s = red[0] + red[1] + red[2] + red[3];
  sq = red[4] + red[5] + red[6] + red[7];
  const float mean = s * (1.f / 1024.f);
  const float var = sq * (1.f / 1024.f) - mean * mean;
  const float inv = rsqrtf(var + 1e-5f);
  float xe[4] = {xv.x, xv.y, xv.z, xv.w};
  u16 ov[4];
#pragma unroll
  for (int e = 0; e < 4; ++e)
    ov[e] = f2bf((xe[e] - mean) * inv * g[t * 4 + e] + beta[t * 4 + e]);
  *(u64*)(y + (long)row * 1024 + t * 4) = *(u64*)ov;
}

// ------------- transpose + convert: f32 in[R][C] -> bf16 out[C][R] -------------
__global__ __launch_bounds__(256) void transpose_bf16(const float* __restrict__ in,
                                                      u16* __restrict__ out,
                                                      int R, int C) {
  __shared__ float tile[64][33];
  const int t = threadIdx.x;
  const int tx = t & 31, ty = t >> 5;
  const int rx = t & 63, cy = t >> 6;
  const long r0 = (long)blockIdx.y * 64, c0 = (long)blockIdx.x * 32;
#pragma unroll
  for (int i = 0; i < 8; ++i)
    tile[ty + i * 8][tx] = in[(r0 + ty + i * 8) * C + c0 + tx];
  __syncthreads();
#pragma unroll
  for (int i = 0; i < 8; ++i)
    out[(c0 + i * 4 + cy) * R + r0 + rx] = f2bf(tile[rx][i * 4 + cy]);
}

// ------------- V transpose: vv bf16 [b*2048+s][1024] -> vt [bh][64][2048] -------------
__global__ __launch_bounds__(256) void transpose_v(const u16* __restrict__ vv,
                                                   u16* __restrict__ vt) {
  __shared__ u16 tile[64][72];
  const int bh = blockIdx.y;
  const long s0 = (long)blockIdx.x * 64;
  const int t = threadIdx.x;
  const int r = t >> 3, cc = (t & 7) * 8;
  const long src = ((long)(bh >> 4) * 2048 + s0) * 1024 + (bh & 15) * 64;
  *(bf16x8*)&tile[r][cc] = *(const bf16x8*)(vv + src + (long)r * 1024 + cc);
  *(bf16x8*)&tile[r + 32][cc] = *(const bf16x8*)(vv + src + (long)(r + 32) * 1024 + cc);
  __syncthreads();
  const int d = t >> 3, sx = (t & 7) * 8;
  u16 o0[8], o1[8];
#pragma unroll
  for (int e = 0; e < 8; ++e) { o0[e] = tile[sx + e][d]; o1[e] = tile[sx + e][d + 32]; }
  const long dst = (long)bh * 64 * 2048 + s0;
  *(bf16x8*)(vt + dst + (long)d * 2048 + sx) = *(bf16x8*)o0;
  *(bf16x8*)(vt + dst + (long)(d + 32) * 2048 + sx) = *(bf16x8*)o1;
}

// ------------- RoPE + split -------------
__global__ __launch_bounds__(256) void rope_kernel(const u16* __restrict__ qkv,
                                                   u16* __restrict__ qr,
                                                   u16* __restrict__ kr,
                                                   u16* __restrict__ vv) {
  const int row = blockIdx.x;
  const int s = row & 2047;
  const int t = threadIdx.x;
  const u16* base = qkv + (long)row * 3072;
  const long orow = (long)row * 1024;
#pragma unroll
  for (int rep = 0; rep < 2; ++rep) {
    const int p = rep * 256 + t;
    const int h = p >> 5, d0 = p & 31;
    const float inv = exp2f((float)d0 * (-13.287712379549449f / 32.f));
    const float ang = (float)s * inv;
    float sn, cs;
    sincosf(ang, &sn, &cs);
    const int c1 = h * 64 + d0, c2 = c1 + 32;
    float x1 = bf2f(base[c1]), x2 = bf2f(base[c2]);
    qr[orow + c1] = f2bf((x1 * cs - x2 * sn) * 0.125f);
    qr[orow + c2] = f2bf((x2 * cs + x1 * sn) * 0.125f);
    float y1 = bf2f(base[1024 + c1]), y2 = bf2f(base[1024 + c2]);
    kr[orow + c1] = f2bf(y1 * cs - y2 * sn);
    kr[orow + c2] = f2bf(y2 * cs + y1 * sn);
  }
  *(u64*)(vv + orow + t * 4) = *(const u64*)(base + 2048 + t * 4);
}

// ------------- local-causal flash attention, window 256, hd=64, H=16 -------------
__global__ __launch_bounds__(64, 4) void attn_kernel(const u16* __restrict__ qr,
                                                     const u16* __restrict__ kr,
                                                     const u16* __restrict__ vt,
                                                     u16* __restrict__ o) {
  __shared__ __attribute__((aligned(16))) u16 Pl[16][40];
  int wg = blockIdx.x;
  wg = (wg & 7) * 512 + (wg >> 3);
  const int qt = wg & 127;
  const int bh = wg >> 7;
  const int qs = qt * 16;
  const int l = threadIdx.x;
  const int lr = l & 15, lg = l >> 4;
  const long bho = (long)(bh >> 4) * 2048 * 1024 + (long)(bh & 15) * 64;
  const long vtb = (long)bh * 64 * 2048;

  const u16* qp = qr + bho + (long)(qs + lr) * 1024 + lg * 8;
  const bf16x8 aq0 = *(const bf16x8*)qp;
  const bf16x8 aq1 = *(const bf16x8*)(qp + 32);

  f32x4 oacc[4];
#pragma unroll
  for (int nt = 0; nt < 4; ++nt) { oacc[nt][0] = 0.f; oacc[nt][1] = 0.f; oacc[nt][2] = 0.f; oacc[nt][3] = 0.f; }
  float m_[4], ls[4];
#pragma unroll
  for (int r = 0; r < 4; ++r) { m_[r] = -1e30f; ls[r] = 0.f; }

  for (int ch = 0; ch < 9; ++ch) {
    const int j0 = qs - 256 + ch * 32;
    if (j0 + 32 <= 0) continue;

    const int jc0u = j0 + lr;
    const int jc1u = j0 + 16 + lr;
    const int jc0 = min(max(jc0u, 0), 2047);
    const int jc1 = min(max(jc1u, 0), 2047);
    const u16* kp0 = kr + bho + (long)jc0 * 1024 + lg * 8;
    const u16* kp1 = kr + bho + (long)jc1 * 1024 + lg * 8;
    const bf16x8 b00 = *(const bf16x8*)kp0;
    const bf16x8 b01 = *(const bf16x8*)(kp0 + 32);
    const bf16x8 b10 = *(const bf16x8*)kp1;
    const bf16x8 b11 = *(const bf16x8*)(kp1 + 32);

    f32x4 z; z[0] = 0.f; z[1] = 0.f; z[2] = 0.f; z[3] = 0.f;
    f32x4 s0 = __builtin_amdgcn_mfma_f32_16x16x32_bf16(aq0, b00, z, 0, 0, 0);
    s0 = __builtin_amdgcn_mfma_f32_16x16x32_bf16(aq1, b01, s0, 0, 0, 0);
    f32x4 s1 = __builtin_amdgcn_mfma_f32_16x16x32_bf16(aq0, b10, z, 0, 0, 0);
    s1 = __builtin_amdgcn_mfma_f32_16x16x32_bf16(aq1, b11, s1, 0, 0, 0);

    float p0[4], p1[4], al[4];
#pragma unroll
    for (int r = 0; r < 4; ++r) {
      const int qg = qs + lg * 4 + r;
      const bool v0 = (jc0u >= 0) & (jc0u <= qg) & (qg - jc0u <= 256);
      const bool v1 = (jc1u >= 0) & (jc1u <= qg) & (qg - jc1u <= 256);
      const float t0 = v0 ? s0[r] : -1e30f;
      const float t1 = v1 ? s1[r] : -1e30f;
      float mx = fmaxf(t0, t1);
      mx = fmaxf(mx, __shfl_xor(mx, 1));
      mx = fmaxf(mx, __shfl_xor(mx, 2));
      mx = fmaxf(mx, __shfl_xor(mx, 4));
      mx = fmaxf(mx, __shfl_xor(mx, 8));
      const float mn = fmaxf(m_[r], mx);
      if (mn < -1e29f) {
        al[r] = 1.f; p0[r] = 0.f; p1[r] = 0.f;
      } else {
        al[r] = __expf(m_[r] - mn);
        p0[r] = (t0 < -1e29f) ? 0.f : __expf(t0 - mn);
        p1[r] = (t1 < -1e29f) ? 0.f : __expf(t1 - mn);
      }
      m_[r] = mn;
      float rs = p0[r] + p1[r];
      rs += __shfl_xor(rs, 1);
      rs += __shfl_xor(rs, 2);
      rs += __shfl_xor(rs, 4);
      rs += __shfl_xor(rs, 8);
      ls[r] = ls[r] * al[r] + rs;
    }
#pragma unroll
    for (int r = 0; r < 4; ++r) {
      Pl[lg * 4 + r][lr] = f2bf(p0[r]);
      Pl[lg * 4 + r][lr + 16] = f2bf(p1[r]);
    }
    asm volatile("s_waitcnt lgkmcnt(0)" ::: "memory");
    const bf16x8 pa = *(const bf16x8*)(&Pl[lr][lg * 8]);

    const int jb = min(max(j0 + lg * 8, 0), 2040);
    const u16* vp = vt + vtb + (long)lr * 2048 + jb;
#pragma unroll
    for (int nt = 0; nt < 4; ++nt) {
      const bf16x8 bv = *(const bf16x8*)(vp + (long)(nt * 16) * 2048);
      f32x4 oa = oacc[nt];
#pragma unroll
      for (int r = 0; r < 4; ++r) oa[r] *= al[r];
      oacc[nt] = __builtin_amdgcn_mfma_f32_16x16x32_bf16(pa, bv, oa, 0, 0, 0);
    }
  }
#pragma unroll
  for (int nt = 0; nt < 4; ++nt)
#pragma unroll
    for (int r = 0; r < 4; ++r) {
      const long qg = qs + lg * 4 + r;
      o[bho + qg * 1024 + nt * 16 + lr] = f2bf(oacc[nt][r] / ls[r]);
    }
}

// ================= 256x256 8-phase GEMM (T2+T3+T4+T5), BK=64 =================
// C = A[M,Kfull](cols koff..koff+Kl) * BT[N,Kfull]^T, koff = z*Kl, z = blk/(nbx*nby)
// EPI: 5=bf16 plain, 2=bf16 +bias, 3=bf16 gate*silu(acc+bias), 0=f32 partials to
//      (z<2 ? Cf0 : Cf1) + (z&1)*M*N  (split-K over up to 4 slices, 2 base ptrs)
__device__ __forceinline__ void stage_half(u16* lds, int ldsbase,
                                           const u16* gp, int ld, int col,
                                           int tid, int w) {
  const int r0 = tid >> 3;
  const int sw = ((tid & 7) ^ (r0 & 7)) << 3;
  gload_lds16(gp + (long)r0 * ld + col + sw, lds + ldsbase + w * 512);
  gload_lds16(gp + (long)(r0 + 64) * ld + col + sw, lds + ldsbase + 4096 + w * 512);
}

template <int EPI>
__global__ __launch_bounds__(512, 2) void gemm8p(const u16* __restrict__ A,
                                                 const u16* __restrict__ BT,
                                                 u16* __restrict__ Cb,
                                                 const float* __restrict__ bias,
                                                 const u16* __restrict__ gate,
                                                 float* __restrict__ Cf0,
                                                 float* __restrict__ Cf1,
                                                 int M, int N, int Kfull, int Kl) {
  __shared__ __attribute__((aligned(16))) u16 lds[65536];   // 128 KB
  const int tid = threadIdx.x;
  const int w = tid >> 6, l = tid & 63;
  const int lr = l & 15, lg = l >> 4;
  const int l7 = l & 7;
  const int wr = w >> 2, wc = w & 3;
  const int nbx = N >> 8, nby = M >> 8;
  int wg = blockIdx.x;
  { const int cpx = gridDim.x >> 3; wg = (wg & 7) * cpx + (wg >> 3); }
  const int z = wg / (nbx * nby);
  const int rem = wg % (nbx * nby);
  const long m0 = (long)(rem / nbx) * 256;
  const long n0 = (long)(rem % nbx) * 256;
  const long koff = (long)z * Kl;
  const int NT = Kl >> 6;

  f32x4 acc[8][4];
#pragma unroll
  for (int i = 0; i < 8; ++i)
#pragma unroll
    for (int j = 0; j < 4; ++j) { acc[i][j][0] = 0.f; acc[i][j][1] = 0.f; acc[i][j][2] = 0.f; acc[i][j][3] = 0.f; }

  const u16* Alo = A + m0 * Kfull + koff;
  const u16* Ahi = A + (m0 + 128) * Kfull + koff;
  const u16* Blo = BT + n0 * Kfull + koff;
  const u16* Bhi = BT + (n0 + 128) * Kfull + koff;

  // prologue: A(0) lo/hi, B(0) lo/hi, B(1) lo/hi
  stage_half(lds, 0, Alo, Kfull, 0, tid, w);
  stage_half(lds, 8192, Ahi, Kfull, 0, tid, w);
  stage_half(lds, 32768, Blo, Kfull, 0, tid, w);
  stage_half(lds, 40960, Bhi, Kfull, 0, tid, w);
  stage_half(lds, 49152, Blo, Kfull, 64, tid, w);
  stage_half(lds, 57344, Bhi, Kfull, 64, tid, w);
  asm volatile("s_waitcnt vmcnt(4)" ::: "memory");
  __builtin_amdgcn_s_barrier();

  for (int t = 0; t < NT; ++t) {
    const int p = t & 1;
    const int baA = (p * 2 + wr) * 8192;
    const int bB = 32768 + p * 16384;
    bf16x8 b[4][2];
#pragma unroll
    for (int q = 0; q < 4; ++q) {
      bf16x8 a[2][2];
#pragma unroll
      for (int m2 = 0; m2 < 2; ++m2) {
        const int rowA = (q * 2 + m2) * 16 + lr;
#pragma unroll
        for (int kh = 0; kh < 2; ++kh)
          a[m2][kh] = *(const bf16x8*)(lds + baA + rowA * 64 + (((kh * 4 + lg) ^ l7) << 3));
      }
      if (q == 0) {
#pragma unroll
        for (int fn = 0; fn < 4; ++fn) {
          const int rb = wc * 64 + fn * 16 + lr;
#pragma unroll
          for (int kh = 0; kh < 2; ++kh)
            b[fn][kh] = *(const bf16x8*)(lds + bB + (rb >> 7) * 8192 + (rb & 127) * 64 + (((kh * 4 + lg) ^ l7) << 3));
        }
      }
      if (q == 0 && t + 1 < NT) stage_half(lds, ((p ^ 1) * 2 + 0) * 8192, Alo, Kfull, (t + 1) * 64, tid, w);
      if (q == 1 && t + 1 < NT) stage_half(lds, ((p ^ 1) * 2 + 1) * 8192, Ahi, Kfull, (t + 1) * 64, tid, w);
      if (q == 2 && t + 2 < NT) stage_half(lds, 32768 + (p * 2 + 0) * 8192, Blo, Kfull, (t + 2) * 64, tid, w);
      if (q == 3 && t + 2 < NT) stage_half(lds, 32768 + (p * 2 + 1) * 8192, Bhi, Kfull, (t + 2) * 64, tid, w);

      __builtin_amdgcn_s_barrier();
      asm volatile("s_waitcnt lgkmcnt(0)" ::: "memory");
      __builtin_amdgcn_s_setprio(1);
#pragma unroll
      for (int m2 = 0; m2 < 2; ++m2)
#pragma unroll
        for (int fn = 0; fn < 4; ++fn)
#pragma unroll
          for (int kh = 0; kh < 2; ++kh)
            acc[q * 2 + m2][fn] = __builtin_amdgcn_mfma_f32_16x16x32_bf16(a[m2][kh], b[fn][kh], acc[q * 2 + m2][fn], 0, 0, 0);
      __builtin_amdgcn_s_setprio(0);
      if (q == 3) {
        if (t + 2 < NT) { asm volatile("s_waitcnt vmcnt(4)" ::: "memory"); }
        else            { asm volatile("s_waitcnt vmcnt(0)" ::: "memory"); }
      }
      __builtin_amdgcn_s_barrier();
    }
  }

  float* Cf = nullptr;
  if constexpr (EPI == 0) Cf = (z < 2 ? Cf0 : Cf1) + (long)(z & 1) * M * N;

#pragma unroll
  for (int fm = 0; fm < 8; ++fm) {
    const long mr = m0 + wr * 128 + fm * 16 + lg * 4;
#pragma unroll
    for (int fn = 0; fn < 4; ++fn) {
      const long nc = n0 + wc * 64 + fn * 16 + lr;
#pragma unroll
      for (int r = 0; r < 4; ++r) {
        const long idx = (mr + r) * N + nc;
        const float v = acc[fm][fn][r];
        if constexpr (EPI == 5) {
          Cb[idx] = f2bf(v);
        } else if constexpr (EPI == 2) {
          Cb[idx] = f2bf(v + bias[nc]);
        } else if constexpr (EPI == 3) {
          const float u = v + bias[nc];
          const float sg = 1.f / (1.f + __expf(-u));
          Cb[idx] = f2bf(bf2f(gate[idx]) * u * sg);
        } else {
          Cf[idx] = v;
        }
      }
    }
  }
}

// ------ combine 4 partials + residual, then LayerNorm -> x1 (f32) and y (bf16) ------
__global__ __launch_bounds__(256) void combine_ln(const float* __restrict__ p0,
                                                  const float* __restrict__ p1,
                                                  const float* __restrict__ x,
                                                  const float* __restrict__ g,
                                                  const float* __restrict__ beta,
                                                  float* __restrict__ x1,
                                                  u16* __restrict__ y) {
  __shared__ float red[8];
  const long MN = (long)4096 * 1024;
  const int row = blockIdx.x;
  const int t = threadIdx.x;
  const long base = (long)row * 1024 + t * 4;
  const float4 a = *(const float4*)(p0 + base);
  const float4 b = *(const float4*)(p0 + MN + base);
  const float4 c = *(const float4*)(p1 + base);
  const float4 d = *(const float4*)(p1 + MN + base);
  const float4 r = *(const float4*)(x + base);
  float v[4] = {a.x + b.x + c.x + d.x + r.x, a.y + b.y + c.y + d.y + r.y,
                a.z + b.z + c.z + d.z + r.z, a.w + b.w + c.w + d.w + r.w};
  *(float4*)(x1 + base) = *(float4*)v;
  float s = v[0] + v[1] + v[2] + v[3];
  float sq = v[0] * v[0] + v[1] * v[1] + v[2] * v[2] + v[3] * v[3];
#pragma unroll
  for (int dd = 1; dd < 64; dd <<= 1) {
    s += __shfl_xor(s, dd);
    sq += __shfl_xor(sq, dd);
  }
  if ((t & 63) == 0) { red[t >> 6] = s; red[4 + (t >> 6)] = sq; }
  __syncthreads();
  s = red[0] + red[1] + red[2] + red[3];
  sq = red[4] + red[5] + red[6] + red[7];
  const float mean = s * (1.f / 1024.f);
  const float var = sq * (1.f / 1024.f) - mean * mean;
  const float inv = rsqrtf(var + 1e-5f);
  u16 ov[4];
#pragma unroll
  for (int e = 0; e < 4; ++e)
    ov[e] = f2bf((v[e] - mean) * inv * g[t * 4 + e] + beta[t * 4 + e]);
  *(u64*)(y + base) = *(u64*)ov;
}

// ------ combine 4 partials + bias + residual -> out (f32) ------
__global__ __launch_bounds__(256) void combine4(const float* __restrict__ p0,
                                                const float* __restrict__ p1,
                                                const float* __restrict__ res,
                                                const float* __restrict__ bias,
                                                float* __restrict__ out) {
  const long MN = (long)4096 * 1024;
  const long i = ((long)blockIdx.x * 256 + threadIdx.x) * 4;
  const float4 a = *(const float4*)(p0 + i);
  const float4 b = *(const float4*)(p0 + MN + i);
  const float4 c = *(const float4*)(p1 + i);
  const float4 d = *(const float4*)(p1 + MN + i);
  const float4 r = *(const float4*)(res + i);
  const float4 bb = *(const float4*)(bias + (int)(i & 1023));
  float4 o;
  o.x = a.x + b.x + c.x + d.x + r.x + bb.x;
  o.y = a.y + b.y + c.y + d.y + r.y + bb.y;
  o.z = a.z + b.z + c.z + d.z + r.z + bb.z;
  o.w = a.w + b.w + c.w + d.w + r.w + bb.w;
  *(float4*)(out + i) = o;
}

extern "C" void kernel_launch(void* const* d_in, const int* in_sizes, int n_in,
                              void* d_out, int out_size, void* d_ws, size_t ws_size,
                              hipStream_t stream) {
  (void)in_sizes; (void)n_in; (void)out_size; (void)ws_size;
  const float* x      = (const float*)d_in[0];
  const float* w_qkv  = (const float*)d_in[1];
  const float* w_out  = (const float*)d_in[2];
  const float* g1     = (const float*)d_in[3];
  const float* b1     = (const float*)d_in[4];
  const float* g2     = (const float*)d_in[5];
  const float* b2     = (const float*)d_in[6];
  const float* w_gate = (const float*)d_in[7];
  const float* b_gate = (const float*)d_in[8];
  const float* w_up   = (const float*)d_in[9];
  const float* b_up   = (const float*)d_in[10];
  const float* w_down = (const float*)d_in[11];
  const float* b_down = (const float*)d_in[12];
  float* out = (float*)d_out;

  // Workspace layout (MB offsets), liveness-checked:
  //   0-8   wdownT          8-16  y            16-22 wqkvT      22-24 woutT
  //  24-32  wgateT         32-40  wupT
  //  40-64  qkv (dead after rope) / 40-56 vt (dead after attn) / 40-56 x1 (after out-proj)
  //  56-64  o_
  //  64-72  qr_   72-80 kr_   80-88 vv_   (all dead after attn)
  //  64-128 part_out (out-proj split-K partials, dead after combine_ln)
  //  64-96  gated (written by up-GEMM, after part_out dead)
  //  96-128 gbuf (gate, dead after up-GEMM) -> pd1 (down partials hi)
  //   8-40  pd0 (down partials lo; weights/y dead by then)
  const size_t MB = 1u << 20;
  char* ws = (char*)d_ws;
  u16*   wdownT = (u16*)(ws + 0 * MB);
  u16*   y      = (u16*)(ws + 8 * MB);
  u16*   wqkvT  = (u16*)(ws + 16 * MB);
  u16*   woutT  = (u16*)(ws + 22 * MB);
  u16*   wgateT = (u16*)(ws + 24 * MB);
  u16*   wupT   = (u16*)(ws + 32 * MB);
  u16*   qkv    = (u16*)(ws + 40 * MB);
  u16*   vt     = (u16*)(ws + 40 * MB);
  float* x1     = (float*)(ws + 40 * MB);
  u16*   o_     = (u16*)(ws + 56 * MB);
  u16*   qr_    = (u16*)(ws + 64 * MB);
  u16*   kr_    = (u16*)(ws + 72 * MB);
  u16*   vv_    = (u16*)(ws + 80 * MB);
  float* part   = (float*)(ws + 64 * MB);   // out-proj partials [4][4096][1024]
  u16*   gated  = (u16*)(ws + 64 * MB);
  u16*   gbuf   = (u16*)(ws + 96 * MB);
  float* pd0    = (float*)(ws + 8 * MB);    // down partials z=0,1
  float* pd1    = (float*)(ws + 96 * MB);   // down partials z=2,3

  const dim3 blk(256);
  transpose_bf16<<<dim3(3072 / 32, 1024 / 64), blk, 0, stream>>>(w_qkv, wqkvT, 1024, 3072);
  transpose_bf16<<<dim3(1024 / 32, 1024 / 64), blk, 0, stream>>>(w_out, woutT, 1024, 1024);
  transpose_bf16<<<dim3(4096 / 32, 1024 / 64), blk, 0, stream>>>(w_gate, wgateT, 1024, 4096);
  transpose_bf16<<<dim3(4096 / 32, 1024 / 64), blk, 0, stream>>>(w_up, wupT, 1024, 4096);
  transpose_bf16<<<dim3(1024 / 32, 4096 / 64), blk, 0, stream>>>(w_down, wdownT, 4096, 1024);

  // LN1: x -> y
  ln_kernel<<<4096, blk, 0, stream>>>(x, g1, b1, y);
  // QKV projection (8-phase, bf16 out)
  gemm8p<5><<<dim3((3072 / 256) * (4096 / 256)), dim3(512), 0, stream>>>(
      y, wqkvT, qkv, nullptr, nullptr, nullptr, nullptr, 4096, 3072, 1024, 1024);
  // RoPE + split
  rope_kernel<<<4096, blk, 0, stream>>>(qkv, qr_, kr_, vv_);
  // V transpose (qkv dead -> vt)
  transpose_v<<<dim3(32, 32), blk, 0, stream>>>(vv_, vt);
  // local-causal attention -> o_
  attn_kernel<<<4096, dim3(64), 0, stream>>>(qr_, kr_, vt, o_);
  // out-proj, 8-phase split-K=4 (Kl=256) -> part; combine + residual + LN2 -> x1, y
  gemm8p<0><<<dim3(4 * 16 * 4), dim3(512), 0, stream>>>(
      o_, woutT, nullptr, nullptr, nullptr, part, part + (long)2 * 4096 * 1024,
      4096, 1024, 1024, 256);
  combine_ln<<<4096, blk, 0, stream>>>(part, part + (long)2 * 4096 * 1024, x, g2, b2, x1, y);
  // gate = y*w_gate + b_gate (bf16) -> gbuf
  gemm8p<2><<<dim3((4096 / 256) * (4096 / 256)), dim3(512), 0, stream>>>(
      y, wgateT, gbuf, b_gate, nullptr, nullptr, nullptr, 4096, 4096, 1024, 1024);
  // gated = gbuf * silu(y*w_up + b_up) (bf16) -> gated
  gemm8p<3><<<dim3((4096 / 256) * (4096 / 256)), dim3(512), 0, stream>>>(
      y, wupT, gated, b_up, gbuf, nullptr, nullptr, 4096, 4096, 1024, 1024);
  // down-proj, 8-phase split-K=4 (Kl=1024) -> pd0/pd1; combine + bias + residual -> out
  gemm8p<0><<<dim3(4 * 16 * 4), dim3(512), 0, stream>>>(
      gated, wdownT, nullptr, nullptr, nullptr, pd0, pd1, 4096, 1024, 4096, 1024);
  combine4<<<4096, blk, 0, stream>>>(pd0, pd1, x1, b_down, out);
}

// Round 8
// 283.779 us; speedup vs baseline: 1.5292x; 1.0123x over previous
//
#include <hip/hip_runtime.h>

typedef unsigned short u16;
typedef unsigned long long u64;
typedef __attribute__((ext_vector_type(8))) short bf16x8;
typedef __attribute__((ext_vector_type(4))) float f32x4;

__device__ inline u16 f2bf(float f) {
  unsigned int u = __float_as_uint(f);
  u += 0x7fffu + ((u >> 16) & 1u);
  return (u16)(u >> 16);
}
__device__ inline float bf2f(u16 h) { return __uint_as_float(((unsigned int)h) << 16); }

__device__ inline void gload_lds16(const void* gp, void* lp) {
  __builtin_amdgcn_global_load_lds(
      (const __attribute__((address_space(1))) unsigned int*)gp,
      (__attribute__((address_space(3))) unsigned int*)lp, 16, 0, 0);
}

// ---------------- LayerNorm: f32 [rows][1024] -> bf16 ----------------
__global__ __launch_bounds__(256) void ln_kernel(const float* __restrict__ x,
                                                 const float* __restrict__ g,
                                                 const float* __restrict__ beta,
                                                 u16* __restrict__ y) {
  __shared__ float red[8];
  const int row = blockIdx.x;
  const int t = threadIdx.x;
  const float4 xv = *(const float4*)(x + (long)row * 1024 + t * 4);
  float s = xv.x + xv.y + xv.z + xv.w;
  float sq = xv.x * xv.x + xv.y * xv.y + xv.z * xv.z + xv.w * xv.w;
#pragma unroll
  for (int d = 1; d < 64; d <<= 1) {
    s += __shfl_xor(s, d);
    sq += __shfl_xor(sq, d);
  }
  if ((t & 63) == 0) { red[t >> 6] = s; red[4 + (t >> 6)] = sq; }
  __syncthreads();
  s = red[0] + red[1] + red[2] + red[3];
  sq = red[4] + red[5] + red[6] + red[7];
  const float mean = s * (1.f / 1024.f);
  const float var = sq * (1.f / 1024.f) - mean * mean;
  const float inv = rsqrtf(var + 1e-5f);
  float xe[4] = {xv.x, xv.y, xv.z, xv.w};
  u16 ov[4];
#pragma unroll
  for (int e = 0; e < 4; ++e)
    ov[e] = f2bf((xe[e] - mean) * inv * g[t * 4 + e] + beta[t * 4 + e]);
  *(u64*)(y + (long)row * 1024 + t * 4) = *(u64*)ov;
}

// ------------- transpose + convert: f32 in[R][C] -> bf16 out[C][R] -------------
__global__ __launch_bounds__(256) void transpose_bf16(const float* __restrict__ in,
                                                      u16* __restrict__ out,
                                                      int R, int C) {
  __shared__ float tile[64][33];
  const int t = threadIdx.x;
  const int tx = t & 31, ty = t >> 5;
  const int rx = t & 63, cy = t >> 6;
  const long r0 = (long)blockIdx.y * 64, c0 = (long)blockIdx.x * 32;
#pragma unroll
  for (int i = 0; i < 8; ++i)
    tile[ty + i * 8][tx] = in[(r0 + ty + i * 8) * C + c0 + tx];
  __syncthreads();
#pragma unroll
  for (int i = 0; i < 8; ++i)
    out[(c0 + i * 4 + cy) * R + r0 + rx] = f2bf(tile[rx][i * 4 + cy]);
}

// ------------- RoPE cos/sin table: tbl[0..65535]=cos(s,d0), [65536..]=sin -------------
__global__ __launch_bounds__(256) void trig_kernel(float* __restrict__ tbl) {
  const int i = blockIdx.x * 256 + threadIdx.x;   // 65536 = 2048 s x 32 d0
  const int s = i >> 5, d0 = i & 31;
  const float inv = exp2f((float)d0 * (-13.287712379549449f / 32.f));
  float sn, cs;
  sincosf((float)s * inv, &sn, &cs);
  tbl[i] = cs;
  tbl[65536 + i] = sn;
}

// ------------- local-causal flash attention, window 256, hd=64, H=16 -------------
__global__ __launch_bounds__(64, 4) void attn_kernel(const u16* __restrict__ qr,
                                                     const u16* __restrict__ kr,
                                                     const u16* __restrict__ vt,
                                                     u16* __restrict__ o) {
  __shared__ __attribute__((aligned(16))) u16 Pl[16][40];
  int wg = blockIdx.x;
  wg = (wg & 7) * 512 + (wg >> 3);
  const int qt = wg & 127;
  const int bh = wg >> 7;
  const int qs = qt * 16;
  const int l = threadIdx.x;
  const int lr = l & 15, lg = l >> 4;
  const long bho = (long)(bh >> 4) * 2048 * 1024 + (long)(bh & 15) * 64;
  const long vtb = (long)bh * 64 * 2048;

  const u16* qp = qr + bho + (long)(qs + lr) * 1024 + lg * 8;
  const bf16x8 aq0 = *(const bf16x8*)qp;
  const bf16x8 aq1 = *(const bf16x8*)(qp + 32);

  f32x4 oacc[4];
#pragma unroll
  for (int nt = 0; nt < 4; ++nt) { oacc[nt][0] = 0.f; oacc[nt][1] = 0.f; oacc[nt][2] = 0.f; oacc[nt][3] = 0.f; }
  float m_[4], ls[4];
#pragma unroll
  for (int r = 0; r < 4; ++r) { m_[r] = -1e30f; ls[r] = 0.f; }

  for (int ch = 0; ch < 9; ++ch) {
    const int j0 = qs - 256 + ch * 32;
    if (j0 + 32 <= 0) continue;

    const int jc0u = j0 + lr;
    const int jc1u = j0 + 16 + lr;
    const int jc0 = min(max(jc0u, 0), 2047);
    const int jc1 = min(max(jc1u, 0), 2047);
    const u16* kp0 = kr + bho + (long)jc0 * 1024 + lg * 8;
    const u16* kp1 = kr + bho + (long)jc1 * 1024 + lg * 8;
    const bf16x8 b00 = *(const bf16x8*)kp0;
    const bf16x8 b01 = *(const bf16x8*)(kp0 + 32);
    const bf16x8 b10 = *(const bf16x8*)kp1;
    const bf16x8 b11 = *(const bf16x8*)(kp1 + 32);

    f32x4 z; z[0] = 0.f; z[1] = 0.f; z[2] = 0.f; z[3] = 0.f;
    f32x4 s0 = __builtin_amdgcn_mfma_f32_16x16x32_bf16(aq0, b00, z, 0, 0, 0);
    s0 = __builtin_amdgcn_mfma_f32_16x16x32_bf16(aq1, b01, s0, 0, 0, 0);
    f32x4 s1 = __builtin_amdgcn_mfma_f32_16x16x32_bf16(aq0, b10, z, 0, 0, 0);
    s1 = __builtin_amdgcn_mfma_f32_16x16x32_bf16(aq1, b11, s1, 0, 0, 0);

    float p0[4], p1[4], al[4];
#pragma unroll
    for (int r = 0; r < 4; ++r) {
      const int qg = qs + lg * 4 + r;
      const bool v0 = (jc0u >= 0) & (jc0u <= qg) & (qg - jc0u <= 256);
      const bool v1 = (jc1u >= 0) & (jc1u <= qg) & (qg - jc1u <= 256);
      const float t0 = v0 ? s0[r] : -1e30f;
      const float t1 = v1 ? s1[r] : -1e30f;
      float mx = fmaxf(t0, t1);
      mx = fmaxf(mx, __shfl_xor(mx, 1));
      mx = fmaxf(mx, __shfl_xor(mx, 2));
      mx = fmaxf(mx, __shfl_xor(mx, 4));
      mx = fmaxf(mx, __shfl_xor(mx, 8));
      const float mn = fmaxf(m_[r], mx);
      if (mn < -1e29f) {
        al[r] = 1.f; p0[r] = 0.f; p1[r] = 0.f;
      } else {
        al[r] = __expf(m_[r] - mn);
        p0[r] = (t0 < -1e29f) ? 0.f : __expf(t0 - mn);
        p1[r] = (t1 < -1e29f) ? 0.f : __expf(t1 - mn);
      }
      m_[r] = mn;
      float rs = p0[r] + p1[r];
      rs += __shfl_xor(rs, 1);
      rs += __shfl_xor(rs, 2);
      rs += __shfl_xor(rs, 4);
      rs += __shfl_xor(rs, 8);
      ls[r] = ls[r] * al[r] + rs;
    }
#pragma unroll
    for (int r = 0; r < 4; ++r) {
      Pl[lg * 4 + r][lr] = f2bf(p0[r]);
      Pl[lg * 4 + r][lr + 16] = f2bf(p1[r]);
    }
    asm volatile("s_waitcnt lgkmcnt(0)" ::: "memory");
    const bf16x8 pa = *(const bf16x8*)(&Pl[lr][lg * 8]);

    const int jb = min(max(j0 + lg * 8, 0), 2040);
    const u16* vp = vt + vtb + (long)lr * 2048 + jb;
#pragma unroll
    for (int nt = 0; nt < 4; ++nt) {
      const bf16x8 bv = *(const bf16x8*)(vp + (long)(nt * 16) * 2048);
      f32x4 oa = oacc[nt];
#pragma unroll
      for (int r = 0; r < 4; ++r) oa[r] *= al[r];
      oacc[nt] = __builtin_amdgcn_mfma_f32_16x16x32_bf16(pa, bv, oa, 0, 0, 0);
    }
  }
#pragma unroll
  for (int nt = 0; nt < 4; ++nt)
#pragma unroll
    for (int r = 0; r < 4; ++r) {
      const long qg = qs + lg * 4 + r;
      o[bho + qg * 1024 + nt * 16 + lr] = f2bf(oacc[nt][r] / ls[r]);
    }
}

// ========== 256x256 8-phase GEMM, BK=64, A triple-buffered (160 KiB LDS) ==========
// C = A[M,Kfull](cols koff..koff+Kl) * BT[N,Kfull]^T, koff = z*Kl, z = blk/(nbx*nby)
// LDS (u16): A buf b at b*16384 (halves +0/+8192, b=0..2); B buf p at 49152+p*16384.
// Steady-state wait: vmcnt(8) = this tile's 8 loads in flight, all older landed.
// EPI: 5=bf16 plain, 2=bf16 +bias, 3=bf16 gate*silu(acc+bias), 0=f32 split-K partials,
//      6=qkv fused rope epilogue (Cb=qr, P1=kr, P2=vt[bh][64][2048], tbl=cos/sin)
__device__ __forceinline__ void stage_half(u16* lds, int ldsbase,
                                           const u16* gp, int ld, int col,
                                           int tid, int w) {
  const int r0 = tid >> 3;
  const int sw = ((tid & 7) ^ (r0 & 7)) << 3;
  gload_lds16(gp + (long)r0 * ld + col + sw, lds + ldsbase + w * 512);
  gload_lds16(gp + (long)(r0 + 64) * ld + col + sw, lds + ldsbase + 4096 + w * 512);
}

template <int EPI>
__global__ __launch_bounds__(512, 2) void gemm8p(const u16* __restrict__ A,
                                                 const u16* __restrict__ BT,
                                                 u16* __restrict__ Cb,
                                                 const float* __restrict__ bias,
                                                 const u16* __restrict__ gate,
                                                 float* __restrict__ Cf0,
                                                 float* __restrict__ Cf1,
                                                 u16* __restrict__ P1,
                                                 u16* __restrict__ P2,
                                                 const float* __restrict__ tbl,
                                                 int M, int N, int Kfull, int Kl) {
  __shared__ __attribute__((aligned(16))) u16 lds[81920];   // 160 KiB
  const int tid = threadIdx.x;
  const int w = tid >> 6, l = tid & 63;
  const int lr = l & 15, lg = l >> 4;
  const int l7 = l & 7;
  const int wr = w >> 2, wc = w & 3;
  const int nbx = N >> 8, nby = M >> 8;
  int wg = blockIdx.x;
  { const int cpx = gridDim.x >> 3; wg = (wg & 7) * cpx + (wg >> 3); }
  const int z = wg / (nbx * nby);
  const int rem = wg % (nbx * nby);
  const long m0 = (long)(rem / nbx) * 256;
  const long n0 = (long)(rem % nbx) * 256;
  const long koff = (long)z * Kl;
  const int NT = Kl >> 6;

  f32x4 acc[8][4];
#pragma unroll
  for (int i = 0; i < 8; ++i)
#pragma unroll
    for (int j = 0; j < 4; ++j) { acc[i][j][0] = 0.f; acc[i][j][1] = 0.f; acc[i][j][2] = 0.f; acc[i][j][3] = 0.f; }

  const u16* Alo = A + m0 * Kfull + koff;
  const u16* Ahi = A + (m0 + 128) * Kfull + koff;
  const u16* Blo = BT + n0 * Kfull + koff;
  const u16* Bhi = BT + (n0 + 128) * Kfull + koff;

  // prologue: A(0), B(0), A(1), B(1) — oldest-first so vmcnt(8) releases A0/B0
  stage_half(lds, 0, Alo, Kfull, 0, tid, w);
  stage_half(lds, 8192, Ahi, Kfull, 0, tid, w);
  stage_half(lds, 49152, Blo, Kfull, 0, tid, w);
  stage_half(lds, 57344, Bhi, Kfull, 0, tid, w);
  stage_half(lds, 16384, Alo, Kfull, 64, tid, w);
  stage_half(lds, 24576, Ahi, Kfull, 64, tid, w);
  stage_half(lds, 65536, Blo, Kfull, 64, tid, w);
  stage_half(lds, 73728, Bhi, Kfull, 64, tid, w);
  asm volatile("s_waitcnt vmcnt(8)" ::: "memory");
  __builtin_amdgcn_s_barrier();

  for (int t = 0; t < NT; ++t) {
    const int abuf = t % 3;
    int sA = abuf + 2; if (sA >= 3) sA -= 3;     // (t+2)%3
    const int p = t & 1;
    const int baA = abuf * 16384 + wr * 8192;
    const int bB = 49152 + p * 16384;
    bf16x8 b[4][2];
#pragma unroll
    for (int q = 0; q < 4; ++q) {
      bf16x8 a[2][2];
#pragma unroll
      for (int m2 = 0; m2 < 2; ++m2) {
        const int rowA = (q * 2 + m2) * 16 + lr;
#pragma unroll
        for (int kh = 0; kh < 2; ++kh)
          a[m2][kh] = *(const bf16x8*)(lds + baA + rowA * 64 + (((kh * 4 + lg) ^ l7) << 3));
      }
      if (q == 0) {
#pragma unroll
        for (int fn = 0; fn < 4; ++fn) {
          const int rb = wc * 64 + fn * 16 + lr;
#pragma unroll
          for (int kh = 0; kh < 2; ++kh)
            b[fn][kh] = *(const bf16x8*)(lds + bB + (rb >> 7) * 8192 + (rb & 127) * 64 + (((kh * 4 + lg) ^ l7) << 3));
        }
      }
      // stage tile t+2 (A into 3rd buffer, B into same-parity buffer)
      if (t + 2 < NT) {
        if (q == 0) stage_half(lds, sA * 16384, Alo, Kfull, (t + 2) * 64, tid, w);
        if (q == 1) stage_half(lds, sA * 16384 + 8192, Ahi, Kfull, (t + 2) * 64, tid, w);
        if (q == 2) stage_half(lds, bB, Blo, Kfull, (t + 2) * 64, tid, w);
        if (q == 3) stage_half(lds, bB + 8192, Bhi, Kfull, (t + 2) * 64, tid, w);
      }

      __builtin_amdgcn_s_barrier();
      asm volatile("s_waitcnt lgkmcnt(0)" ::: "memory");
      __builtin_amdgcn_s_setprio(1);
#pragma unroll
      for (int m2 = 0; m2 < 2; ++m2)
#pragma unroll
        for (int fn = 0; fn < 4; ++fn)
#pragma unroll
          for (int kh = 0; kh < 2; ++kh)
            acc[q * 2 + m2][fn] = __builtin_amdgcn_mfma_f32_16x16x32_bf16(a[m2][kh], b[fn][kh], acc[q * 2 + m2][fn], 0, 0, 0);
      __builtin_amdgcn_s_setprio(0);
      if (q == 3) {
        if (t + 2 < NT) { asm volatile("s_waitcnt vmcnt(8)" ::: "memory"); }
        else            { asm volatile("s_waitcnt vmcnt(0)" ::: "memory"); }
      }
      __builtin_amdgcn_s_barrier();
    }
  }

  if constexpr (EPI == 6) {
    // fused RoPE epilogue for qkv: regions (by n-range) Q | K | V
    const int regn = (int)((n0 + wc * 64) >> 10);   // 0=Q, 1=K, else V
    if (regn < 2) {
      const float scale = (regn == 0) ? 0.125f : 1.f;
      u16* dst = (regn == 0) ? Cb : P1;
      const int cbase = (int)(n0 & 1023) + wc * 64 + lr;
#pragma unroll
      for (int fm = 0; fm < 8; ++fm) {
        const long mr = m0 + wr * 128 + fm * 16 + lg * 4;
#pragma unroll
        for (int fn = 0; fn < 2; ++fn) {
          const int c1 = cbase + fn * 16;
          const int d0 = fn * 16 + lr;
#pragma unroll
          for (int r = 0; r < 4; ++r) {
            const long row = mr + r;
            const int s = (int)(row & 2047);
            const float cs = tbl[(s << 5) + d0];
            const float sn = tbl[65536 + (s << 5) + d0];
            const float x1v = acc[fm][fn][r], x2v = acc[fm][fn + 2][r];
            dst[row * 1024 + c1] = f2bf((x1v * cs - x2v * sn) * scale);
            dst[row * 1024 + c1 + 32] = f2bf((x2v * cs + x1v * sn) * scale);
          }
        }
      }
    } else {
      // V -> vt[b*16+h][d][s], 4 consecutive s per acc vector
#pragma unroll
      for (int fm = 0; fm < 8; ++fm) {
        const long mr = m0 + wr * 128 + fm * 16 + lg * 4;
        const int bb = (int)(mr >> 11);
        const int s = (int)(mr & 2047);
#pragma unroll
        for (int fn = 0; fn < 4; ++fn) {
          const int ncv = (int)(n0 - 2048) + wc * 64 + fn * 16 + lr;
          const int h = ncv >> 6, d = ncv & 63;
          u16 pk[4];
#pragma unroll
          for (int r = 0; r < 4; ++r) pk[r] = f2bf(acc[fm][fn][r]);
          *(u64*)(P2 + (long)(bb * 16 + h) * 131072 + (long)d * 2048 + s) = *(u64*)pk;
        }
      }
    }
    return;
  }

  float* Cf = nullptr;
  if constexpr (EPI == 0) Cf = (z < 2 ? Cf0 : Cf1) + (long)(z & 1) * M * N;

#pragma unroll
  for (int fm = 0; fm < 8; ++fm) {
    const long mr = m0 + wr * 128 + fm * 16 + lg * 4;
#pragma unroll
    for (int fn = 0; fn < 4; ++fn) {
      const long nc = n0 + wc * 64 + fn * 16 + lr;
#pragma unroll
      for (int r = 0; r < 4; ++r) {
        const long idx = (mr + r) * N + nc;
        const float v = acc[fm][fn][r];
        if constexpr (EPI == 5) {
          Cb[idx] = f2bf(v);
        } else if constexpr (EPI == 2) {
          Cb[idx] = f2bf(v + bias[nc]);
        } else if constexpr (EPI == 3) {
          const float u = v + bias[nc];
          const float sg = 1.f / (1.f + __expf(-u));
          Cb[idx] = f2bf(bf2f(gate[idx]) * u * sg);
        } else if constexpr (EPI == 0) {
          Cf[idx] = v;
        }
      }
    }
  }
}

// ------ combine 4 partials + residual, then LayerNorm -> x1 (f32) and y (bf16) ------
__global__ __launch_bounds__(256) void combine_ln(const float* __restrict__ p0,
                                                  const float* __restrict__ p1,
                                                  const float* __restrict__ x,
                                                  const float* __restrict__ g,
                                                  const float* __restrict__ beta,
                                                  float* __restrict__ x1,
                                                  u16* __restrict__ y) {
  __shared__ float red[8];
  const long MN = (long)4096 * 1024;
  const int row = blockIdx.x;
  const int t = threadIdx.x;
  const long base = (long)row * 1024 + t * 4;
  const float4 a = *(const float4*)(p0 + base);
  const float4 b = *(const float4*)(p0 + MN + base);
  const float4 c = *(const float4*)(p1 + base);
  const float4 d = *(const float4*)(p1 + MN + base);
  const float4 r = *(const float4*)(x + base);
  float v[4] = {a.x + b.x + c.x + d.x + r.x, a.y + b.y + c.y + d.y + r.y,
                a.z + b.z + c.z + d.z + r.z, a.w + b.w + c.w + d.w + r.w};
  *(float4*)(x1 + base) = *(float4*)v;
  float s = v[0] + v[1] + v[2] + v[3];
  float sq = v[0] * v[0] + v[1] * v[1] + v[2] * v[2] + v[3] * v[3];
#pragma unroll
  for (int dd = 1; dd < 64; dd <<= 1) {
    s += __shfl_xor(s, dd);
    sq += __shfl_xor(sq, dd);
  }
  if ((t & 63) == 0) { red[t >> 6] = s; red[4 + (t >> 6)] = sq; }
  __syncthreads();
  s = red[0] + red[1] + red[2] + red[3];
  sq = red[4] + red[5] + red[6] + red[7];
  const float mean = s * (1.f / 1024.f);
  const float var = sq * (1.f / 1024.f) - mean * mean;
  const float inv = rsqrtf(var + 1e-5f);
  u16 ov[4];
#pragma unroll
  for (int e = 0; e < 4; ++e)
    ov[e] = f2bf((v[e] - mean) * inv * g[t * 4 + e] + beta[t * 4 + e]);
  *(u64*)(y + base) = *(u64*)ov;
}

// ------ combine 4 partials + bias + residual -> out (f32) ------
__global__ __launch_bounds__(256) void combine4(const float* __restrict__ p0,
                                                const float* __restrict__ p1,
                                                const float* __restrict__ res,
                                                const float* __restrict__ bias,
                                                float* __restrict__ out) {
  const long MN = (long)4096 * 1024;
  const long i = ((long)blockIdx.x * 256 + threadIdx.x) * 4;
  const float4 a = *(const float4*)(p0 + i);
  const float4 b = *(const float4*)(p0 + MN + i);
  const float4 c = *(const float4*)(p1 + i);
  const float4 d = *(const float4*)(p1 + MN + i);
  const float4 r = *(const float4*)(res + i);
  const float4 bb = *(const float4*)(bias + (int)(i & 1023));
  float4 o;
  o.x = a.x + b.x + c.x + d.x + r.x + bb.x;
  o.y = a.y + b.y + c.y + d.y + r.y + bb.y;
  o.z = a.z + b.z + c.z + d.z + r.z + bb.z;
  o.w = a.w + b.w + c.w + d.w + r.w + bb.w;
  *(float4*)(out + i) = o;
}

extern "C" void kernel_launch(void* const* d_in, const int* in_sizes, int n_in,
                              void* d_out, int out_size, void* d_ws, size_t ws_size,
                              hipStream_t stream) {
  (void)in_sizes; (void)n_in; (void)out_size; (void)ws_size;
  const float* x      = (const float*)d_in[0];
  const float* w_qkv  = (const float*)d_in[1];
  const float* w_out  = (const float*)d_in[2];
  const float* g1     = (const float*)d_in[3];
  const float* b1     = (const float*)d_in[4];
  const float* g2     = (const float*)d_in[5];
  const float* b2     = (const float*)d_in[6];
  const float* w_gate = (const float*)d_in[7];
  const float* b_gate = (const float*)d_in[8];
  const float* w_up   = (const float*)d_in[9];
  const float* b_up   = (const float*)d_in[10];
  const float* w_down = (const float*)d_in[11];
  const float* b_down = (const float*)d_in[12];
  float* out = (float*)d_out;

  // Workspace layout (MB), liveness-checked:
  //  0-8 wdownT | 8-16 y | 16-22 wqkvT | 22-24 woutT | 24-32 wgateT | 32-40 wupT
  //  40-48 qr | 48-56 kr | 56-64 vt | 64-64.5 trig (dead after qkv) | 64-72 o_
  //  out-proj partials: 72-104 (z0,1) + 104-136 (z2,3), dead after combine_ln
  //  x1: 56-72 (vt/o_ dead by combine_ln) | gbuf: 72-104 | gated: 104-136
  //  down partials: pd0 16-48 (weights/qr dead), pd1 72-104 (gbuf dead)
  const size_t MB = 1u << 20;
  char* ws = (char*)d_ws;
  u16*   wdownT = (u16*)(ws + 0 * MB);
  u16*   y      = (u16*)(ws + 8 * MB);
  u16*   wqkvT  = (u16*)(ws + 16 * MB);
  u16*   woutT  = (u16*)(ws + 22 * MB);
  u16*   wgateT = (u16*)(ws + 24 * MB);
  u16*   wupT   = (u16*)(ws + 32 * MB);
  u16*   qr_    = (u16*)(ws + 40 * MB);
  u16*   kr_    = (u16*)(ws + 48 * MB);
  u16*   vt     = (u16*)(ws + 56 * MB);
  float* trig   = (float*)(ws + 64 * MB);
  u16*   o_     = (u16*)(ws + 64 * MB);     // overwrites trig after qkv done
  float* part0  = (float*)(ws + 72 * MB);   // out-proj partials z=0,1
  float* part1  = (float*)(ws + 104 * MB);  // out-proj partials z=2,3
  float* x1     = (float*)(ws + 56 * MB);   // after attn+out-proj, vt/o_ dead
  u16*   gbuf   = (u16*)(ws + 72 * MB);
  u16*   gated  = (u16*)(ws + 104 * MB);
  float* pd0    = (float*)(ws + 16 * MB);   // down partials z=0,1
  float* pd1    = (float*)(ws + 72 * MB);   // down partials z=2,3

  const dim3 blk(256);
  transpose_bf16<<<dim3(3072 / 32, 1024 / 64), blk, 0, stream>>>(w_qkv, wqkvT, 1024, 3072);
  transpose_bf16<<<dim3(1024 / 32, 1024 / 64), blk, 0, stream>>>(w_out, woutT, 1024, 1024);
  transpose_bf16<<<dim3(4096 / 32, 1024 / 64), blk, 0, stream>>>(w_gate, wgateT, 1024, 4096);
  transpose_bf16<<<dim3(4096 / 32, 1024 / 64), blk, 0, stream>>>(w_up, wupT, 1024, 4096);
  transpose_bf16<<<dim3(1024 / 32, 4096 / 64), blk, 0, stream>>>(w_down, wdownT, 4096, 1024);
  trig_kernel<<<256, blk, 0, stream>>>(trig);

  // LN1: x -> y
  ln_kernel<<<4096, blk, 0, stream>>>(x, g1, b1, y);
  // QKV projection + fused RoPE/V-transpose epilogue -> qr, kr, vt
  gemm8p<6><<<dim3((3072 / 256) * (4096 / 256)), dim3(512), 0, stream>>>(
      y, wqkvT, qr_, nullptr, nullptr, nullptr, nullptr, kr_, vt, trig,
      4096, 3072, 1024, 1024);
  // local-causal attention -> o_
  attn_kernel<<<4096, dim3(64), 0, stream>>>(qr_, kr_, vt, o_);
  // out-proj, split-K=4 (Kl=256) -> part0/part1; combine + residual + LN2 -> x1, y
  gemm8p<0><<<dim3(4 * 16 * 4), dim3(512), 0, stream>>>(
      o_, woutT, nullptr, nullptr, nullptr, part0, part1, nullptr, nullptr, nullptr,
      4096, 1024, 1024, 256);
  combine_ln<<<4096, blk, 0, stream>>>(part0, part1, x, g2, b2, x1, y);
  // gate = y*w_gate + b_gate -> gbuf
  gemm8p<2><<<dim3((4096 / 256) * (4096 / 256)), dim3(512), 0, stream>>>(
      y, wgateT, gbuf, b_gate, nullptr, nullptr, nullptr, nullptr, nullptr, nullptr,
      4096, 4096, 1024, 1024);
  // gated = gbuf * silu(y*w_up + b_up)
  gemm8p<3><<<dim3((4096 / 256) * (4096 / 256)), dim3(512), 0, stream>>>(
      y, wupT, gated, b_up, gbuf, nullptr, nullptr, nullptr, nullptr, nullptr,
      4096, 4096, 1024, 1024);
  // down-proj, split-K=4 (Kl=1024) -> pd0/pd1; combine + bias + residual -> out
  gemm8p<0><<<dim3(4 * 16 * 4), dim3(512), 0, stream>>>(
      gated, wdownT, nullptr, nullptr, nullptr, pd0, pd1, nullptr, nullptr, nullptr,
      4096, 1024, 4096, 1024);
  combine4<<<4096, blk, 0, stream>>>(pd0, pd1, x1, b_down, out);
}

// Round 9
// 277.913 us; speedup vs baseline: 1.5615x; 1.0211x over previous
//
#include <hip/hip_runtime.h>

typedef unsigned short u16;
typedef unsigned long long u64;
typedef __attribute__((ext_vector_type(8))) short bf16x8;
typedef __attribute__((ext_vector_type(4))) float f32x4;

__device__ inline u16 f2bf(float f) {
  unsigned int u = __float_as_uint(f);
  u += 0x7fffu + ((u >> 16) & 1u);
  return (u16)(u >> 16);
}
__device__ inline float bf2f(u16 h) { return __uint_as_float(((unsigned int)h) << 16); }

__device__ inline void gload_lds16(const void* gp, void* lp) {
  __builtin_amdgcn_global_load_lds(
      (const __attribute__((address_space(1))) unsigned int*)gp,
      (__attribute__((address_space(3))) unsigned int*)lp, 16, 0, 0);
}

// ---------------- LayerNorm: f32 [rows][1024] -> bf16 ----------------
__global__ __launch_bounds__(256) void ln_kernel(const float* __restrict__ x,
                                                 const float* __restrict__ g,
                                                 const float* __restrict__ beta,
                                                 u16* __restrict__ y) {
  __shared__ float red[8];
  const int row = blockIdx.x;
  const int t = threadIdx.x;
  const float4 xv = *(const float4*)(x + (long)row * 1024 + t * 4);
  float s = xv.x + xv.y + xv.z + xv.w;
  float sq = xv.x * xv.x + xv.y * xv.y + xv.z * xv.z + xv.w * xv.w;
#pragma unroll
  for (int d = 1; d < 64; d <<= 1) {
    s += __shfl_xor(s, d);
    sq += __shfl_xor(sq, d);
  }
  if ((t & 63) == 0) { red[t >> 6] = s; red[4 + (t >> 6)] = sq; }
  __syncthreads();
  s = red[0] + red[1] + red[2] + red[3];
  sq = red[4] + red[5] + red[6] + red[7];
  const float mean = s * (1.f / 1024.f);
  const float var = sq * (1.f / 1024.f) - mean * mean;
  const float inv = rsqrtf(var + 1e-5f);
  float xe[4] = {xv.x, xv.y, xv.z, xv.w};
  u16 ov[4];
#pragma unroll
  for (int e = 0; e < 4; ++e)
    ov[e] = f2bf((xe[e] - mean) * inv * g[t * 4 + e] + beta[t * 4 + e]);
  *(u64*)(y + (long)row * 1024 + t * 4) = *(u64*)ov;
}

// ------------- transpose + convert: f32 in[R][C] -> bf16 out[C][R] -------------
__global__ __launch_bounds__(256) void transpose_bf16(const float* __restrict__ in,
                                                      u16* __restrict__ out,
                                                      int R, int C) {
  __shared__ float tile[64][33];
  const int t = threadIdx.x;
  const int tx = t & 31, ty = t >> 5;
  const int rx = t & 63, cy = t >> 6;
  const long r0 = (long)blockIdx.y * 64, c0 = (long)blockIdx.x * 32;
#pragma unroll
  for (int i = 0; i < 8; ++i)
    tile[ty + i * 8][tx] = in[(r0 + ty + i * 8) * C + c0 + tx];
  __syncthreads();
#pragma unroll
  for (int i = 0; i < 8; ++i)
    out[(c0 + i * 4 + cy) * R + r0 + rx] = f2bf(tile[rx][i * 4 + cy]);
}

// ---- interleaved transpose for gate/up: col c -> row (c>>4)*32 + off + (c&15) ----
__global__ __launch_bounds__(256) void transpose_ilv(const float* __restrict__ in,
                                                     u16* __restrict__ out,
                                                     int R, int C, int off) {
  __shared__ float tile[64][33];
  const int t = threadIdx.x;
  const int tx = t & 31, ty = t >> 5;
  const int rx = t & 63, cy = t >> 6;
  const long r0 = (long)blockIdx.y * 64, c0 = (long)blockIdx.x * 32;
#pragma unroll
  for (int i = 0; i < 8; ++i)
    tile[ty + i * 8][tx] = in[(r0 + ty + i * 8) * C + c0 + tx];
  __syncthreads();
#pragma unroll
  for (int i = 0; i < 8; ++i) {
    const int c = (int)c0 + i * 4 + cy;
    const long v = ((long)(c >> 4) << 5) + off + (c & 15);
    out[v * R + r0 + rx] = f2bf(tile[rx][i * 4 + cy]);
  }
}

// ------------- RoPE cos/sin table: tbl[0..65535]=cos(s,d0), [65536..]=sin -------------
__global__ __launch_bounds__(256) void trig_kernel(float* __restrict__ tbl) {
  const int i = blockIdx.x * 256 + threadIdx.x;   // 65536 = 2048 s x 32 d0
  const int s = i >> 5, d0 = i & 31;
  const float inv = exp2f((float)d0 * (-13.287712379549449f / 32.f));
  float sn, cs;
  sincosf((float)s * inv, &sn, &cs);
  tbl[i] = cs;
  tbl[65536 + i] = sn;
}

// ------------- local-causal flash attention, window 256, hd=64, H=16 -------------
__global__ __launch_bounds__(64, 4) void attn_kernel(const u16* __restrict__ qr,
                                                     const u16* __restrict__ kr,
                                                     const u16* __restrict__ vt,
                                                     u16* __restrict__ o) {
  __shared__ __attribute__((aligned(16))) u16 Pl[16][40];
  int wg = blockIdx.x;
  wg = (wg & 7) * 512 + (wg >> 3);
  const int qt = wg & 127;
  const int bh = wg >> 7;
  const int qs = qt * 16;
  const int l = threadIdx.x;
  const int lr = l & 15, lg = l >> 4;
  const long bho = (long)(bh >> 4) * 2048 * 1024 + (long)(bh & 15) * 64;
  const long vtb = (long)bh * 64 * 2048;

  const u16* qp = qr + bho + (long)(qs + lr) * 1024 + lg * 8;
  const bf16x8 aq0 = *(const bf16x8*)qp;
  const bf16x8 aq1 = *(const bf16x8*)(qp + 32);

  f32x4 oacc[4];
#pragma unroll
  for (int nt = 0; nt < 4; ++nt) { oacc[nt][0] = 0.f; oacc[nt][1] = 0.f; oacc[nt][2] = 0.f; oacc[nt][3] = 0.f; }
  float m_[4], ls[4];
#pragma unroll
  for (int r = 0; r < 4; ++r) { m_[r] = -1e30f; ls[r] = 0.f; }

  for (int ch = 0; ch < 9; ++ch) {
    const int j0 = qs - 256 + ch * 32;
    if (j0 + 32 <= 0) continue;

    const int jc0u = j0 + lr;
    const int jc1u = j0 + 16 + lr;
    const int jc0 = min(max(jc0u, 0), 2047);
    const int jc1 = min(max(jc1u, 0), 2047);
    const u16* kp0 = kr + bho + (long)jc0 * 1024 + lg * 8;
    const u16* kp1 = kr + bho + (long)jc1 * 1024 + lg * 8;
    const bf16x8 b00 = *(const bf16x8*)kp0;
    const bf16x8 b01 = *(const bf16x8*)(kp0 + 32);
    const bf16x8 b10 = *(const bf16x8*)kp1;
    const bf16x8 b11 = *(const bf16x8*)(kp1 + 32);

    f32x4 z; z[0] = 0.f; z[1] = 0.f; z[2] = 0.f; z[3] = 0.f;
    f32x4 s0 = __builtin_amdgcn_mfma_f32_16x16x32_bf16(aq0, b00, z, 0, 0, 0);
    s0 = __builtin_amdgcn_mfma_f32_16x16x32_bf16(aq1, b01, s0, 0, 0, 0);
    f32x4 s1 = __builtin_amdgcn_mfma_f32_16x16x32_bf16(aq0, b10, z, 0, 0, 0);
    s1 = __builtin_amdgcn_mfma_f32_16x16x32_bf16(aq1, b11, s1, 0, 0, 0);

    float p0[4], p1[4], al[4];
#pragma unroll
    for (int r = 0; r < 4; ++r) {
      const int qg = qs + lg * 4 + r;
      const bool v0 = (jc0u >= 0) & (jc0u <= qg) & (qg - jc0u <= 256);
      const bool v1 = (jc1u >= 0) & (jc1u <= qg) & (qg - jc1u <= 256);
      const float t0 = v0 ? s0[r] : -1e30f;
      const float t1 = v1 ? s1[r] : -1e30f;
      float mx = fmaxf(t0, t1);
      mx = fmaxf(mx, __shfl_xor(mx, 1));
      mx = fmaxf(mx, __shfl_xor(mx, 2));
      mx = fmaxf(mx, __shfl_xor(mx, 4));
      mx = fmaxf(mx, __shfl_xor(mx, 8));
      const float mn = fmaxf(m_[r], mx);
      if (mn < -1e29f) {
        al[r] = 1.f; p0[r] = 0.f; p1[r] = 0.f;
      } else {
        al[r] = __expf(m_[r] - mn);
        p0[r] = (t0 < -1e29f) ? 0.f : __expf(t0 - mn);
        p1[r] = (t1 < -1e29f) ? 0.f : __expf(t1 - mn);
      }
      m_[r] = mn;
      float rs = p0[r] + p1[r];
      rs += __shfl_xor(rs, 1);
      rs += __shfl_xor(rs, 2);
      rs += __shfl_xor(rs, 4);
      rs += __shfl_xor(rs, 8);
      ls[r] = ls[r] * al[r] + rs;
    }
#pragma unroll
    for (int r = 0; r < 4; ++r) {
      Pl[lg * 4 + r][lr] = f2bf(p0[r]);
      Pl[lg * 4 + r][lr + 16] = f2bf(p1[r]);
    }
    asm volatile("s_waitcnt lgkmcnt(0)" ::: "memory");
    const bf16x8 pa = *(const bf16x8*)(&Pl[lr][lg * 8]);

    const int jb = min(max(j0 + lg * 8, 0), 2040);
    const u16* vp = vt + vtb + (long)lr * 2048 + jb;
#pragma unroll
    for (int nt = 0; nt < 4; ++nt) {
      const bf16x8 bv = *(const bf16x8*)(vp + (long)(nt * 16) * 2048);
      f32x4 oa = oacc[nt];
#pragma unroll
      for (int r = 0; r < 4; ++r) oa[r] *= al[r];
      oacc[nt] = __builtin_amdgcn_mfma_f32_16x16x32_bf16(pa, bv, oa, 0, 0, 0);
    }
  }
#pragma unroll
  for (int nt = 0; nt < 4; ++nt)
#pragma unroll
    for (int r = 0; r < 4; ++r) {
      const long qg = qs + lg * 4 + r;
      o[bho + qg * 1024 + nt * 16 + lr] = f2bf(oacc[nt][r] / ls[r]);
    }
}

// ========== 256x256 8-phase GEMM, BK=64, A triple-buffered (160 KiB LDS) ==========
// C = A[M,Kfull](cols koff..koff+Kl) * BT[N,Kfull]^T, koff = z*Kl, z = blk/(nbx*nby)
// EPI 0: f32 split-K partials -> (z<2?Cf0:Cf1)+(z&1)*M*N
// EPI 6: qkv fused rope epilogue (Cb=qr, P1=kr, P2=vt[bh][64][2048], tbl=cos/sin)
// EPI 7: fused gate/up (interleaved wguT, N=8192 virtual): out bf16 [M][4096],
//        bias=b_gate, tbl=b_up (as float*), Cb=out
__device__ __forceinline__ void stage_half(u16* lds, int ldsbase,
                                           const u16* gp, int ld, int col,
                                           int tid, int w) {
  const int r0 = tid >> 3;
  const int sw = ((tid & 7) ^ (r0 & 7)) << 3;
  gload_lds16(gp + (long)r0 * ld + col + sw, lds + ldsbase + w * 512);
  gload_lds16(gp + (long)(r0 + 64) * ld + col + sw, lds + ldsbase + 4096 + w * 512);
}

template <int EPI>
__global__ __launch_bounds__(512, 2) void gemm8p(const u16* __restrict__ A,
                                                 const u16* __restrict__ BT,
                                                 u16* __restrict__ Cb,
                                                 const float* __restrict__ bias,
                                                 float* __restrict__ Cf0,
                                                 float* __restrict__ Cf1,
                                                 u16* __restrict__ P1,
                                                 u16* __restrict__ P2,
                                                 const float* __restrict__ tbl,
                                                 int M, int N, int Kfull, int Kl) {
  __shared__ __attribute__((aligned(16))) u16 lds[81920];   // 160 KiB
  const int tid = threadIdx.x;
  const int w = tid >> 6, l = tid & 63;
  const int lr = l & 15, lg = l >> 4;
  const int l7 = l & 7;
  const int wr = w >> 2, wc = w & 3;
  const int nbx = N >> 8, nby = M >> 8;
  int wg = blockIdx.x;
  { const int cpx = gridDim.x >> 3; wg = (wg & 7) * cpx + (wg >> 3); }
  const int z = wg / (nbx * nby);
  const int rem = wg % (nbx * nby);
  const long m0 = (long)(rem / nbx) * 256;
  const long n0 = (long)(rem % nbx) * 256;
  const long koff = (long)z * Kl;
  const int NT = Kl >> 6;

  f32x4 acc[8][4];
#pragma unroll
  for (int i = 0; i < 8; ++i)
#pragma unroll
    for (int j = 0; j < 4; ++j) { acc[i][j][0] = 0.f; acc[i][j][1] = 0.f; acc[i][j][2] = 0.f; acc[i][j][3] = 0.f; }

  const u16* Alo = A + m0 * Kfull + koff;
  const u16* Ahi = A + (m0 + 128) * Kfull + koff;
  const u16* Blo = BT + n0 * Kfull + koff;
  const u16* Bhi = BT + (n0 + 128) * Kfull + koff;

  // prologue: A(0), B(0), A(1), B(1) — oldest-first so vmcnt(8) releases A0/B0
  stage_half(lds, 0, Alo, Kfull, 0, tid, w);
  stage_half(lds, 8192, Ahi, Kfull, 0, tid, w);
  stage_half(lds, 49152, Blo, Kfull, 0, tid, w);
  stage_half(lds, 57344, Bhi, Kfull, 0, tid, w);
  stage_half(lds, 16384, Alo, Kfull, 64, tid, w);
  stage_half(lds, 24576, Ahi, Kfull, 64, tid, w);
  stage_half(lds, 65536, Blo, Kfull, 64, tid, w);
  stage_half(lds, 73728, Bhi, Kfull, 64, tid, w);
  asm volatile("s_waitcnt vmcnt(8)" ::: "memory");
  __builtin_amdgcn_s_barrier();

  for (int t = 0; t < NT; ++t) {
    const int abuf = t % 3;
    int sA = abuf + 2; if (sA >= 3) sA -= 3;     // (t+2)%3
    const int p = t & 1;
    const int baA = abuf * 16384 + wr * 8192;
    const int bB = 49152 + p * 16384;
    bf16x8 b[4][2];
#pragma unroll
    for (int q = 0; q < 4; ++q) {
      bf16x8 a[2][2];
#pragma unroll
      for (int m2 = 0; m2 < 2; ++m2) {
        const int rowA = (q * 2 + m2) * 16 + lr;
#pragma unroll
        for (int kh = 0; kh < 2; ++kh)
          a[m2][kh] = *(const bf16x8*)(lds + baA + rowA * 64 + (((kh * 4 + lg) ^ l7) << 3));
      }
      if (q == 0) {
#pragma unroll
        for (int fn = 0; fn < 4; ++fn) {
          const int rb = wc * 64 + fn * 16 + lr;
#pragma unroll
          for (int kh = 0; kh < 2; ++kh)
            b[fn][kh] = *(const bf16x8*)(lds + bB + (rb >> 7) * 8192 + (rb & 127) * 64 + (((kh * 4 + lg) ^ l7) << 3));
        }
      }
      // stage tile t+2 (A into 3rd buffer, B into same-parity buffer)
      if (t + 2 < NT) {
        if (q == 0) stage_half(lds, sA * 16384, Alo, Kfull, (t + 2) * 64, tid, w);
        if (q == 1) stage_half(lds, sA * 16384 + 8192, Ahi, Kfull, (t + 2) * 64, tid, w);
        if (q == 2) stage_half(lds, bB, Blo, Kfull, (t + 2) * 64, tid, w);
        if (q == 3) stage_half(lds, bB + 8192, Bhi, Kfull, (t + 2) * 64, tid, w);
      }

      __builtin_amdgcn_s_barrier();
      asm volatile("s_waitcnt lgkmcnt(0)" ::: "memory");
      __builtin_amdgcn_s_setprio(1);
#pragma unroll
      for (int m2 = 0; m2 < 2; ++m2)
#pragma unroll
        for (int fn = 0; fn < 4; ++fn)
#pragma unroll
          for (int kh = 0; kh < 2; ++kh)
            acc[q * 2 + m2][fn] = __builtin_amdgcn_mfma_f32_16x16x32_bf16(a[m2][kh], b[fn][kh], acc[q * 2 + m2][fn], 0, 0, 0);
      __builtin_amdgcn_s_setprio(0);
      if (q == 3) {
        if (t + 2 < NT) { asm volatile("s_waitcnt vmcnt(8)" ::: "memory"); }
        else            { asm volatile("s_waitcnt vmcnt(0)" ::: "memory"); }
      }
      __builtin_amdgcn_s_barrier();
    }
  }

  if constexpr (EPI == 6) {
    // fused RoPE epilogue for qkv: regions (by n-range) Q | K | V
    const int regn = (int)((n0 + wc * 64) >> 10);   // 0=Q, 1=K, else V
    if (regn < 2) {
      const float scale = (regn == 0) ? 0.125f : 1.f;
      u16* dst = (regn == 0) ? Cb : P1;
      const int cbase = (int)(n0 & 1023) + wc * 64 + lr;
#pragma unroll
      for (int fm = 0; fm < 8; ++fm) {
        const long mr = m0 + wr * 128 + fm * 16 + lg * 4;
#pragma unroll
        for (int fn = 0; fn < 2; ++fn) {
          const int c1 = cbase + fn * 16;
          const int d0 = fn * 16 + lr;
#pragma unroll
          for (int r = 0; r < 4; ++r) {
            const long row = mr + r;
            const int s = (int)(row & 2047);
            const float cs = tbl[(s << 5) + d0];
            const float sn = tbl[65536 + (s << 5) + d0];
            const float x1v = acc[fm][fn][r], x2v = acc[fm][fn + 2][r];
            dst[row * 1024 + c1] = f2bf((x1v * cs - x2v * sn) * scale);
            dst[row * 1024 + c1 + 32] = f2bf((x2v * cs + x1v * sn) * scale);
          }
        }
      }
    } else {
      // V -> vt[b*16+h][d][s], 4 consecutive s per acc vector
#pragma unroll
      for (int fm = 0; fm < 8; ++fm) {
        const long mr = m0 + wr * 128 + fm * 16 + lg * 4;
        const int bb = (int)(mr >> 11);
        const int s = (int)(mr & 2047);
#pragma unroll
        for (int fn = 0; fn < 4; ++fn) {
          const int ncv = (int)(n0 - 2048) + wc * 64 + fn * 16 + lr;
          const int h = ncv >> 6, d = ncv & 63;
          u16 pk[4];
#pragma unroll
          for (int r = 0; r < 4; ++r) pk[r] = f2bf(acc[fm][fn][r]);
          *(u64*)(P2 + (long)(bb * 16 + h) * 131072 + (long)d * 2048 + s) = *(u64*)pk;
        }
      }
    }
    return;
  }

  if constexpr (EPI == 7) {
    // fused gate/up: virtual col v = n0+wc*64+fn*16+lr; fn even=gate, odd=up;
    // real col rc = base/2 + (fn>>1)*16 + lr; out stride 4096
    const int rcb = (int)((n0 + wc * 64) >> 1);
#pragma unroll
    for (int fm = 0; fm < 8; ++fm) {
      const long mr = m0 + wr * 128 + fm * 16 + lg * 4;
#pragma unroll
      for (int fp = 0; fp < 2; ++fp) {
        const int rc = rcb + fp * 16 + lr;
        const float bg = bias[rc];
        const float bu = tbl[rc];
#pragma unroll
        for (int r = 0; r < 4; ++r) {
          const float g = acc[fm][2 * fp][r] + bg;
          const float u = acc[fm][2 * fp + 1][r] + bu;
          const float sg = 1.f / (1.f + __expf(-u));
          Cb[(mr + r) * 4096 + rc] = f2bf(g * u * sg);
        }
      }
    }
    return;
  }

  float* Cf = (z < 2 ? Cf0 : Cf1) + (long)(z & 1) * M * N;
#pragma unroll
  for (int fm = 0; fm < 8; ++fm) {
    const long mr = m0 + wr * 128 + fm * 16 + lg * 4;
#pragma unroll
    for (int fn = 0; fn < 4; ++fn) {
      const long nc = n0 + wc * 64 + fn * 16 + lr;
#pragma unroll
      for (int r = 0; r < 4; ++r)
        Cf[(mr + r) * N + nc] = acc[fm][fn][r];
    }
  }
}

// ------ combine 4 partials + residual, then LayerNorm -> x1 (f32) and y (bf16) ------
__global__ __launch_bounds__(256) void combine_ln(const float* __restrict__ p0,
                                                  const float* __restrict__ p1,
                                                  const float* __restrict__ x,
                                                  const float* __restrict__ g,
                                                  const float* __restrict__ beta,
                                                  float* __restrict__ x1,
                                                  u16* __restrict__ y) {
  __shared__ float red[8];
  const long MN = (long)4096 * 1024;
  const int row = blockIdx.x;
  const int t = threadIdx.x;
  const long base = (long)row * 1024 + t * 4;
  const float4 a = *(const float4*)(p0 + base);
  const float4 b = *(const float4*)(p0 + MN + base);
  const float4 c = *(const float4*)(p1 + base);
  const float4 d = *(const float4*)(p1 + MN + base);
  const float4 r = *(const float4*)(x + base);
  float v[4] = {a.x + b.x + c.x + d.x + r.x, a.y + b.y + c.y + d.y + r.y,
                a.z + b.z + c.z + d.z + r.z, a.w + b.w + c.w + d.w + r.w};
  *(float4*)(x1 + base) = *(float4*)v;
  float s = v[0] + v[1] + v[2] + v[3];
  float sq = v[0] * v[0] + v[1] * v[1] + v[2] * v[2] + v[3] * v[3];
#pragma unroll
  for (int dd = 1; dd < 64; dd <<= 1) {
    s += __shfl_xor(s, dd);
    sq += __shfl_xor(sq, dd);
  }
  if ((t & 63) == 0) { red[t >> 6] = s; red[4 + (t >> 6)] = sq; }
  __syncthreads();
  s = red[0] + red[1] + red[2] + red[3];
  sq = red[4] + red[5] + red[6] + red[7];
  const float mean = s * (1.f / 1024.f);
  const float var = sq * (1.f / 1024.f) - mean * mean;
  const float inv = rsqrtf(var + 1e-5f);
  u16 ov[4];
#pragma unroll
  for (int e = 0; e < 4; ++e)
    ov[e] = f2bf((v[e] - mean) * inv * g[t * 4 + e] + beta[t * 4 + e]);
  *(u64*)(y + base) = *(u64*)ov;
}

// ------ combine 4 partials + bias + residual -> out (f32) ------
__global__ __launch_bounds__(256) void combine4(const float* __restrict__ p0,
                                                const float* __restrict__ p1,
                                                const float* __restrict__ res,
                                                const float* __restrict__ bias,
                                                float* __restrict__ out) {
  const long MN = (long)4096 * 1024;
  const long i = ((long)blockIdx.x * 256 + threadIdx.x) * 4;
  const float4 a = *(const float4*)(p0 + i);
  const float4 b = *(const float4*)(p0 + MN + i);
  const float4 c = *(const float4*)(p1 + i);
  const float4 d = *(const float4*)(p1 + MN + i);
  const float4 r = *(const float4*)(res + i);
  const float4 bb = *(const float4*)(bias + (int)(i & 1023));
  float4 o;
  o.x = a.x + b.x + c.x + d.x + r.x + bb.x;
  o.y = a.y + b.y + c.y + d.y + r.y + bb.y;
  o.z = a.z + b.z + c.z + d.z + r.z + bb.z;
  o.w = a.w + b.w + c.w + d.w + r.w + bb.w;
  *(float4*)(out + i) = o;
}

extern "C" void kernel_launch(void* const* d_in, const int* in_sizes, int n_in,
                              void* d_out, int out_size, void* d_ws, size_t ws_size,
                              hipStream_t stream) {
  (void)in_sizes; (void)n_in; (void)out_size; (void)ws_size;
  const float* x      = (const float*)d_in[0];
  const float* w_qkv  = (const float*)d_in[1];
  const float* w_out  = (const float*)d_in[2];
  const float* g1     = (const float*)d_in[3];
  const float* b1     = (const float*)d_in[4];
  const float* g2     = (const float*)d_in[5];
  const float* b2     = (const float*)d_in[6];
  const float* w_gate = (const float*)d_in[7];
  const float* b_gate = (const float*)d_in[8];
  const float* w_up   = (const float*)d_in[9];
  const float* b_up   = (const float*)d_in[10];
  const float* w_down = (const float*)d_in[11];
  const float* b_down = (const float*)d_in[12];
  float* out = (float*)d_out;

  // Workspace layout (MB), liveness-checked:
  //  0-8 wdownT | 8-16 y | 16-22 wqkvT | 22-24 woutT | 24-40 wguT (interleaved)
  //  40-48 qr | 48-56 kr | 56-64 vt | 64-64.5 trig (dead after qkv) | 64-72 o_
  //  out-proj partials: 72-104 + 104-136, dead after combine_ln
  //  x1: 56-72 (vt/o_ dead) | gated: 104-136 (part dead)
  //  down partials: pd0 16-48 (wqkvT/woutT/wguT dead by then), pd1 72-104
  const size_t MB = 1u << 20;
  char* ws = (char*)d_ws;
  u16*   wdownT = (u16*)(ws + 0 * MB);
  u16*   y      = (u16*)(ws + 8 * MB);
  u16*   wqkvT  = (u16*)(ws + 16 * MB);
  u16*   woutT  = (u16*)(ws + 22 * MB);
  u16*   wguT   = (u16*)(ws + 24 * MB);     // [8192][1024] interleaved gate/up
  u16*   qr_    = (u16*)(ws + 40 * MB);
  u16*   kr_    = (u16*)(ws + 48 * MB);
  u16*   vt     = (u16*)(ws + 56 * MB);
  float* trig   = (float*)(ws + 64 * MB);
  u16*   o_     = (u16*)(ws + 64 * MB);     // overwrites trig after qkv done
  float* part0  = (float*)(ws + 72 * MB);
  float* part1  = (float*)(ws + 104 * MB);
  float* x1     = (float*)(ws + 56 * MB);
  u16*   gated  = (u16*)(ws + 104 * MB);
  float* pd0    = (float*)(ws + 16 * MB);
  float* pd1    = (float*)(ws + 72 * MB);

  const dim3 blk(256);
  transpose_bf16<<<dim3(3072 / 32, 1024 / 64), blk, 0, stream>>>(w_qkv, wqkvT, 1024, 3072);
  transpose_bf16<<<dim3(1024 / 32, 1024 / 64), blk, 0, stream>>>(w_out, woutT, 1024, 1024);
  transpose_ilv<<<dim3(4096 / 32, 1024 / 64), blk, 0, stream>>>(w_gate, wguT, 1024, 4096, 0);
  transpose_ilv<<<dim3(4096 / 32, 1024 / 64), blk, 0, stream>>>(w_up, wguT, 1024, 4096, 16);
  transpose_bf16<<<dim3(1024 / 32, 4096 / 64), blk, 0, stream>>>(w_down, wdownT, 4096, 1024);
  trig_kernel<<<256, blk, 0, stream>>>(trig);

  // LN1: x -> y
  ln_kernel<<<4096, blk, 0, stream>>>(x, g1, b1, y);
  // QKV projection + fused RoPE/V-transpose epilogue -> qr, kr, vt
  gemm8p<6><<<dim3((3072 / 256) * (4096 / 256)), dim3(512), 0, stream>>>(
      y, wqkvT, qr_, nullptr, nullptr, nullptr, kr_, vt, trig,
      4096, 3072, 1024, 1024);
  // local-causal attention -> o_
  attn_kernel<<<4096, dim3(64), 0, stream>>>(qr_, kr_, vt, o_);
  // out-proj, split-K=4 (Kl=256) -> part0/part1; combine + residual + LN2 -> x1, y
  gemm8p<0><<<dim3(4 * 16 * 4), dim3(512), 0, stream>>>(
      o_, woutT, nullptr, nullptr, part0, part1, nullptr, nullptr, nullptr,
      4096, 1024, 1024, 256);
  combine_ln<<<4096, blk, 0, stream>>>(part0, part1, x, g2, b2, x1, y);
  // fused gate/up dual GEMM (virtual N=8192, interleaved) -> gated bf16 [4096][4096]
  gemm8p<7><<<dim3((8192 / 256) * (4096 / 256)), dim3(512), 0, stream>>>(
      y, wguT, gated, b_gate, nullptr, nullptr, nullptr, nullptr, b_up,
      4096, 8192, 1024, 1024);
  // down-proj, split-K=4 (Kl=1024) -> pd0/pd1; combine + bias + residual -> out
  gemm8p<0><<<dim3(4 * 16 * 4), dim3(512), 0, stream>>>(
      gated, wdownT, nullptr, nullptr, pd0, pd1, nullptr, nullptr, nullptr,
      4096, 1024, 4096, 1024);
  combine4<<<4096, blk, 0, stream>>>(pd0, pd1, x1, b_down, out);
}

// Round 10
// 273.120 us; speedup vs baseline: 1.5889x; 1.0175x over previous
//
#include <hip/hip_runtime.h>

typedef unsigned short u16;
typedef unsigned long long u64;
typedef __attribute__((ext_vector_type(8))) short bf16x8;
typedef __attribute__((ext_vector_type(4))) float f32x4;

__device__ inline u16 f2bf(float f) {
  unsigned int u = __float_as_uint(f);
  u += 0x7fffu + ((u >> 16) & 1u);
  return (u16)(u >> 16);
}
__device__ inline float bf2f(u16 h) { return __uint_as_float(((unsigned int)h) << 16); }

__device__ inline void gload_lds16(const void* gp, void* lp) {
  __builtin_amdgcn_global_load_lds(
      (const __attribute__((address_space(1))) unsigned int*)gp,
      (__attribute__((address_space(3))) unsigned int*)lp, 16, 0, 0);
}

// ---------------- LayerNorm: f32 [rows][1024] -> bf16 ----------------
__global__ __launch_bounds__(256) void ln_kernel(const float* __restrict__ x,
                                                 const float* __restrict__ g,
                                                 const float* __restrict__ beta,
                                                 u16* __restrict__ y) {
  __shared__ float red[8];
  const int row = blockIdx.x;
  const int t = threadIdx.x;
  const float4 xv = *(const float4*)(x + (long)row * 1024 + t * 4);
  float s = xv.x + xv.y + xv.z + xv.w;
  float sq = xv.x * xv.x + xv.y * xv.y + xv.z * xv.z + xv.w * xv.w;
#pragma unroll
  for (int d = 1; d < 64; d <<= 1) {
    s += __shfl_xor(s, d);
    sq += __shfl_xor(sq, d);
  }
  if ((t & 63) == 0) { red[t >> 6] = s; red[4 + (t >> 6)] = sq; }
  __syncthreads();
  s = red[0] + red[1] + red[2] + red[3];
  sq = red[4] + red[5] + red[6] + red[7];
  const float mean = s * (1.f / 1024.f);
  const float var = sq * (1.f / 1024.f) - mean * mean;
  const float inv = rsqrtf(var + 1e-5f);
  float xe[4] = {xv.x, xv.y, xv.z, xv.w};
  u16 ov[4];
#pragma unroll
  for (int e = 0; e < 4; ++e)
    ov[e] = f2bf((xe[e] - mean) * inv * g[t * 4 + e] + beta[t * 4 + e]);
  *(u64*)(y + (long)row * 1024 + t * 4) = *(u64*)ov;
}

// ------------- transpose + convert: f32 in[R][C] -> bf16 out[C][R] -------------
__global__ __launch_bounds__(256) void transpose_bf16(const float* __restrict__ in,
                                                      u16* __restrict__ out,
                                                      int R, int C) {
  __shared__ float tile[64][33];
  const int t = threadIdx.x;
  const int tx = t & 31, ty = t >> 5;
  const int rx = t & 63, cy = t >> 6;
  const long r0 = (long)blockIdx.y * 64, c0 = (long)blockIdx.x * 32;
#pragma unroll
  for (int i = 0; i < 8; ++i)
    tile[ty + i * 8][tx] = in[(r0 + ty + i * 8) * C + c0 + tx];
  __syncthreads();
#pragma unroll
  for (int i = 0; i < 8; ++i)
    out[(c0 + i * 4 + cy) * R + r0 + rx] = f2bf(tile[rx][i * 4 + cy]);
}

// ---- interleaved transpose for gate/up: col c -> row (c>>4)*32 + off + (c&15) ----
__global__ __launch_bounds__(256) void transpose_ilv(const float* __restrict__ in,
                                                     u16* __restrict__ out,
                                                     int R, int C, int off) {
  __shared__ float tile[64][33];
  const int t = threadIdx.x;
  const int tx = t & 31, ty = t >> 5;
  const int rx = t & 63, cy = t >> 6;
  const long r0 = (long)blockIdx.y * 64, c0 = (long)blockIdx.x * 32;
#pragma unroll
  for (int i = 0; i < 8; ++i)
    tile[ty + i * 8][tx] = in[(r0 + ty + i * 8) * C + c0 + tx];
  __syncthreads();
#pragma unroll
  for (int i = 0; i < 8; ++i) {
    const int c = (int)c0 + i * 4 + cy;
    const long v = ((long)(c >> 4) << 5) + off + (c & 15);
    out[v * R + r0 + rx] = f2bf(tile[rx][i * 4 + cy]);
  }
}

// ------------- RoPE cos/sin table: tbl[0..65535]=cos(s,d0), [65536..]=sin -------------
__global__ __launch_bounds__(256) void trig_kernel(float* __restrict__ tbl) {
  const int i = blockIdx.x * 256 + threadIdx.x;   // 65536 = 2048 s x 32 d0
  const int s = i >> 5, d0 = i & 31;
  const float inv = exp2f((float)d0 * (-13.287712379549449f / 32.f));
  float sn, cs;
  sincosf((float)s * inv, &sn, &cs);
  tbl[i] = cs;
  tbl[65536 + i] = sn;
}

// ------------- local-causal flash attention, window 256, hd=64, H=16 -------------
__global__ __launch_bounds__(64, 4) void attn_kernel(const u16* __restrict__ qr,
                                                     const u16* __restrict__ kr,
                                                     const u16* __restrict__ vt,
                                                     u16* __restrict__ o) {
  __shared__ __attribute__((aligned(16))) u16 Pl[16][40];
  int wg = blockIdx.x;
  wg = (wg & 7) * 512 + (wg >> 3);
  const int qt = wg & 127;
  const int bh = wg >> 7;
  const int qs = qt * 16;
  const int l = threadIdx.x;
  const int lr = l & 15, lg = l >> 4;
  const long bho = (long)(bh >> 4) * 2048 * 1024 + (long)(bh & 15) * 64;
  const long vtb = (long)bh * 64 * 2048;

  const u16* qp = qr + bho + (long)(qs + lr) * 1024 + lg * 8;
  const bf16x8 aq0 = *(const bf16x8*)qp;
  const bf16x8 aq1 = *(const bf16x8*)(qp + 32);

  f32x4 oacc[4];
#pragma unroll
  for (int nt = 0; nt < 4; ++nt) { oacc[nt][0] = 0.f; oacc[nt][1] = 0.f; oacc[nt][2] = 0.f; oacc[nt][3] = 0.f; }
  float m_[4], ls[4];
#pragma unroll
  for (int r = 0; r < 4; ++r) { m_[r] = -1e30f; ls[r] = 0.f; }

  for (int ch = 0; ch < 9; ++ch) {
    const int j0 = qs - 256 + ch * 32;
    if (j0 + 32 <= 0) continue;

    const int jc0u = j0 + lr;
    const int jc1u = j0 + 16 + lr;
    const int jc0 = min(max(jc0u, 0), 2047);
    const int jc1 = min(max(jc1u, 0), 2047);
    const u16* kp0 = kr + bho + (long)jc0 * 1024 + lg * 8;
    const u16* kp1 = kr + bho + (long)jc1 * 1024 + lg * 8;
    const bf16x8 b00 = *(const bf16x8*)kp0;
    const bf16x8 b01 = *(const bf16x8*)(kp0 + 32);
    const bf16x8 b10 = *(const bf16x8*)kp1;
    const bf16x8 b11 = *(const bf16x8*)(kp1 + 32);

    f32x4 z; z[0] = 0.f; z[1] = 0.f; z[2] = 0.f; z[3] = 0.f;
    f32x4 s0 = __builtin_amdgcn_mfma_f32_16x16x32_bf16(aq0, b00, z, 0, 0, 0);
    s0 = __builtin_amdgcn_mfma_f32_16x16x32_bf16(aq1, b01, s0, 0, 0, 0);
    f32x4 s1 = __builtin_amdgcn_mfma_f32_16x16x32_bf16(aq0, b10, z, 0, 0, 0);
    s1 = __builtin_amdgcn_mfma_f32_16x16x32_bf16(aq1, b11, s1, 0, 0, 0);

    float p0[4], p1[4], al[4];
#pragma unroll
    for (int r = 0; r < 4; ++r) {
      const int qg = qs + lg * 4 + r;
      const bool v0 = (jc0u >= 0) & (jc0u <= qg) & (qg - jc0u <= 256);
      const bool v1 = (jc1u >= 0) & (jc1u <= qg) & (qg - jc1u <= 256);
      const float t0 = v0 ? s0[r] : -1e30f;
      const float t1 = v1 ? s1[r] : -1e30f;
      float mx = fmaxf(t0, t1);
      mx = fmaxf(mx, __shfl_xor(mx, 1));
      mx = fmaxf(mx, __shfl_xor(mx, 2));
      mx = fmaxf(mx, __shfl_xor(mx, 4));
      mx = fmaxf(mx, __shfl_xor(mx, 8));
      const float mn = fmaxf(m_[r], mx);
      if (mn < -1e29f) {
        al[r] = 1.f; p0[r] = 0.f; p1[r] = 0.f;
      } else {
        al[r] = __expf(m_[r] - mn);
        p0[r] = (t0 < -1e29f) ? 0.f : __expf(t0 - mn);
        p1[r] = (t1 < -1e29f) ? 0.f : __expf(t1 - mn);
      }
      m_[r] = mn;
      float rs = p0[r] + p1[r];
      rs += __shfl_xor(rs, 1);
      rs += __shfl_xor(rs, 2);
      rs += __shfl_xor(rs, 4);
      rs += __shfl_xor(rs, 8);
      ls[r] = ls[r] * al[r] + rs;
    }
#pragma unroll
    for (int r = 0; r < 4; ++r) {
      Pl[lg * 4 + r][lr] = f2bf(p0[r]);
      Pl[lg * 4 + r][lr + 16] = f2bf(p1[r]);
    }
    asm volatile("s_waitcnt lgkmcnt(0)" ::: "memory");
    const bf16x8 pa = *(const bf16x8*)(&Pl[lr][lg * 8]);

    const int jb = min(max(j0 + lg * 8, 0), 2040);
    const u16* vp = vt + vtb + (long)lr * 2048 + jb;
#pragma unroll
    for (int nt = 0; nt < 4; ++nt) {
      const bf16x8 bv = *(const bf16x8*)(vp + (long)(nt * 16) * 2048);
      f32x4 oa = oacc[nt];
#pragma unroll
      for (int r = 0; r < 4; ++r) oa[r] *= al[r];
      oacc[nt] = __builtin_amdgcn_mfma_f32_16x16x32_bf16(pa, bv, oa, 0, 0, 0);
    }
  }
#pragma unroll
  for (int nt = 0; nt < 4; ++nt)
#pragma unroll
    for (int r = 0; r < 4; ++r) {
      const long qg = qs + lg * 4 + r;
      o[bho + qg * 1024 + nt * 16 + lr] = f2bf(oacc[nt][r] / ls[r]);
    }
}

// ========== 256x256 8-phase GEMM, BK=64, A triple-buffered (160 KiB LDS) ==========
// C = A[M,Kfull](cols koff..koff+Kl) * BT[N,Kfull]^T, koff = z*Kl, z = blk/(nbx*nby)
// Block mapping: XCD-contiguous chunks + GROUP_M=8 (each 64-block chunk covers an
// ~8m x 8n super-tile -> A+B panel footprint ~8MB, streams through the 4MB L2).
// EPI 0: f32 split-K partials -> (z<2?Cf0:Cf1)+(z&1)*M*N
// EPI 6: qkv fused rope epilogue (Cb=qr, P1=kr, P2=vt[bh][64][2048], tbl=cos/sin)
// EPI 7: fused gate/up (interleaved wguT, N=8192 virtual): out bf16 [M][4096],
//        bias=b_gate, tbl=b_up (as float*), Cb=out
__device__ __forceinline__ void stage_half(u16* lds, int ldsbase,
                                           const u16* gp, int ld, int col,
                                           int tid, int w) {
  const int r0 = tid >> 3;
  const int sw = ((tid & 7) ^ (r0 & 7)) << 3;
  gload_lds16(gp + (long)r0 * ld + col + sw, lds + ldsbase + w * 512);
  gload_lds16(gp + (long)(r0 + 64) * ld + col + sw, lds + ldsbase + 4096 + w * 512);
}

template <int EPI>
__global__ __launch_bounds__(512, 2) void gemm8p(const u16* __restrict__ A,
                                                 const u16* __restrict__ BT,
                                                 u16* __restrict__ Cb,
                                                 const float* __restrict__ bias,
                                                 float* __restrict__ Cf0,
                                                 float* __restrict__ Cf1,
                                                 u16* __restrict__ P1,
                                                 u16* __restrict__ P2,
                                                 const float* __restrict__ tbl,
                                                 int M, int N, int Kfull, int Kl) {
  __shared__ __attribute__((aligned(16))) u16 lds[81920];   // 160 KiB
  const int tid = threadIdx.x;
  const int w = tid >> 6, l = tid & 63;
  const int lr = l & 15, lg = l >> 4;
  const int l7 = l & 7;
  const int wr = w >> 2, wc = w & 3;
  const int nbx = N >> 8, nby = M >> 8;
  int wg = blockIdx.x;
  { const int cpx = gridDim.x >> 3; wg = (wg & 7) * cpx + (wg >> 3); }
  const int z = wg / (nbx * nby);
  const int rem = wg % (nbx * nby);
  // GROUP_M=8 swizzle: consecutive blocks sweep 8 m-rows before advancing n
  const int rr = rem % (8 * nbx);
  const long m0 = (long)((rem / (8 * nbx)) * 8 + (rr & 7)) * 256;
  const long n0 = (long)(rr >> 3) * 256;
  const long koff = (long)z * Kl;
  const int NT = Kl >> 6;

  f32x4 acc[8][4];
#pragma unroll
  for (int i = 0; i < 8; ++i)
#pragma unroll
    for (int j = 0; j < 4; ++j) { acc[i][j][0] = 0.f; acc[i][j][1] = 0.f; acc[i][j][2] = 0.f; acc[i][j][3] = 0.f; }

  const u16* Alo = A + m0 * Kfull + koff;
  const u16* Ahi = A + (m0 + 128) * Kfull + koff;
  const u16* Blo = BT + n0 * Kfull + koff;
  const u16* Bhi = BT + (n0 + 128) * Kfull + koff;

  // prologue: A(0), B(0), A(1), B(1) — oldest-first so vmcnt(8) releases A0/B0
  stage_half(lds, 0, Alo, Kfull, 0, tid, w);
  stage_half(lds, 8192, Ahi, Kfull, 0, tid, w);
  stage_half(lds, 49152, Blo, Kfull, 0, tid, w);
  stage_half(lds, 57344, Bhi, Kfull, 0, tid, w);
  stage_half(lds, 16384, Alo, Kfull, 64, tid, w);
  stage_half(lds, 24576, Ahi, Kfull, 64, tid, w);
  stage_half(lds, 65536, Blo, Kfull, 64, tid, w);
  stage_half(lds, 73728, Bhi, Kfull, 64, tid, w);
  asm volatile("s_waitcnt vmcnt(8)" ::: "memory");
  __builtin_amdgcn_s_barrier();

  for (int t = 0; t < NT; ++t) {
    const int abuf = t % 3;
    int sA = abuf + 2; if (sA >= 3) sA -= 3;     // (t+2)%3
    const int p = t & 1;
    const int baA = abuf * 16384 + wr * 8192;
    const int bB = 49152 + p * 16384;
    bf16x8 b[4][2];
#pragma unroll
    for (int q = 0; q < 4; ++q) {
      bf16x8 a[2][2];
#pragma unroll
      for (int m2 = 0; m2 < 2; ++m2) {
        const int rowA = (q * 2 + m2) * 16 + lr;
#pragma unroll
        for (int kh = 0; kh < 2; ++kh)
          a[m2][kh] = *(const bf16x8*)(lds + baA + rowA * 64 + (((kh * 4 + lg) ^ l7) << 3));
      }
      if (q == 0) {
#pragma unroll
        for (int fn = 0; fn < 4; ++fn) {
          const int rb = wc * 64 + fn * 16 + lr;
#pragma unroll
          for (int kh = 0; kh < 2; ++kh)
            b[fn][kh] = *(const bf16x8*)(lds + bB + (rb >> 7) * 8192 + (rb & 127) * 64 + (((kh * 4 + lg) ^ l7) << 3));
        }
      }
      // stage tile t+2 (A into 3rd buffer, B into same-parity buffer)
      if (t + 2 < NT) {
        if (q == 0) stage_half(lds, sA * 16384, Alo, Kfull, (t + 2) * 64, tid, w);
        if (q == 1) stage_half(lds, sA * 16384 + 8192, Ahi, Kfull, (t + 2) * 64, tid, w);
        if (q == 2) stage_half(lds, bB, Blo, Kfull, (t + 2) * 64, tid, w);
        if (q == 3) stage_half(lds, bB + 8192, Bhi, Kfull, (t + 2) * 64, tid, w);
      }
      if (q == 0) { asm volatile("s_waitcnt lgkmcnt(8)" ::: "memory"); }

      __builtin_amdgcn_s_barrier();
      asm volatile("s_waitcnt lgkmcnt(0)" ::: "memory");
      __builtin_amdgcn_s_setprio(1);
#pragma unroll
      for (int m2 = 0; m2 < 2; ++m2)
#pragma unroll
        for (int fn = 0; fn < 4; ++fn)
#pragma unroll
          for (int kh = 0; kh < 2; ++kh)
            acc[q * 2 + m2][fn] = __builtin_amdgcn_mfma_f32_16x16x32_bf16(a[m2][kh], b[fn][kh], acc[q * 2 + m2][fn], 0, 0, 0);
      __builtin_amdgcn_s_setprio(0);
      if (q == 3) {
        if (t + 2 < NT) { asm volatile("s_waitcnt vmcnt(8)" ::: "memory"); }
        else            { asm volatile("s_waitcnt vmcnt(0)" ::: "memory"); }
      }
      __builtin_amdgcn_s_barrier();
    }
  }

  if constexpr (EPI == 6) {
    // fused RoPE epilogue for qkv: regions (by n-range) Q | K | V
    const int regn = (int)((n0 + wc * 64) >> 10);   // 0=Q, 1=K, else V
    if (regn < 2) {
      const float scale = (regn == 0) ? 0.125f : 1.f;
      u16* dst = (regn == 0) ? Cb : P1;
      const int cbase = (int)(n0 & 1023) + wc * 64 + lr;
#pragma unroll
      for (int fm = 0; fm < 8; ++fm) {
        const long mr = m0 + wr * 128 + fm * 16 + lg * 4;
#pragma unroll
        for (int fn = 0; fn < 2; ++fn) {
          const int c1 = cbase + fn * 16;
          const int d0 = fn * 16 + lr;
#pragma unroll
          for (int r = 0; r < 4; ++r) {
            const long row = mr + r;
            const int s = (int)(row & 2047);
            const float cs = tbl[(s << 5) + d0];
            const float sn = tbl[65536 + (s << 5) + d0];
            const float x1v = acc[fm][fn][r], x2v = acc[fm][fn + 2][r];
            dst[row * 1024 + c1] = f2bf((x1v * cs - x2v * sn) * scale);
            dst[row * 1024 + c1 + 32] = f2bf((x2v * cs + x1v * sn) * scale);
          }
        }
      }
    } else {
      // V -> vt[b*16+h][d][s], 4 consecutive s per acc vector
#pragma unroll
      for (int fm = 0; fm < 8; ++fm) {
        const long mr = m0 + wr * 128 + fm * 16 + lg * 4;
        const int bb = (int)(mr >> 11);
        const int s = (int)(mr & 2047);
#pragma unroll
        for (int fn = 0; fn < 4; ++fn) {
          const int ncv = (int)(n0 - 2048) + wc * 64 + fn * 16 + lr;
          const int h = ncv >> 6, d = ncv & 63;
          u16 pk[4];
#pragma unroll
          for (int r = 0; r < 4; ++r) pk[r] = f2bf(acc[fm][fn][r]);
          *(u64*)(P2 + (long)(bb * 16 + h) * 131072 + (long)d * 2048 + s) = *(u64*)pk;
        }
      }
    }
    return;
  }

  if constexpr (EPI == 7) {
    // fused gate/up: virtual col v = n0+wc*64+fn*16+lr; fn even=gate, odd=up;
    // real col rc = base/2 + (fn>>1)*16 + lr; out stride 4096
    const int rcb = (int)((n0 + wc * 64) >> 1);
#pragma unroll
    for (int fm = 0; fm < 8; ++fm) {
      const long mr = m0 + wr * 128 + fm * 16 + lg * 4;
#pragma unroll
      for (int fp = 0; fp < 2; ++fp) {
        const int rc = rcb + fp * 16 + lr;
        const float bg = bias[rc];
        const float bu = tbl[rc];
#pragma unroll
        for (int r = 0; r < 4; ++r) {
          const float g = acc[fm][2 * fp][r] + bg;
          const float u = acc[fm][2 * fp + 1][r] + bu;
          const float sg = 1.f / (1.f + __expf(-u));
          Cb[(mr + r) * 4096 + rc] = f2bf(g * u * sg);
        }
      }
    }
    return;
  }

  float* Cf = (z < 2 ? Cf0 : Cf1) + (long)(z & 1) * M * N;
#pragma unroll
  for (int fm = 0; fm < 8; ++fm) {
    const long mr = m0 + wr * 128 + fm * 16 + lg * 4;
#pragma unroll
    for (int fn = 0; fn < 4; ++fn) {
      const long nc = n0 + wc * 64 + fn * 16 + lr;
#pragma unroll
      for (int r = 0; r < 4; ++r)
        Cf[(mr + r) * N + nc] = acc[fm][fn][r];
    }
  }
}

// ------ combine 4 partials + residual, then LayerNorm -> x1 (f32) and y (bf16) ------
__global__ __launch_bounds__(256) void combine_ln(const float* __restrict__ p0,
                                                  const float* __restrict__ p1,
                                                  const float* __restrict__ x,
                                                  const float* __restrict__ g,
                                                  const float* __restrict__ beta,
                                                  float* __restrict__ x1,
                                                  u16* __restrict__ y) {
  __shared__ float red[8];
  const long MN = (long)4096 * 1024;
  const int row = blockIdx.x;
  const int t = threadIdx.x;
  const long base = (long)row * 1024 + t * 4;
  const float4 a = *(const float4*)(p0 + base);
  const float4 b = *(const float4*)(p0 + MN + base);
  const float4 c = *(const float4*)(p1 + base);
  const float4 d = *(const float4*)(p1 + MN + base);
  const float4 r = *(const float4*)(x + base);
  float v[4] = {a.x + b.x + c.x + d.x + r.x, a.y + b.y + c.y + d.y + r.y,
                a.z + b.z + c.z + d.z + r.z, a.w + b.w + c.w + d.w + r.w};
  *(float4*)(x1 + base) = *(float4*)v;
  float s = v[0] + v[1] + v[2] + v[3];
  float sq = v[0] * v[0] + v[1] * v[1] + v[2] * v[2] + v[3] * v[3];
#pragma unroll
  for (int dd = 1; dd < 64; dd <<= 1) {
    s += __shfl_xor(s, dd);
    sq += __shfl_xor(sq, dd);
  }
  if ((t & 63) == 0) { red[t >> 6] = s; red[4 + (t >> 6)] = sq; }
  __syncthreads();
  s = red[0] + red[1] + red[2] + red[3];
  sq = red[4] + red[5] + red[6] + red[7];
  const float mean = s * (1.f / 1024.f);
  const float var = sq * (1.f / 1024.f) - mean * mean;
  const float inv = rsqrtf(var + 1e-5f);
  u16 ov[4];
#pragma unroll
  for (int e = 0; e < 4; ++e)
    ov[e] = f2bf((v[e] - mean) * inv * g[t * 4 + e] + beta[t * 4 + e]);
  *(u64*)(y + base) = *(u64*)ov;
}

// ------ combine 4 partials + bias + residual -> out (f32) ------
__global__ __launch_bounds__(256) void combine4(const float* __restrict__ p0,
                                                const float* __restrict__ p1,
                                                const float* __restrict__ res,
                                                const float* __restrict__ bias,
                                                float* __restrict__ out) {
  const long MN = (long)4096 * 1024;
  const long i = ((long)blockIdx.x * 256 + threadIdx.x) * 4;
  const float4 a = *(const float4*)(p0 + i);
  const float4 b = *(const float4*)(p0 + MN + i);
  const float4 c = *(const float4*)(p1 + i);
  const float4 d = *(const float4*)(p1 + MN + i);
  const float4 r = *(const float4*)(res + i);
  const float4 bb = *(const float4*)(bias + (int)(i & 1023));
  float4 o;
  o.x = a.x + b.x + c.x + d.x + r.x + bb.x;
  o.y = a.y + b.y + c.y + d.y + r.y + bb.y;
  o.z = a.z + b.z + c.z + d.z + r.z + bb.z;
  o.w = a.w + b.w + c.w + d.w + r.w + bb.w;
  *(float4*)(out + i) = o;
}

extern "C" void kernel_launch(void* const* d_in, const int* in_sizes, int n_in,
                              void* d_out, int out_size, void* d_ws, size_t ws_size,
                              hipStream_t stream) {
  (void)in_sizes; (void)n_in; (void)out_size; (void)ws_size;
  const float* x      = (const float*)d_in[0];
  const float* w_qkv  = (const float*)d_in[1];
  const float* w_out  = (const float*)d_in[2];
  const float* g1     = (const float*)d_in[3];
  const float* b1     = (const float*)d_in[4];
  const float* g2     = (const float*)d_in[5];
  const float* b2     = (const float*)d_in[6];
  const float* w_gate = (const float*)d_in[7];
  const float* b_gate = (const float*)d_in[8];
  const float* w_up   = (const float*)d_in[9];
  const float* b_up   = (const float*)d_in[10];
  const float* w_down = (const float*)d_in[11];
  const float* b_down = (const float*)d_in[12];
  float* out = (float*)d_out;

  // Workspace layout (MB), liveness-checked:
  //  0-8 wdownT | 8-16 y | 16-22 wqkvT | 22-24 woutT | 24-40 wguT (interleaved)
  //  40-48 qr | 48-56 kr | 56-64 vt | 64-64.5 trig (dead after qkv) | 64-72 o_
  //  out-proj partials: 72-104 + 104-136, dead after combine_ln
  //  x1: 56-72 (vt/o_ dead) | gated: 104-136 (part dead)
  //  down partials: pd0 16-48 (wqkvT/woutT/wguT dead by then), pd1 72-104
  const size_t MB = 1u << 20;
  char* ws = (char*)d_ws;
  u16*   wdownT = (u16*)(ws + 0 * MB);
  u16*   y      = (u16*)(ws + 8 * MB);
  u16*   wqkvT  = (u16*)(ws + 16 * MB);
  u16*   woutT  = (u16*)(ws + 22 * MB);
  u16*   wguT   = (u16*)(ws + 24 * MB);     // [8192][1024] interleaved gate/up
  u16*   qr_    = (u16*)(ws + 40 * MB);
  u16*   kr_    = (u16*)(ws + 48 * MB);
  u16*   vt     = (u16*)(ws + 56 * MB);
  float* trig   = (float*)(ws + 64 * MB);
  u16*   o_     = (u16*)(ws + 64 * MB);     // overwrites trig after qkv done
  float* part0  = (float*)(ws + 72 * MB);
  float* part1  = (float*)(ws + 104 * MB);
  float* x1     = (float*)(ws + 56 * MB);
  u16*   gated  = (u16*)(ws + 104 * MB);
  float* pd0    = (float*)(ws + 16 * MB);
  float* pd1    = (float*)(ws + 72 * MB);

  const dim3 blk(256);
  transpose_bf16<<<dim3(3072 / 32, 1024 / 64), blk, 0, stream>>>(w_qkv, wqkvT, 1024, 3072);
  transpose_bf16<<<dim3(1024 / 32, 1024 / 64), blk, 0, stream>>>(w_out, woutT, 1024, 1024);
  transpose_ilv<<<dim3(4096 / 32, 1024 / 64), blk, 0, stream>>>(w_gate, wguT, 1024, 4096, 0);
  transpose_ilv<<<dim3(4096 / 32, 1024 / 64), blk, 0, stream>>>(w_up, wguT, 1024, 4096, 16);
  transpose_bf16<<<dim3(1024 / 32, 4096 / 64), blk, 0, stream>>>(w_down, wdownT, 4096, 1024);
  trig_kernel<<<256, blk, 0, stream>>>(trig);

  // LN1: x -> y
  ln_kernel<<<4096, blk, 0, stream>>>(x, g1, b1, y);
  // QKV projection + fused RoPE/V-transpose epilogue -> qr, kr, vt
  gemm8p<6><<<dim3((3072 / 256) * (4096 / 256)), dim3(512), 0, stream>>>(
      y, wqkvT, qr_, nullptr, nullptr, nullptr, kr_, vt, trig,
      4096, 3072, 1024, 1024);
  // local-causal attention -> o_
  attn_kernel<<<4096, dim3(64), 0, stream>>>(qr_, kr_, vt, o_);
  // out-proj, split-K=4 (Kl=256) -> part0/part1; combine + residual + LN2 -> x1, y
  gemm8p<0><<<dim3(4 * 16 * 4), dim3(512), 0, stream>>>(
      o_, woutT, nullptr, nullptr, part0, part1, nullptr, nullptr, nullptr,
      4096, 1024, 1024, 256);
  combine_ln<<<4096, blk, 0, stream>>>(part0, part1, x, g2, b2, x1, y);
  // fused gate/up dual GEMM (virtual N=8192, interleaved) -> gated bf16 [4096][4096]
  gemm8p<7><<<dim3((8192 / 256) * (4096 / 256)), dim3(512), 0, stream>>>(
      y, wguT, gated, b_gate, nullptr, nullptr, nullptr, nullptr, b_up,
      4096, 8192, 1024, 1024);
  // down-proj, split-K=4 (Kl=1024) -> pd0/pd1; combine + bias + residual -> out
  gemm8p<0><<<dim3(4 * 16 * 4), dim3(512), 0, stream>>>(
      gated, wdownT, nullptr, nullptr, pd0, pd1, nullptr, nullptr, nullptr,
      4096, 1024, 4096, 1024);
  combine4<<<4096, blk, 0, stream>>>(pd0, pd1, x1, b_down, out);
}